// Round 7
// baseline (1576.513 us; speedup 1.0000x reference)
//
#include <hip/hip_runtime.h>
#include <hip/hip_bf16.h>

// ---------------------------------------------------------------------------
// GAT encoder, round 7: emulated-fp32 GEMM via hi/lo split bf16 MFMA
// (3 products: Ahi*Bhi + Ahi*Blo + Alo*Bhi, fp32 accum -> ~2^-17 relative).
// Round-7 change: GEMM is LDS-FREE. Fragments are loaded straight from
// global memory with per-lane global_load_dwordx4 (16 rows x 4 lq-lanes
// consume each 64B line fully). No staging, no barriers, no vmcnt(0) drain;
// waves are independent -> s_setprio(1) around the MFMA cluster (T5 regime).
// B panels are L2-resident per-XCD with the natural dispatch order.
// Everything outside the GEMM is identical to round 6.
// ---------------------------------------------------------------------------

#define LB(x) __launch_bounds__(x)

typedef unsigned short u16;
typedef unsigned int u32;
typedef __attribute__((ext_vector_type(8))) short bf16x8;
typedef __attribute__((ext_vector_type(4))) float f32x4;

__device__ __forceinline__ float b2f(u16 u) {
    union { float f; u32 u; } x;
    x.u = ((u32)u) << 16;
    return x.f;
}
__device__ __forceinline__ u16 f2b(float f) {
    u32 u = __float_as_uint(f);
    u = (u + 0x7FFFu + ((u >> 16) & 1u)) >> 16;   // RNE
    return (u16)u;
}
__device__ __forceinline__ float rec2(u32 p) {
    return b2f((u16)(p >> 16)) + b2f((u16)p);
}

// ---------------- CSR build ----------------
__global__ void k_deg(const int* __restrict__ ei, int E, int Np, int* __restrict__ deg) {
    int e = blockIdx.x * blockDim.x + threadIdx.x;
    if (e >= E + Np) return;
    int dst = (e < E) ? ei[E + e] : (e - E);
    atomicAdd(&deg[dst], 1);
}

__global__ LB(256) void k_s1(const int* __restrict__ deg, int* __restrict__ row_ptr,
                             int* __restrict__ bsum, int n) {
    __shared__ int sh[256];
    int b = blockIdx.x, t = threadIdx.x;
    int i = b * 256 + t;
    int v = (i < n) ? deg[i] : 0;
    sh[t] = v;
    __syncthreads();
    #pragma unroll
    for (int off = 1; off < 256; off <<= 1) {
        int add = (t >= off) ? sh[t - off] : 0;
        __syncthreads();
        sh[t] += add;
        __syncthreads();
    }
    if (i < n) row_ptr[i + 1] = sh[t];
    if (t == 255) bsum[b] = sh[255];
}

__global__ LB(64) void k_s2(int* __restrict__ bsum, int* __restrict__ boff, int nb) {
    __shared__ int sh[64];
    int t = threadIdx.x;
    sh[t] = (t < nb) ? bsum[t] : 0;
    __syncthreads();
    #pragma unroll
    for (int off = 1; off < 64; off <<= 1) {
        int add = (t >= off) ? sh[t - off] : 0;
        __syncthreads();
        sh[t] += add;
        __syncthreads();
    }
    if (t < nb) boff[t] = (t == 0) ? 0 : sh[t - 1];
}

__global__ LB(256) void k_s3(const int* __restrict__ deg, int* __restrict__ row_ptr,
                             const int* __restrict__ boff, int* __restrict__ cursor, int n) {
    int b = blockIdx.x, t = threadIdx.x;
    int i = b * 256 + t;
    if (i == 0) row_ptr[0] = 0;
    if (i < n) {
        int inc = row_ptr[i + 1] + boff[b];
        row_ptr[i + 1] = inc;
        cursor[i] = inc - deg[i];
    }
}

__global__ void k_fill(const int* __restrict__ ei, int E, int Np,
                       int* __restrict__ cursor, int* __restrict__ col_src) {
    int e = blockIdx.x * blockDim.x + threadIdx.x;
    if (e >= E + Np) return;
    int src, dst;
    if (e < E) { src = ei[e]; dst = ei[E + e]; }
    else       { src = dst = e - E; }
    int pos = atomicAdd(&cursor[dst], 1);
    col_src[pos] = src;
}

// ---------------- fp32 -> hi/lo planes ----------------
__global__ void k_pack(const float* __restrict__ in, u16* __restrict__ hi,
                       u16* __restrict__ lo, int n4) {
    int i = blockIdx.x * blockDim.x + threadIdx.x;
    if (i >= n4) return;
    float4 v = ((const float4*)in)[i];
    ushort4 h, l;
    h.x = f2b(v.x); l.x = f2b(v.x - b2f(h.x));
    h.y = f2b(v.y); l.y = f2b(v.y - b2f(h.y));
    h.z = f2b(v.z); l.z = f2b(v.z - b2f(h.z));
    h.w = f2b(v.w); l.w = f2b(v.w - b2f(h.w));
    ((ushort4*)hi)[i] = h;
    ((ushort4*)lo)[i] = l;
}

// ---------------- weight transpose + split: Wt[n][k] planes ----------------
__global__ LB(256) void k_wt_pack(const float* __restrict__ W, u16* __restrict__ Whi,
                                  u16* __restrict__ Wlo, int K, int Nn) {
    __shared__ float sh[32][33];
    int n0 = blockIdx.x * 32, k0 = blockIdx.y * 32;
    int c = threadIdx.x & 31, r0 = threadIdx.x >> 5;
    #pragma unroll
    for (int r = r0; r < 32; r += 8)
        sh[r][c] = W[(size_t)(k0 + r) * Nn + n0 + c];
    __syncthreads();
    #pragma unroll
    for (int r = r0; r < 32; r += 8) {
        float v = sh[c][r];
        u16 hi = f2b(v);
        Whi[(size_t)(n0 + r) * K + k0 + c] = hi;
        Wlo[(size_t)(n0 + r) * K + k0 + c] = f2b(v - b2f(hi));
    }
}

// ---------------- LDS-free split-plane MFMA GEMM: C = A @ Bt^T -------------
// 128x128 tile, 4 waves (2x2), 64x64/wave, BK=32, 48 MFMA/K-step/wave.
// Fragments loaded per-lane from global: lane (ln15,lq) reads row +ln15,
// k-chunk lq*8 -> the 4 lq lanes consume a full 64B line of each row.
// No __shared__, no __syncthreads in the K-loop.
template<bool PACKC>
__global__ __launch_bounds__(256, 3)
void k_gemm_nl(const u16* __restrict__ Ahi, const u16* __restrict__ Alo,
               const u16* __restrict__ Bhi, const u16* __restrict__ Blo,
               const float* __restrict__ bias,
               u16* __restrict__ Chi, u16* __restrict__ Clo,
               u32* __restrict__ Cpk,
               int M, int K, int Nn) {
    const int tid  = threadIdx.x;
    const int lane = tid & 63;
    const int w    = tid >> 6;
    const int wr   = w >> 1;
    const int wc   = w & 1;
    const int row0 = blockIdx.y * 128;
    const int col0 = blockIdx.x * 128;
    const int ln15 = lane & 15;
    const int lq   = lane >> 4;

    // per-lane base element-offsets (rows clamped for the M tail)
    size_t aoff[4], boff[4];
    #pragma unroll
    for (int m = 0; m < 4; ++m) {
        int r = row0 + wr * 64 + m * 16 + ln15;
        if (r > M - 1) r = M - 1;
        aoff[m] = (size_t)r * K + lq * 8;
    }
    #pragma unroll
    for (int n = 0; n < 4; ++n)
        boff[n] = (size_t)(col0 + wc * 64 + n * 16 + ln15) * K + lq * 8;

    f32x4 acc[4][4];
    #pragma unroll
    for (int m = 0; m < 4; ++m)
        #pragma unroll
        for (int n = 0; n < 4; ++n) acc[m][n] = (f32x4){0.f, 0.f, 0.f, 0.f};

    for (int k0 = 0; k0 < K; k0 += 32) {
        bf16x8 ah[4], al[4], bh[4], bl[4];
        #pragma unroll
        for (int m = 0; m < 4; ++m) {
            ah[m] = *(const bf16x8*)(Ahi + aoff[m] + k0);
            al[m] = *(const bf16x8*)(Alo + aoff[m] + k0);
        }
        #pragma unroll
        for (int n = 0; n < 4; ++n) {
            bh[n] = *(const bf16x8*)(Bhi + boff[n] + k0);
            bl[n] = *(const bf16x8*)(Blo + boff[n] + k0);
        }
        __builtin_amdgcn_s_setprio(1);
        #pragma unroll
        for (int m = 0; m < 4; ++m)
            #pragma unroll
            for (int n = 0; n < 4; ++n) {
                acc[m][n] = __builtin_amdgcn_mfma_f32_16x16x32_bf16(al[m], bh[n], acc[m][n], 0, 0, 0);
                acc[m][n] = __builtin_amdgcn_mfma_f32_16x16x32_bf16(ah[m], bl[n], acc[m][n], 0, 0, 0);
                acc[m][n] = __builtin_amdgcn_mfma_f32_16x16x32_bf16(ah[m], bh[n], acc[m][n], 0, 0, 0);
            }
        __builtin_amdgcn_s_setprio(0);
    }

    // D: col = lane&15, row = (lane>>4)*4 + j  [m89/m91-verified]
    #pragma unroll
    for (int m = 0; m < 4; ++m) {
        #pragma unroll
        for (int n = 0; n < 4; ++n) {
            int gc = col0 + wc * 64 + n * 16 + ln15;
            float badd = bias ? bias[gc] : 0.f;
            #pragma unroll
            for (int j = 0; j < 4; ++j) {
                int gr = row0 + wr * 64 + m * 16 + lq * 4 + j;
                if (gr < M) {
                    float v = acc[m][n][j] + badd;
                    u16 hi = f2b(v);
                    u16 lo = f2b(v - b2f(hi));
                    size_t o = (size_t)gr * Nn + gc;
                    if (PACKC) {
                        Cpk[o] = ((u32)hi << 16) | (u32)lo;   // 64B full-line stores
                    } else {
                        Chi[o] = hi;
                        Clo[o] = lo;
                    }
                }
            }
        }
    }
}

// ---------------- attention scalars from packed h ----------------
// grid = N, block = 64*H; C == 512.
__global__ void k_att(const u32* __restrict__ h_pk,
                      const float* __restrict__ att_s, const float* __restrict__ att_d,
                      float* __restrict__ a_src, float* __restrict__ a_dst,
                      int H, int C) {
    int n = blockIdx.x;
    int w = threadIdx.x >> 6;
    int lane = threadIdx.x & 63;
    const u32* hp = h_pk + (size_t)n * H * C + (size_t)w * C + lane * 8;
    uint4 p0 = ((const uint4*)hp)[0];
    uint4 p1 = ((const uint4*)hp)[1];
    float hv[8] = { rec2(p0.x), rec2(p0.y), rec2(p0.z), rec2(p0.w),
                    rec2(p1.x), rec2(p1.y), rec2(p1.z), rec2(p1.w) };
    float s1 = 0.f, s2 = 0.f;
    int ob = w * C + lane * 8;
    #pragma unroll
    for (int j = 0; j < 8; ++j) {
        s1 = fmaf(hv[j], att_s[ob + j], s1);
        s2 = fmaf(hv[j], att_d[ob + j], s2);
    }
    #pragma unroll
    for (int off = 32; off; off >>= 1) {
        s1 += __shfl_xor(s1, off);
        s2 += __shfl_xor(s2, off);
    }
    if (lane == 0) { a_src[n * H + w] = s1; a_dst[n * H + w] = s2; }
}

// ---------------- fused segment softmax per dst (one wave) ----------------
template<int HH>
__global__ LB(64) void k_softmax(const int* __restrict__ row_ptr, const int* __restrict__ col_src,
                                 const float* __restrict__ a_src, const float* __restrict__ a_dst,
                                 float* __restrict__ alpha) {
    int d = blockIdx.x;
    int t = threadIdx.x;
    int s = row_ptr[d], eend = row_ptr[d + 1];
    int cnt = eend - s;
    float adh[HH];
    #pragma unroll
    for (int h = 0; h < HH; ++h) adh[h] = a_dst[d * HH + h];

    if (cnt <= 64) {
        bool act = t < cnt;
        float av[HH];
        #pragma unroll
        for (int h = 0; h < HH; ++h) av[h] = 0.f;
        if (act) {
            int src = col_src[s + t];
            if (HH == 4) {
                float4 q = ((const float4*)a_src)[src];
                av[0] = q.x; av[1] = q.y; av[2] = q.z; av[3] = q.w;
            } else {
                av[0] = a_src[src];
            }
        }
        float v[HH], m[HH], sum[HH];
        #pragma unroll
        for (int h = 0; h < HH; ++h) {
            float x = av[h] + adh[h];
            x = (x > 0.f) ? x : 0.2f * x;
            v[h] = act ? x : -1e30f;
            m[h] = v[h];
        }
        #pragma unroll
        for (int off = 32; off; off >>= 1)
            #pragma unroll
            for (int h = 0; h < HH; ++h) m[h] = fmaxf(m[h], __shfl_xor(m[h], off));
        #pragma unroll
        for (int h = 0; h < HH; ++h) {
            float e = act ? __expf(v[h] - m[h]) : 0.f;
            v[h] = e;
            sum[h] = e;
        }
        #pragma unroll
        for (int off = 32; off; off >>= 1)
            #pragma unroll
            for (int h = 0; h < HH; ++h) sum[h] += __shfl_xor(sum[h], off);
        if (act) {
            if (HH == 4) {
                float4 o;
                o.x = v[0] / sum[0]; o.y = v[1] / sum[1];
                o.z = v[2] / sum[2]; o.w = v[3] / sum[3];
                ((float4*)alpha)[s + t] = o;
            } else {
                alpha[s + t] = v[0] / sum[0];
            }
        }
        return;
    }

    // generic fallback (deg > 64): 3-pass recompute
    for (int h = 0; h < HH; ++h) {
        float m = -1e30f;
        for (int e = s + t; e < eend; e += 64) {
            float x = a_src[col_src[e] * HH + h] + adh[h];
            x = (x > 0.f) ? x : 0.2f * x;
            m = fmaxf(m, x);
        }
        #pragma unroll
        for (int off = 32; off; off >>= 1) m = fmaxf(m, __shfl_xor(m, off));
        float sum = 0.f;
        for (int e = s + t; e < eend; e += 64) {
            float x = a_src[col_src[e] * HH + h] + adh[h];
            x = (x > 0.f) ? x : 0.2f * x;
            sum += __expf(x - m);
        }
        #pragma unroll
        for (int off = 32; off; off >>= 1) sum += __shfl_xor(sum, off);
        float inv = 1.0f / sum;
        for (int e = s + t; e < eend; e += 64) {
            float x = a_src[col_src[e] * HH + h] + adh[h];
            x = (x > 0.f) ? x : 0.2f * x;
            alpha[e * HH + h] = __expf(x - m) * inv;
        }
    }
}

// ---------------- aggregate: out[d] = sum_e alpha[e,h]*h[src] (+bias,ELU) --
// input packed u32; output planes (coalesced rows) or fp32 final.
template <bool PLANES_OUT, bool ELU_>
__global__ LB(256) void k_agg(const int* __restrict__ row_ptr, const int* __restrict__ col_src,
                              const float* __restrict__ alpha,
                              const u32* __restrict__ h_pk,
                              const float* __restrict__ bias,
                              u16* __restrict__ Ohi, u16* __restrict__ Olo,
                              float* __restrict__ Of, int H, int C) {
    int d = blockIdx.x;
    int tid = threadIdx.x;
    int F = H * C;
    int o = tid * 8;
    int h0 = o / C;   // wave-uniform for C=512
    float acc[8];
    #pragma unroll
    for (int j = 0; j < 8; ++j) acc[j] = 0.f;
    int s = row_ptr[d], eend = row_ptr[d + 1];
    for (int e = s; e < eend; ++e) {
        int src = col_src[e];
        float a = alpha[e * H + h0];
        const uint4* hp = (const uint4*)(h_pk + (size_t)src * F + o);
        uint4 p0 = hp[0], p1 = hp[1];
        acc[0] = fmaf(a, rec2(p0.x), acc[0]);
        acc[1] = fmaf(a, rec2(p0.y), acc[1]);
        acc[2] = fmaf(a, rec2(p0.z), acc[2]);
        acc[3] = fmaf(a, rec2(p0.w), acc[3]);
        acc[4] = fmaf(a, rec2(p1.x), acc[4]);
        acc[5] = fmaf(a, rec2(p1.y), acc[5]);
        acc[6] = fmaf(a, rec2(p1.z), acc[6]);
        acc[7] = fmaf(a, rec2(p1.w), acc[7]);
    }
    #pragma unroll
    for (int j = 0; j < 8; ++j) {
        acc[j] += bias[o + j];
        if (ELU_) acc[j] = (acc[j] > 0.f) ? acc[j] : __expf(acc[j]) - 1.f;
    }
    if (PLANES_OUT) {
        bf16x8 rh, rl;
        #pragma unroll
        for (int j = 0; j < 8; ++j) {
            u16 hi = f2b(acc[j]);
            rh[j] = (short)hi;
            rl[j] = (short)f2b(acc[j] - b2f(hi));
        }
        *(bf16x8*)(Ohi + (size_t)d * F + o) = rh;
        *(bf16x8*)(Olo + (size_t)d * F + o) = rl;
    } else {
        float* po = Of + (size_t)d * F + o;
        #pragma unroll
        for (int j4 = 0; j4 < 2; ++j4) {
            float4 r;
            r.x = acc[j4 * 4 + 0]; r.y = acc[j4 * 4 + 1];
            r.z = acc[j4 * 4 + 2]; r.w = acc[j4 * 4 + 3];
            *(float4*)&po[j4 * 4] = r;
        }
    }
}

// ---------------------------------------------------------------------------
extern "C" void kernel_launch(void* const* d_in, const int* in_sizes, int n_in,
                              void* d_out, int out_size, void* d_ws, size_t ws_size,
                              hipStream_t stream) {
    const float* x      = (const float*)d_in[0];
    const int*   ei     = (const int*)d_in[1];
    const float* proj_W = (const float*)d_in[2];
    const float* proj_b = (const float*)d_in[3];
    const float* W1  = (const float*)d_in[4];
    const float* as1 = (const float*)d_in[5];
    const float* ad1 = (const float*)d_in[6];
    const float* b1  = (const float*)d_in[7];
    const float* W2  = (const float*)d_in[8];
    const float* as2 = (const float*)d_in[9];
    const float* ad2 = (const float*)d_in[10];
    const float* b2  = (const float*)d_in[11];
    const float* W3  = (const float*)d_in[12];
    const float* as3 = (const float*)d_in[13];
    const float* ad3 = (const float*)d_in[14];
    const float* b3  = (const float*)d_in[15];

    const int N  = in_sizes[0] / 256;   // 10000
    const int E  = in_sizes[1] / 2;     // 160000
    const int Ep = E + N;
    const int NB = (N + 255) / 256;     // 40 scan blocks

    size_t off = 0;
    auto alloc = [&](size_t bytes) -> void* {
        void* p = (char*)d_ws + off;
        off += (bytes + 255) & ~(size_t)255;
        return p;
    };
    u16* bufA_hi = (u16*)alloc((size_t)N * 2048 * 2);   // GEMM A input planes
    u16* bufA_lo = (u16*)alloc((size_t)N * 2048 * 2);
    u32* bufPk   = (u32*)alloc((size_t)N * 2048 * 4);   // packed GEMM output
    float* a_src   = (float*)alloc((size_t)N * 4 * 4);
    float* a_dst   = (float*)alloc((size_t)N * 4 * 4);
    float* alpha   = (float*)alloc((size_t)Ep * 4 * 4);
    int*   deg     = (int*)alloc((size_t)N * 4);
    int*   cursor  = (int*)alloc((size_t)N * 4);
    int*   row_ptr = (int*)alloc((size_t)(N + 1) * 4);
    int*   col_src = (int*)alloc((size_t)Ep * 4);
    int*   bsum    = (int*)alloc((size_t)NB * 4);
    int*   boff    = (int*)alloc((size_t)NB * 4);
    (void)ws_size;

    // JIT weight planes in d_out (16.78 MB <= 20.48 MB); fully overwritten
    // by the final aggregate afterwards.
    u16* whi = (u16*)d_out;
    u16* wlo = (u16*)d_out + (size_t)2048 * 2048;

    // ---- CSR build ----
    hipMemsetAsync(deg, 0, (size_t)N * 4, stream);
    int eb = (Ep + 255) / 256;
    k_deg<<<eb, 256, 0, stream>>>(ei, E, N, deg);
    k_s1<<<NB, 256, 0, stream>>>(deg, row_ptr, bsum, N);
    k_s2<<<1, 64, 0, stream>>>(bsum, boff, NB);
    k_s3<<<NB, 256, 0, stream>>>(deg, row_ptr, boff, cursor, N);
    k_fill<<<eb, 256, 0, stream>>>(ei, E, N, cursor, col_src);

    const int MB1 = (N + 127) / 128;  // 79

    // ---- pack x into bufA planes [N,256] (proj A input) ----
    k_pack<<<(N * 256 / 4 + 255) / 256, 256, 0, stream>>>(x, bufA_hi, bufA_lo, N * 256 / 4);

    // ---- proj: bufA planes -> proj planes (in bufPk space) ----
    u16* proj_hi = (u16*)bufPk;                       // [N,512] u16
    u16* proj_lo = (u16*)bufPk + (size_t)N * 512;     // [N,512] u16
    k_wt_pack<<<dim3(512 / 32, 256 / 32), 256, 0, stream>>>(proj_W, whi, wlo, 256, 512);
    k_gemm_nl<false><<<dim3(512 / 128, MB1), 256, 0, stream>>>(
        bufA_hi, bufA_lo, whi, wlo, proj_b, proj_hi, proj_lo, nullptr, N, 256, 512);

    // ---- layer 1 (H=4, C=512, concat, ELU) ----
    k_wt_pack<<<dim3(2048 / 32, 512 / 32), 256, 0, stream>>>(W1, whi, wlo, 512, 2048);
    u32* l1pk = (u32*)bufA_hi;   // [N,2048] u32 spans bufA_hi+bufA_lo (80MB)
    k_gemm_nl<true><<<dim3(2048 / 128, MB1), 256, 0, stream>>>(
        proj_hi, proj_lo, whi, wlo, nullptr, nullptr, nullptr, l1pk, N, 512, 2048);
    k_att<<<N, 256, 0, stream>>>(l1pk, as1, ad1, a_src, a_dst, 4, 512);
    k_softmax<4><<<N, 64, 0, stream>>>(row_ptr, col_src, a_src, a_dst, alpha);
    u16* h1_hi = (u16*)bufPk;                         // [N,2048] u16
    u16* h1_lo = (u16*)bufPk + (size_t)N * 2048;      // [N,2048] u16
    k_agg<true, true><<<N, 256, 0, stream>>>(row_ptr, col_src, alpha, l1pk,
                                             b1, h1_hi, h1_lo, nullptr, 4, 512);

    // ---- layer 2 (H=4, C=512, concat, ELU) ----
    k_wt_pack<<<dim3(2048 / 32, 2048 / 32), 256, 0, stream>>>(W2, whi, wlo, 2048, 2048);
    u32* l2pk = (u32*)bufA_hi;   // reuse 80MB region (l1pk dead after agg)
    k_gemm_nl<true><<<dim3(2048 / 128, MB1), 256, 0, stream>>>(
        h1_hi, h1_lo, whi, wlo, nullptr, nullptr, nullptr, l2pk, N, 2048, 2048);
    k_att<<<N, 256, 0, stream>>>(l2pk, as2, ad2, a_src, a_dst, 4, 512);
    k_softmax<4><<<N, 64, 0, stream>>>(row_ptr, col_src, a_src, a_dst, alpha);
    u16* h2_hi = (u16*)bufPk;
    u16* h2_lo = (u16*)bufPk + (size_t)N * 2048;
    k_agg<true, true><<<N, 256, 0, stream>>>(row_ptr, col_src, alpha, l2pk,
                                             b2, h2_hi, h2_lo, nullptr, 4, 512);

    // ---- layer 3 (H=1, C=512, mean over single head = identity, no ELU) ----
    k_wt_pack<<<dim3(512 / 32, 2048 / 32), 256, 0, stream>>>(W3, whi, wlo, 2048, 512);
    u32* l3pk = (u32*)bufA_hi;   // [N,512] u32
    k_gemm_nl<true><<<dim3(512 / 128, MB1), 256, 0, stream>>>(
        h2_hi, h2_lo, whi, wlo, nullptr, nullptr, nullptr, l3pk, N, 2048, 512);
    k_att<<<N, 64, 0, stream>>>(l3pk, as3, ad3, a_src, a_dst, 1, 512);
    k_softmax<1><<<N, 64, 0, stream>>>(row_ptr, col_src, a_src, a_dst, alpha);
    k_agg<false, false><<<N, 64, 0, stream>>>(row_ptr, col_src, alpha, l3pk,
                                              b3, nullptr, nullptr, (float*)d_out, 1, 512);
}

// Round 9
// 1060.212 us; speedup vs baseline: 1.4870x; 1.4870x over previous
//
#include <hip/hip_runtime.h>
#include <hip/hip_bf16.h>

// ---------------------------------------------------------------------------
// GAT encoder, round 9: emulated-fp32 GEMM via hi/lo split bf16 MFMA
// (3 products: Ahi*Bhi + Ahi*Blo + Alo*Bhi, fp32 accum -> ~2^-17 relative).
// Round-9 changes vs round-6:
//  * attention scalars FUSED into the GEMM epilogue (exact fp32 logits from
//    the accumulator, 16-lane shuffle reduce + atomicAdd) -- k_att removed.
//  * h packed-u32 (exact) for layers 1-2; fp16 h for layer 3 only (error
//    ~2^-11*|h3| hits the output directly, no amplification).
//  * BN=64 tile for the N=512 GEMMs (proj, L3): grid 316 -> 632.
// ---------------------------------------------------------------------------

#define LB(x) __launch_bounds__(x)

typedef unsigned short u16;
typedef unsigned int u32;
typedef __attribute__((ext_vector_type(8))) short short8;
typedef __attribute__((ext_vector_type(8))) short bf16x8;
typedef __attribute__((ext_vector_type(4))) float f32x4;

__device__ __forceinline__ float b2f(u16 u) {
    union { float f; u32 u; } x;
    x.u = ((u32)u) << 16;
    return x.f;
}
__device__ __forceinline__ u16 f2b(float f) {
    u32 u = __float_as_uint(f);
    u = (u + 0x7FFFu + ((u >> 16) & 1u)) >> 16;   // RNE
    return (u16)u;
}
__device__ __forceinline__ float rec2(u32 p) {
    return b2f((u16)(p >> 16)) + b2f((u16)p);
}
__device__ __forceinline__ u16 f2h(float f) {
    union { _Float16 h; u16 u; } x;
    x.h = (_Float16)f;
    return x.u;
}
__device__ __forceinline__ float h2f(u16 u) {
    union { _Float16 h; u16 u; } x;
    x.u = u;
    return (float)x.h;
}
__device__ __forceinline__ void lds_cp16(const void* g, void* l) {
    __builtin_amdgcn_global_load_lds(
        (const __attribute__((address_space(1))) unsigned int*)g,
        (__attribute__((address_space(3))) unsigned int*)l, 16, 0, 0);
}

// ---------------- CSR build ----------------
__global__ void k_deg(const int* __restrict__ ei, int E, int Np, int* __restrict__ deg) {
    int e = blockIdx.x * blockDim.x + threadIdx.x;
    if (e >= E + Np) return;
    int dst = (e < E) ? ei[E + e] : (e - E);
    atomicAdd(&deg[dst], 1);
}

__global__ LB(256) void k_s1(const int* __restrict__ deg, int* __restrict__ row_ptr,
                             int* __restrict__ bsum, int n) {
    __shared__ int sh[256];
    int b = blockIdx.x, t = threadIdx.x;
    int i = b * 256 + t;
    int v = (i < n) ? deg[i] : 0;
    sh[t] = v;
    __syncthreads();
    #pragma unroll
    for (int off = 1; off < 256; off <<= 1) {
        int add = (t >= off) ? sh[t - off] : 0;
        __syncthreads();
        sh[t] += add;
        __syncthreads();
    }
    if (i < n) row_ptr[i + 1] = sh[t];
    if (t == 255) bsum[b] = sh[255];
}

__global__ LB(64) void k_s2(int* __restrict__ bsum, int* __restrict__ boff, int nb) {
    __shared__ int sh[64];
    int t = threadIdx.x;
    sh[t] = (t < nb) ? bsum[t] : 0;
    __syncthreads();
    #pragma unroll
    for (int off = 1; off < 64; off <<= 1) {
        int add = (t >= off) ? sh[t - off] : 0;
        __syncthreads();
        sh[t] += add;
        __syncthreads();
    }
    if (t < nb) boff[t] = (t == 0) ? 0 : sh[t - 1];
}

__global__ LB(256) void k_s3(const int* __restrict__ deg, int* __restrict__ row_ptr,
                             const int* __restrict__ boff, int* __restrict__ cursor, int n) {
    int b = blockIdx.x, t = threadIdx.x;
    int i = b * 256 + t;
    if (i == 0) row_ptr[0] = 0;
    if (i < n) {
        int inc = row_ptr[i + 1] + boff[b];
        row_ptr[i + 1] = inc;
        cursor[i] = inc - deg[i];
    }
}

__global__ void k_fill(const int* __restrict__ ei, int E, int Np,
                       int* __restrict__ cursor, int* __restrict__ col_src) {
    int e = blockIdx.x * blockDim.x + threadIdx.x;
    if (e >= E + Np) return;
    int src, dst;
    if (e < E) { src = ei[e]; dst = ei[E + e]; }
    else       { src = dst = e - E; }
    int pos = atomicAdd(&cursor[dst], 1);
    col_src[pos] = src;
}

// ---------------- fp32 -> hi/lo planes ----------------
__global__ void k_pack(const float* __restrict__ in, u16* __restrict__ hi,
                       u16* __restrict__ lo, int n4) {
    int i = blockIdx.x * blockDim.x + threadIdx.x;
    if (i >= n4) return;
    float4 v = ((const float4*)in)[i];
    ushort4 h, l;
    h.x = f2b(v.x); l.x = f2b(v.x - b2f(h.x));
    h.y = f2b(v.y); l.y = f2b(v.y - b2f(h.y));
    h.z = f2b(v.z); l.z = f2b(v.z - b2f(h.z));
    h.w = f2b(v.w); l.w = f2b(v.w - b2f(h.w));
    ((ushort4*)hi)[i] = h;
    ((ushort4*)lo)[i] = l;
}

// ---------------- weight transpose + split: Wt[n][k] planes ----------------
__global__ LB(256) void k_wt_pack(const float* __restrict__ W, u16* __restrict__ Whi,
                                  u16* __restrict__ Wlo, int K, int Nn) {
    __shared__ float sh[32][33];
    int n0 = blockIdx.x * 32, k0 = blockIdx.y * 32;
    int c = threadIdx.x & 31, r0 = threadIdx.x >> 5;
    #pragma unroll
    for (int r = r0; r < 32; r += 8)
        sh[r][c] = W[(size_t)(k0 + r) * Nn + n0 + c];
    __syncthreads();
    #pragma unroll
    for (int r = r0; r < 32; r += 8) {
        float v = sh[c][r];
        u16 hi = f2b(v);
        Whi[(size_t)(n0 + r) * K + k0 + c] = hi;
        Wlo[(size_t)(n0 + r) * K + k0 + c] = f2b(v - b2f(hi));
    }
}

// ---------------- split-plane MFMA GEMM: C = A[M,K] @ Bt[Nn,K]^T -----------
// Round-6 proven core: BM=128, BK=32, 4 waves (2x2), LDS XOR swizzle
// (row&7)<<4 with inverse-permuted global_load_lds source.
// NFR = B-frags/wave (4 -> BN=128; 2 -> BN=64).  OUTMODE: 0=hi/lo planes
// (+bias), 1=packed u32, 2=fp16.  ATT: fuse a_src/a_dst = h . att_{s,d}
// (exact fp32 from accumulator; 16-lane shuffle reduce + atomicAdd).
template<int NFR, int OUTMODE, bool ATT>
__global__ LB(256) void k_gemm_pl(const u16* __restrict__ Ahi, const u16* __restrict__ Alo,
                                  const u16* __restrict__ Bhi, const u16* __restrict__ Blo,
                                  const float* __restrict__ bias,
                                  u16* __restrict__ Chi, u16* __restrict__ Clo,
                                  u32* __restrict__ Cpk, u16* __restrict__ Cf16,
                                  const float* __restrict__ att_s, const float* __restrict__ att_d,
                                  float* __restrict__ a_src, float* __restrict__ a_dst,
                                  int HH, int M, int K, int Nn) {
    constexpr int BN = NFR * 32;
    __shared__ u16 AsHi[128 * 32], AsLo[128 * 32];
    __shared__ u16 BsHi[BN * 32], BsLo[BN * 32];
    const int tid  = threadIdx.x;
    const int lane = tid & 63;
    const int w    = tid >> 6;
    const int wr   = w >> 1;
    const int wc   = w & 1;
    const int row0 = blockIdx.y * 128;
    const int col0 = blockIdx.x * BN;
    const int ln15 = lane & 15;
    const int lq   = lane >> 4;

    f32x4 acc[4][NFR];
    #pragma unroll
    for (int m = 0; m < 4; ++m)
        #pragma unroll
        for (int n = 0; n < NFR; ++n) acc[m][n] = (f32x4){0.f, 0.f, 0.f, 0.f};

    for (int k0 = 0; k0 < K; k0 += 32) {
        // A planes: 512 16B-chunks each, 2 per thread per plane.
        #pragma unroll
        for (int i = 0; i < 2; ++i) {
            int c = i * 256 + tid;
            int r  = 2 * (c >> 3) + (((c >> 2) ^ (c >> 4)) & 1);   // inverse swizzle
            int kc = (c & 3) ^ (r & 3);
            int gra = row0 + r; if (gra >= M) gra = M - 1;          // tail clamp
            size_t ga = (size_t)gra * K + k0 + kc * 8;
            lds_cp16(Ahi + ga, (char*)AsHi + c * 16);
            lds_cp16(Alo + ga, (char*)AsLo + c * 16);
        }
        // B planes: BN*4 chunks each, NFR/2 per thread per plane.
        #pragma unroll
        for (int i = 0; i < NFR / 2; ++i) {
            int c = i * 256 + tid;
            int r  = 2 * (c >> 3) + (((c >> 2) ^ (c >> 4)) & 1);
            int kc = (c & 3) ^ (r & 3);
            size_t gb = (size_t)(col0 + r) * K + k0 + kc * 8;
            lds_cp16(Bhi + gb, (char*)BsHi + c * 16);
            lds_cp16(Blo + gb, (char*)BsLo + c * 16);
        }
        __syncthreads();
        bf16x8 ah[4], al[4], bh[NFR], bl[NFR];
        #pragma unroll
        for (int m = 0; m < 4; ++m) {
            int row = wr * 64 + m * 16 + ln15;
            int byo = (row * 64 + lq * 16) ^ ((row & 7) << 4);
            ah[m] = *(const bf16x8*)((const char*)AsHi + byo);
            al[m] = *(const bf16x8*)((const char*)AsLo + byo);
        }
        #pragma unroll
        for (int n = 0; n < NFR; ++n) {
            int row = wc * (NFR * 16) + n * 16 + ln15;
            int byo = (row * 64 + lq * 16) ^ ((row & 7) << 4);
            bh[n] = *(const bf16x8*)((const char*)BsHi + byo);
            bl[n] = *(const bf16x8*)((const char*)BsLo + byo);
        }
        #pragma unroll
        for (int m = 0; m < 4; ++m)
            #pragma unroll
            for (int n = 0; n < NFR; ++n) {
                acc[m][n] = __builtin_amdgcn_mfma_f32_16x16x32_bf16(al[m], bh[n], acc[m][n], 0, 0, 0);
                acc[m][n] = __builtin_amdgcn_mfma_f32_16x16x32_bf16(ah[m], bl[n], acc[m][n], 0, 0, 0);
                acc[m][n] = __builtin_amdgcn_mfma_f32_16x16x32_bf16(ah[m], bh[n], acc[m][n], 0, 0, 0);
            }
        __syncthreads();
    }

    // D: col = lane&15, row = (lane>>4)*4 + j  [m89/m91-verified]
    #pragma unroll
    for (int m = 0; m < 4; ++m) {
        #pragma unroll
        for (int n = 0; n < NFR; ++n) {
            int gc = col0 + wc * (NFR * 16) + n * 16 + ln15;
            float badd = (OUTMODE == 0 && bias) ? bias[gc] : 0.f;
            #pragma unroll
            for (int j = 0; j < 4; ++j) {
                int gr = row0 + wr * 64 + m * 16 + lq * 4 + j;
                if (gr < M) {
                    float v = acc[m][n][j] + badd;
                    size_t o = (size_t)gr * Nn + gc;
                    if (OUTMODE == 0) {
                        u16 hi = f2b(v);
                        Chi[o] = hi;
                        Clo[o] = f2b(v - b2f(hi));
                    } else if (OUTMODE == 1) {
                        u16 hi = f2b(v);
                        Cpk[o] = ((u32)hi << 16) | (u32)f2b(v - b2f(hi));
                    } else {
                        Cf16[o] = f2h(v);
                    }
                }
            }
        }
    }

    if (ATT) {
        // per-lane att coefficients for its NFR columns (att flat [H*C] = [Nn])
        float atts[NFR], attd[NFR];
        #pragma unroll
        for (int n = 0; n < NFR; ++n) {
            int gc = col0 + wc * (NFR * 16) + n * 16 + ln15;
            atts[n] = att_s[gc];
            attd[n] = att_d[gc];
        }
        const int head = (col0 + wc * (NFR * 16)) >> 9;   // /512, wave-uniform
        #pragma unroll
        for (int m = 0; m < 4; ++m) {
            #pragma unroll
            for (int j = 0; j < 4; ++j) {
                int gr = row0 + wr * 64 + m * 16 + lq * 4 + j;
                float s1 = 0.f, s2 = 0.f;
                #pragma unroll
                for (int n = 0; n < NFR; ++n) {
                    float v = acc[m][n][j];
                    s1 = fmaf(v, atts[n], s1);
                    s2 = fmaf(v, attd[n], s2);
                }
                #pragma unroll
                for (int off = 1; off < 16; off <<= 1) {
                    s1 += __shfl_xor(s1, off);
                    s2 += __shfl_xor(s2, off);
                }
                if (ln15 == 0 && gr < M) {
                    atomicAdd(&a_src[gr * HH + head], s1);
                    atomicAdd(&a_dst[gr * HH + head], s2);
                }
            }
        }
    }
}

// ---------------- fused segment softmax per dst (one wave) ----------------
template<int HH>
__global__ LB(64) void k_softmax(const int* __restrict__ row_ptr, const int* __restrict__ col_src,
                                 const float* __restrict__ a_src, const float* __restrict__ a_dst,
                                 float* __restrict__ alpha) {
    int d = blockIdx.x;
    int t = threadIdx.x;
    int s = row_ptr[d], eend = row_ptr[d + 1];
    int cnt = eend - s;
    float adh[HH];
    #pragma unroll
    for (int h = 0; h < HH; ++h) adh[h] = a_dst[d * HH + h];

    if (cnt <= 64) {
        bool act = t < cnt;
        float av[HH];
        #pragma unroll
        for (int h = 0; h < HH; ++h) av[h] = 0.f;
        if (act) {
            int src = col_src[s + t];
            if (HH == 4) {
                float4 q = ((const float4*)a_src)[src];
                av[0] = q.x; av[1] = q.y; av[2] = q.z; av[3] = q.w;
            } else {
                av[0] = a_src[src];
            }
        }
        float v[HH], m[HH], sum[HH];
        #pragma unroll
        for (int h = 0; h < HH; ++h) {
            float x = av[h] + adh[h];
            x = (x > 0.f) ? x : 0.2f * x;
            v[h] = act ? x : -1e30f;
            m[h] = v[h];
        }
        #pragma unroll
        for (int off = 32; off; off >>= 1)
            #pragma unroll
            for (int h = 0; h < HH; ++h) m[h] = fmaxf(m[h], __shfl_xor(m[h], off));
        #pragma unroll
        for (int h = 0; h < HH; ++h) {
            float e = act ? __expf(v[h] - m[h]) : 0.f;
            v[h] = e;
            sum[h] = e;
        }
        #pragma unroll
        for (int off = 32; off; off >>= 1)
            #pragma unroll
            for (int h = 0; h < HH; ++h) sum[h] += __shfl_xor(sum[h], off);
        if (act) {
            if (HH == 4) {
                float4 o;
                o.x = v[0] / sum[0]; o.y = v[1] / sum[1];
                o.z = v[2] / sum[2]; o.w = v[3] / sum[3];
                ((float4*)alpha)[s + t] = o;
            } else {
                alpha[s + t] = v[0] / sum[0];
            }
        }
        return;
    }

    // generic fallback (deg > 64): 3-pass recompute
    for (int h = 0; h < HH; ++h) {
        float m = -1e30f;
        for (int e = s + t; e < eend; e += 64) {
            float x = a_src[col_src[e] * HH + h] + adh[h];
            x = (x > 0.f) ? x : 0.2f * x;
            m = fmaxf(m, x);
        }
        #pragma unroll
        for (int off = 32; off; off >>= 1) m = fmaxf(m, __shfl_xor(m, off));
        float sum = 0.f;
        for (int e = s + t; e < eend; e += 64) {
            float x = a_src[col_src[e] * HH + h] + adh[h];
            x = (x > 0.f) ? x : 0.2f * x;
            sum += __expf(x - m);
        }
        #pragma unroll
        for (int off = 32; off; off >>= 1) sum += __shfl_xor(sum, off);
        float inv = 1.0f / sum;
        for (int e = s + t; e < eend; e += 64) {
            float x = a_src[col_src[e] * HH + h] + adh[h];
            x = (x > 0.f) ? x : 0.2f * x;
            alpha[e * HH + h] = __expf(x - m) * inv;
        }
    }
}

// ---------------- aggregate: out[d] = sum_e alpha[e,h]*h[src] (+bias,ELU) --
// HMODE 0: packed u32 h; HMODE 1: fp16 h. Output planes or fp32 final.
template <int HMODE, bool PLANES_OUT, bool ELU_>
__global__ LB(256) void k_agg(const int* __restrict__ row_ptr, const int* __restrict__ col_src,
                              const float* __restrict__ alpha,
                              const u32* __restrict__ h_pk, const u16* __restrict__ hf,
                              const float* __restrict__ bias,
                              u16* __restrict__ Ohi, u16* __restrict__ Olo,
                              float* __restrict__ Of, int H, int C) {
    int d = blockIdx.x;
    int tid = threadIdx.x;
    int F = H * C;
    int o = tid * 8;
    int h0 = o / C;   // wave-uniform for C=512
    float acc[8];
    #pragma unroll
    for (int j = 0; j < 8; ++j) acc[j] = 0.f;
    int s = row_ptr[d], eend = row_ptr[d + 1];
    for (int e = s; e < eend; ++e) {
        int src = col_src[e];
        float a = alpha[e * H + h0];
        if (HMODE == 0) {
            const uint4* hp = (const uint4*)(h_pk + (size_t)src * F + o);
            uint4 p0 = hp[0], p1 = hp[1];
            acc[0] = fmaf(a, rec2(p0.x), acc[0]);
            acc[1] = fmaf(a, rec2(p0.y), acc[1]);
            acc[2] = fmaf(a, rec2(p0.z), acc[2]);
            acc[3] = fmaf(a, rec2(p0.w), acc[3]);
            acc[4] = fmaf(a, rec2(p1.x), acc[4]);
            acc[5] = fmaf(a, rec2(p1.y), acc[5]);
            acc[6] = fmaf(a, rec2(p1.z), acc[6]);
            acc[7] = fmaf(a, rec2(p1.w), acc[7]);
        } else {
            short8 v = *(const short8*)(hf + (size_t)src * F + o);
            #pragma unroll
            for (int j = 0; j < 8; ++j)
                acc[j] = fmaf(a, h2f((u16)v[j]), acc[j]);
        }
    }
    #pragma unroll
    for (int j = 0; j < 8; ++j) {
        acc[j] += bias[o + j];
        if (ELU_) acc[j] = (acc[j] > 0.f) ? acc[j] : __expf(acc[j]) - 1.f;
    }
    if (PLANES_OUT) {
        bf16x8 rh, rl;
        #pragma unroll
        for (int j = 0; j < 8; ++j) {
            u16 hi = f2b(acc[j]);
            rh[j] = (short)hi;
            rl[j] = (short)f2b(acc[j] - b2f(hi));
        }
        *(bf16x8*)(Ohi + (size_t)d * F + o) = rh;
        *(bf16x8*)(Olo + (size_t)d * F + o) = rl;
    } else {
        float* po = Of + (size_t)d * F + o;
        #pragma unroll
        for (int j4 = 0; j4 < 2; ++j4) {
            float4 r;
            r.x = acc[j4 * 4 + 0]; r.y = acc[j4 * 4 + 1];
            r.z = acc[j4 * 4 + 2]; r.w = acc[j4 * 4 + 3];
            *(float4*)&po[j4 * 4] = r;
        }
    }
}

// ---------------------------------------------------------------------------
extern "C" void kernel_launch(void* const* d_in, const int* in_sizes, int n_in,
                              void* d_out, int out_size, void* d_ws, size_t ws_size,
                              hipStream_t stream) {
    const float* x      = (const float*)d_in[0];
    const int*   ei     = (const int*)d_in[1];
    const float* proj_W = (const float*)d_in[2];
    const float* proj_b = (const float*)d_in[3];
    const float* W1  = (const float*)d_in[4];
    const float* as1 = (const float*)d_in[5];
    const float* ad1 = (const float*)d_in[6];
    const float* b1  = (const float*)d_in[7];
    const float* W2  = (const float*)d_in[8];
    const float* as2 = (const float*)d_in[9];
    const float* ad2 = (const float*)d_in[10];
    const float* b2  = (const float*)d_in[11];
    const float* W3  = (const float*)d_in[12];
    const float* as3 = (const float*)d_in[13];
    const float* ad3 = (const float*)d_in[14];
    const float* b3  = (const float*)d_in[15];

    const int N  = in_sizes[0] / 256;   // 10000
    const int E  = in_sizes[1] / 2;     // 160000
    const int Ep = E + N;
    const int NB = (N + 255) / 256;     // 40 scan blocks

    size_t off = 0;
    auto alloc = [&](size_t bytes) -> void* {
        void* p = (char*)d_ws + off;
        off += (bytes + 255) & ~(size_t)255;
        return p;
    };
    u16* bufA_hi = (u16*)alloc((size_t)N * 2048 * 2);   // region A (80 MB)
    u16* bufA_lo = (u16*)alloc((size_t)N * 2048 * 2);
    u32* bufPk   = (u32*)alloc((size_t)N * 2048 * 4);   // region B (80 MB)
    u16* xb_hi   = (u16*)alloc((size_t)N * 256 * 2);
    u16* xb_lo   = (u16*)alloc((size_t)N * 256 * 2);
    float* att_z   = (float*)alloc((size_t)N * 18 * 4); // a_src/a_dst x3 layers
    float* alpha   = (float*)alloc((size_t)Ep * 4 * 4);
    int*   deg     = (int*)alloc((size_t)N * 4);
    int*   cursor  = (int*)alloc((size_t)N * 4);
    int*   row_ptr = (int*)alloc((size_t)(N + 1) * 4);
    int*   col_src = (int*)alloc((size_t)Ep * 4);
    int*   bsum    = (int*)alloc((size_t)NB * 4);
    int*   boff    = (int*)alloc((size_t)NB * 4);
    (void)ws_size;

    float* a_src1 = att_z;
    float* a_dst1 = att_z + (size_t)N * 4;
    float* a_src2 = att_z + (size_t)N * 8;
    float* a_dst2 = att_z + (size_t)N * 12;
    float* a_src3 = att_z + (size_t)N * 16;
    float* a_dst3 = att_z + (size_t)N * 17;

    // JIT weight planes in d_out (16.78 MB <= 20.48 MB); fully overwritten
    // by the final aggregate afterwards.
    u16* whi = (u16*)d_out;
    u16* wlo = (u16*)d_out + (size_t)2048 * 2048;

    // ---- CSR build + zero att accumulators ----
    hipMemsetAsync(deg, 0, (size_t)N * 4, stream);
    hipMemsetAsync(att_z, 0, (size_t)N * 18 * 4, stream);
    int eb = (Ep + 255) / 256;
    k_deg<<<eb, 256, 0, stream>>>(ei, E, N, deg);
    k_s1<<<NB, 256, 0, stream>>>(deg, row_ptr, bsum, N);
    k_s2<<<1, 64, 0, stream>>>(bsum, boff, NB);
    k_s3<<<NB, 256, 0, stream>>>(deg, row_ptr, boff, cursor, N);
    k_fill<<<eb, 256, 0, stream>>>(ei, E, N, cursor, col_src);

    const int MB1 = (N + 127) / 128;  // 79

    // ---- pack x into planes [N,256] ----
    k_pack<<<(N * 256 / 4 + 255) / 256, 256, 0, stream>>>(x, xb_hi, xb_lo, N * 256 / 4);

    // ---- proj: x planes -> proj planes (bufPk space), BN=64, +bias ----
    u16* proj_hi = (u16*)bufPk;                       // [N,512] u16
    u16* proj_lo = (u16*)bufPk + (size_t)N * 512;
    k_wt_pack<<<dim3(512 / 32, 256 / 32), 256, 0, stream>>>(proj_W, whi, wlo, 256, 512);
    k_gemm_pl<2, 0, false><<<dim3(512 / 64, MB1), 256, 0, stream>>>(
        xb_hi, xb_lo, whi, wlo, proj_b, proj_hi, proj_lo, nullptr, nullptr,
        nullptr, nullptr, nullptr, nullptr, 0, N, 256, 512);

    // ---- layer 1 (H=4, C=512, concat, ELU) ----
    k_wt_pack<<<dim3(2048 / 32, 512 / 32), 256, 0, stream>>>(W1, whi, wlo, 512, 2048);
    u32* l1pk = (u32*)bufA_hi;   // [N,2048] u32 spans region A
    k_gemm_pl<4, 1, true><<<dim3(2048 / 128, MB1), 256, 0, stream>>>(
        proj_hi, proj_lo, whi, wlo, nullptr, nullptr, nullptr, l1pk, nullptr,
        as1, ad1, a_src1, a_dst1, 4, N, 512, 2048);
    k_softmax<4><<<N, 64, 0, stream>>>(row_ptr, col_src, a_src1, a_dst1, alpha);
    u16* h1_hi = (u16*)bufPk;                         // planes in region B
    u16* h1_lo = (u16*)bufPk + (size_t)N * 2048;
    k_agg<0, true, true><<<N, 256, 0, stream>>>(row_ptr, col_src, alpha, l1pk, nullptr,
                                                b1, h1_hi, h1_lo, nullptr, 4, 512);

    // ---- layer 2 (H=4, C=512, concat, ELU) ----
    k_wt_pack<<<dim3(2048 / 32, 2048 / 32), 256, 0, stream>>>(W2, whi, wlo, 2048, 2048);
    u32* l2pk = (u32*)bufA_hi;   // reuse region A
    k_gemm_pl<4, 1, true><<<dim3(2048 / 128, MB1), 256, 0, stream>>>(
        h1_hi, h1_lo, whi, wlo, nullptr, nullptr, nullptr, l2pk, nullptr,
        as2, ad2, a_src2, a_dst2, 4, N, 2048, 2048);
    k_softmax<4><<<N, 64, 0, stream>>>(row_ptr, col_src, a_src2, a_dst2, alpha);
    u16* h2_hi = (u16*)bufPk;
    u16* h2_lo = (u16*)bufPk + (size_t)N * 2048;
    k_agg<0, true, true><<<N, 256, 0, stream>>>(row_ptr, col_src, alpha, l2pk, nullptr,
                                                b2, h2_hi, h2_lo, nullptr, 4, 512);

    // ---- layer 3 (H=1, C=512, mean over single head = identity, no ELU) ----
    k_wt_pack<<<dim3(512 / 32, 2048 / 32), 256, 0, stream>>>(W3, whi, wlo, 2048, 512);
    u16* l3f = (u16*)bufA_hi;   // [N,512] fp16 in region A
    k_gemm_pl<2, 2, true><<<dim3(512 / 64, MB1), 256, 0, stream>>>(
        h2_hi, h2_lo, whi, wlo, nullptr, nullptr, nullptr, nullptr, l3f,
        as3, ad3, a_src3, a_dst3, 1, N, 2048, 512);
    k_softmax<1><<<N, 64, 0, stream>>>(row_ptr, col_src, a_src3, a_dst3, alpha);
    k_agg<1, false, false><<<N, 64, 0, stream>>>(row_ptr, col_src, alpha, nullptr, l3f,
                                                 b3, nullptr, nullptr, (float*)d_out, 1, 512);
}

// Round 10
// 966.604 us; speedup vs baseline: 1.6310x; 1.0968x over previous
//
#include <hip/hip_runtime.h>
#include <hip/hip_bf16.h>

// ---------------------------------------------------------------------------
// GAT encoder, round 10: emulated-fp32 GEMM via hi/lo split bf16 MFMA
// (3 products: Ahi*Bhi + Ahi*Blo + Alo*Bhi, fp32 accum -> ~2^-17 relative).
// vs round-9 (passed, 1060us, absmax 0.25):
//  * layer-2 hop payload in fp16: GEMM2 C -> fp16 plane, agg2 gathers fp16.
//    Logits remain exact (fused epilogue); layer-1 payload remains exact
//    (packed u32) since its error passes two further amplification stages.
//  * everything else identical to round 9.
// ---------------------------------------------------------------------------

#define LB(x) __launch_bounds__(x)

typedef unsigned short u16;
typedef unsigned int u32;
typedef __attribute__((ext_vector_type(8))) short short8;
typedef __attribute__((ext_vector_type(8))) short bf16x8;
typedef __attribute__((ext_vector_type(4))) float f32x4;

__device__ __forceinline__ float b2f(u16 u) {
    union { float f; u32 u; } x;
    x.u = ((u32)u) << 16;
    return x.f;
}
__device__ __forceinline__ u16 f2b(float f) {
    u32 u = __float_as_uint(f);
    u = (u + 0x7FFFu + ((u >> 16) & 1u)) >> 16;   // RNE
    return (u16)u;
}
__device__ __forceinline__ float rec2(u32 p) {
    return b2f((u16)(p >> 16)) + b2f((u16)p);
}
__device__ __forceinline__ u16 f2h(float f) {
    union { _Float16 h; u16 u; } x;
    x.h = (_Float16)f;
    return x.u;
}
__device__ __forceinline__ float h2f(u16 u) {
    union { _Float16 h; u16 u; } x;
    x.u = u;
    return (float)x.h;
}
__device__ __forceinline__ void lds_cp16(const void* g, void* l) {
    __builtin_amdgcn_global_load_lds(
        (const __attribute__((address_space(1))) unsigned int*)g,
        (__attribute__((address_space(3))) unsigned int*)l, 16, 0, 0);
}

// ---------------- CSR build ----------------
__global__ void k_deg(const int* __restrict__ ei, int E, int Np, int* __restrict__ deg) {
    int e = blockIdx.x * blockDim.x + threadIdx.x;
    if (e >= E + Np) return;
    int dst = (e < E) ? ei[E + e] : (e - E);
    atomicAdd(&deg[dst], 1);
}

__global__ LB(256) void k_s1(const int* __restrict__ deg, int* __restrict__ row_ptr,
                             int* __restrict__ bsum, int n) {
    __shared__ int sh[256];
    int b = blockIdx.x, t = threadIdx.x;
    int i = b * 256 + t;
    int v = (i < n) ? deg[i] : 0;
    sh[t] = v;
    __syncthreads();
    #pragma unroll
    for (int off = 1; off < 256; off <<= 1) {
        int add = (t >= off) ? sh[t - off] : 0;
        __syncthreads();
        sh[t] += add;
        __syncthreads();
    }
    if (i < n) row_ptr[i + 1] = sh[t];
    if (t == 255) bsum[b] = sh[255];
}

__global__ LB(64) void k_s2(int* __restrict__ bsum, int* __restrict__ boff, int nb) {
    __shared__ int sh[64];
    int t = threadIdx.x;
    sh[t] = (t < nb) ? bsum[t] : 0;
    __syncthreads();
    #pragma unroll
    for (int off = 1; off < 64; off <<= 1) {
        int add = (t >= off) ? sh[t - off] : 0;
        __syncthreads();
        sh[t] += add;
        __syncthreads();
    }
    if (t < nb) boff[t] = (t == 0) ? 0 : sh[t - 1];
}

__global__ LB(256) void k_s3(const int* __restrict__ deg, int* __restrict__ row_ptr,
                             const int* __restrict__ boff, int* __restrict__ cursor, int n) {
    int b = blockIdx.x, t = threadIdx.x;
    int i = b * 256 + t;
    if (i == 0) row_ptr[0] = 0;
    if (i < n) {
        int inc = row_ptr[i + 1] + boff[b];
        row_ptr[i + 1] = inc;
        cursor[i] = inc - deg[i];
    }
}

__global__ void k_fill(const int* __restrict__ ei, int E, int Np,
                       int* __restrict__ cursor, int* __restrict__ col_src) {
    int e = blockIdx.x * blockDim.x + threadIdx.x;
    if (e >= E + Np) return;
    int src, dst;
    if (e < E) { src = ei[e]; dst = ei[E + e]; }
    else       { src = dst = e - E; }
    int pos = atomicAdd(&cursor[dst], 1);
    col_src[pos] = src;
}

// ---------------- fp32 -> hi/lo planes ----------------
__global__ void k_pack(const float* __restrict__ in, u16* __restrict__ hi,
                       u16* __restrict__ lo, int n4) {
    int i = blockIdx.x * blockDim.x + threadIdx.x;
    if (i >= n4) return;
    float4 v = ((const float4*)in)[i];
    ushort4 h, l;
    h.x = f2b(v.x); l.x = f2b(v.x - b2f(h.x));
    h.y = f2b(v.y); l.y = f2b(v.y - b2f(h.y));
    h.z = f2b(v.z); l.z = f2b(v.z - b2f(h.z));
    h.w = f2b(v.w); l.w = f2b(v.w - b2f(h.w));
    ((ushort4*)hi)[i] = h;
    ((ushort4*)lo)[i] = l;
}

// ---------------- weight transpose + split: Wt[n][k] planes ----------------
__global__ LB(256) void k_wt_pack(const float* __restrict__ W, u16* __restrict__ Whi,
                                  u16* __restrict__ Wlo, int K, int Nn) {
    __shared__ float sh[32][33];
    int n0 = blockIdx.x * 32, k0 = blockIdx.y * 32;
    int c = threadIdx.x & 31, r0 = threadIdx.x >> 5;
    #pragma unroll
    for (int r = r0; r < 32; r += 8)
        sh[r][c] = W[(size_t)(k0 + r) * Nn + n0 + c];
    __syncthreads();
    #pragma unroll
    for (int r = r0; r < 32; r += 8) {
        float v = sh[c][r];
        u16 hi = f2b(v);
        Whi[(size_t)(n0 + r) * K + k0 + c] = hi;
        Wlo[(size_t)(n0 + r) * K + k0 + c] = f2b(v - b2f(hi));
    }
}

// ---------------- split-plane MFMA GEMM: C = A[M,K] @ Bt[Nn,K]^T -----------
// Round-6 proven core: BM=128, BK=32, 4 waves (2x2), LDS XOR swizzle
// (row&7)<<4 with inverse-permuted global_load_lds source.
// NFR = B-frags/wave (4 -> BN=128; 2 -> BN=64).  OUTMODE: 0=hi/lo planes
// (+bias), 1=packed u32, 2=fp16.  ATT: fuse a_src/a_dst = h . att_{s,d}
// (exact fp32 from accumulator; 16-lane shuffle reduce + atomicAdd).
template<int NFR, int OUTMODE, bool ATT>
__global__ LB(256) void k_gemm_pl(const u16* __restrict__ Ahi, const u16* __restrict__ Alo,
                                  const u16* __restrict__ Bhi, const u16* __restrict__ Blo,
                                  const float* __restrict__ bias,
                                  u16* __restrict__ Chi, u16* __restrict__ Clo,
                                  u32* __restrict__ Cpk, u16* __restrict__ Cf16,
                                  const float* __restrict__ att_s, const float* __restrict__ att_d,
                                  float* __restrict__ a_src, float* __restrict__ a_dst,
                                  int HH, int M, int K, int Nn) {
    constexpr int BN = NFR * 32;
    __shared__ u16 AsHi[128 * 32], AsLo[128 * 32];
    __shared__ u16 BsHi[BN * 32], BsLo[BN * 32];
    const int tid  = threadIdx.x;
    const int lane = tid & 63;
    const int w    = tid >> 6;
    const int wr   = w >> 1;
    const int wc   = w & 1;
    const int row0 = blockIdx.y * 128;
    const int col0 = blockIdx.x * BN;
    const int ln15 = lane & 15;
    const int lq   = lane >> 4;

    f32x4 acc[4][NFR];
    #pragma unroll
    for (int m = 0; m < 4; ++m)
        #pragma unroll
        for (int n = 0; n < NFR; ++n) acc[m][n] = (f32x4){0.f, 0.f, 0.f, 0.f};

    for (int k0 = 0; k0 < K; k0 += 32) {
        // A planes: 512 16B-chunks each, 2 per thread per plane.
        #pragma unroll
        for (int i = 0; i < 2; ++i) {
            int c = i * 256 + tid;
            int r  = 2 * (c >> 3) + (((c >> 2) ^ (c >> 4)) & 1);   // inverse swizzle
            int kc = (c & 3) ^ (r & 3);
            int gra = row0 + r; if (gra >= M) gra = M - 1;          // tail clamp
            size_t ga = (size_t)gra * K + k0 + kc * 8;
            lds_cp16(Ahi + ga, (char*)AsHi + c * 16);
            lds_cp16(Alo + ga, (char*)AsLo + c * 16);
        }
        // B planes: BN*4 chunks each, NFR/2 per thread per plane.
        #pragma unroll
        for (int i = 0; i < NFR / 2; ++i) {
            int c = i * 256 + tid;
            int r  = 2 * (c >> 3) + (((c >> 2) ^ (c >> 4)) & 1);
            int kc = (c & 3) ^ (r & 3);
            size_t gb = (size_t)(col0 + r) * K + k0 + kc * 8;
            lds_cp16(Bhi + gb, (char*)BsHi + c * 16);
            lds_cp16(Blo + gb, (char*)BsLo + c * 16);
        }
        __syncthreads();
        bf16x8 ah[4], al[4], bh[NFR], bl[NFR];
        #pragma unroll
        for (int m = 0; m < 4; ++m) {
            int row = wr * 64 + m * 16 + ln15;
            int byo = (row * 64 + lq * 16) ^ ((row & 7) << 4);
            ah[m] = *(const bf16x8*)((const char*)AsHi + byo);
            al[m] = *(const bf16x8*)((const char*)AsLo + byo);
        }
        #pragma unroll
        for (int n = 0; n < NFR; ++n) {
            int row = wc * (NFR * 16) + n * 16 + ln15;
            int byo = (row * 64 + lq * 16) ^ ((row & 7) << 4);
            bh[n] = *(const bf16x8*)((const char*)BsHi + byo);
            bl[n] = *(const bf16x8*)((const char*)BsLo + byo);
        }
        #pragma unroll
        for (int m = 0; m < 4; ++m)
            #pragma unroll
            for (int n = 0; n < NFR; ++n) {
                acc[m][n] = __builtin_amdgcn_mfma_f32_16x16x32_bf16(al[m], bh[n], acc[m][n], 0, 0, 0);
                acc[m][n] = __builtin_amdgcn_mfma_f32_16x16x32_bf16(ah[m], bl[n], acc[m][n], 0, 0, 0);
                acc[m][n] = __builtin_amdgcn_mfma_f32_16x16x32_bf16(ah[m], bh[n], acc[m][n], 0, 0, 0);
            }
        __syncthreads();
    }

    // D: col = lane&15, row = (lane>>4)*4 + j  [m89/m91-verified]
    #pragma unroll
    for (int m = 0; m < 4; ++m) {
        #pragma unroll
        for (int n = 0; n < NFR; ++n) {
            int gc = col0 + wc * (NFR * 16) + n * 16 + ln15;
            float badd = (OUTMODE == 0 && bias) ? bias[gc] : 0.f;
            #pragma unroll
            for (int j = 0; j < 4; ++j) {
                int gr = row0 + wr * 64 + m * 16 + lq * 4 + j;
                if (gr < M) {
                    float v = acc[m][n][j] + badd;
                    size_t o = (size_t)gr * Nn + gc;
                    if (OUTMODE == 0) {
                        u16 hi = f2b(v);
                        Chi[o] = hi;
                        Clo[o] = f2b(v - b2f(hi));
                    } else if (OUTMODE == 1) {
                        u16 hi = f2b(v);
                        Cpk[o] = ((u32)hi << 16) | (u32)f2b(v - b2f(hi));
                    } else {
                        Cf16[o] = f2h(v);
                    }
                }
            }
        }
    }

    if (ATT) {
        // per-lane att coefficients for its NFR columns (att flat [H*C] = [Nn])
        float atts[NFR], attd[NFR];
        #pragma unroll
        for (int n = 0; n < NFR; ++n) {
            int gc = col0 + wc * (NFR * 16) + n * 16 + ln15;
            atts[n] = att_s[gc];
            attd[n] = att_d[gc];
        }
        const int head = (col0 + wc * (NFR * 16)) >> 9;   // /512, wave-uniform
        #pragma unroll
        for (int m = 0; m < 4; ++m) {
            #pragma unroll
            for (int j = 0; j < 4; ++j) {
                int gr = row0 + wr * 64 + m * 16 + lq * 4 + j;
                float s1 = 0.f, s2 = 0.f;
                #pragma unroll
                for (int n = 0; n < NFR; ++n) {
                    float v = acc[m][n][j];
                    s1 = fmaf(v, atts[n], s1);
                    s2 = fmaf(v, attd[n], s2);
                }
                #pragma unroll
                for (int off = 1; off < 16; off <<= 1) {
                    s1 += __shfl_xor(s1, off);
                    s2 += __shfl_xor(s2, off);
                }
                if (ln15 == 0 && gr < M) {
                    atomicAdd(&a_src[gr * HH + head], s1);
                    atomicAdd(&a_dst[gr * HH + head], s2);
                }
            }
        }
    }
}

// ---------------- fused segment softmax per dst (one wave) ----------------
template<int HH>
__global__ LB(64) void k_softmax(const int* __restrict__ row_ptr, const int* __restrict__ col_src,
                                 const float* __restrict__ a_src, const float* __restrict__ a_dst,
                                 float* __restrict__ alpha) {
    int d = blockIdx.x;
    int t = threadIdx.x;
    int s = row_ptr[d], eend = row_ptr[d + 1];
    int cnt = eend - s;
    float adh[HH];
    #pragma unroll
    for (int h = 0; h < HH; ++h) adh[h] = a_dst[d * HH + h];

    if (cnt <= 64) {
        bool act = t < cnt;
        float av[HH];
        #pragma unroll
        for (int h = 0; h < HH; ++h) av[h] = 0.f;
        if (act) {
            int src = col_src[s + t];
            if (HH == 4) {
                float4 q = ((const float4*)a_src)[src];
                av[0] = q.x; av[1] = q.y; av[2] = q.z; av[3] = q.w;
            } else {
                av[0] = a_src[src];
            }
        }
        float v[HH], m[HH], sum[HH];
        #pragma unroll
        for (int h = 0; h < HH; ++h) {
            float x = av[h] + adh[h];
            x = (x > 0.f) ? x : 0.2f * x;
            v[h] = act ? x : -1e30f;
            m[h] = v[h];
        }
        #pragma unroll
        for (int off = 32; off; off >>= 1)
            #pragma unroll
            for (int h = 0; h < HH; ++h) m[h] = fmaxf(m[h], __shfl_xor(m[h], off));
        #pragma unroll
        for (int h = 0; h < HH; ++h) {
            float e = act ? __expf(v[h] - m[h]) : 0.f;
            v[h] = e;
            sum[h] = e;
        }
        #pragma unroll
        for (int off = 32; off; off >>= 1)
            #pragma unroll
            for (int h = 0; h < HH; ++h) sum[h] += __shfl_xor(sum[h], off);
        if (act) {
            if (HH == 4) {
                float4 o;
                o.x = v[0] / sum[0]; o.y = v[1] / sum[1];
                o.z = v[2] / sum[2]; o.w = v[3] / sum[3];
                ((float4*)alpha)[s + t] = o;
            } else {
                alpha[s + t] = v[0] / sum[0];
            }
        }
        return;
    }

    // generic fallback (deg > 64): 3-pass recompute
    for (int h = 0; h < HH; ++h) {
        float m = -1e30f;
        for (int e = s + t; e < eend; e += 64) {
            float x = a_src[col_src[e] * HH + h] + adh[h];
            x = (x > 0.f) ? x : 0.2f * x;
            m = fmaxf(m, x);
        }
        #pragma unroll
        for (int off = 32; off; off >>= 1) m = fmaxf(m, __shfl_xor(m, off));
        float sum = 0.f;
        for (int e = s + t; e < eend; e += 64) {
            float x = a_src[col_src[e] * HH + h] + adh[h];
            x = (x > 0.f) ? x : 0.2f * x;
            sum += __expf(x - m);
        }
        #pragma unroll
        for (int off = 32; off; off >>= 1) sum += __shfl_xor(sum, off);
        float inv = 1.0f / sum;
        for (int e = s + t; e < eend; e += 64) {
            float x = a_src[col_src[e] * HH + h] + adh[h];
            x = (x > 0.f) ? x : 0.2f * x;
            alpha[e * HH + h] = __expf(x - m) * inv;
        }
    }
}

// ---------------- aggregate: out[d] = sum_e alpha[e,h]*h[src] (+bias,ELU) --
// HMODE 0: packed u32 h; HMODE 1: fp16 h. Output planes or fp32 final.
template <int HMODE, bool PLANES_OUT, bool ELU_>
__global__ LB(256) void k_agg(const int* __restrict__ row_ptr, const int* __restrict__ col_src,
                              const float* __restrict__ alpha,
                              const u32* __restrict__ h_pk, const u16* __restrict__ hf,
                              const float* __restrict__ bias,
                              u16* __restrict__ Ohi, u16* __restrict__ Olo,
                              float* __restrict__ Of, int H, int C) {
    int d = blockIdx.x;
    int tid = threadIdx.x;
    int F = H * C;
    int o = tid * 8;
    int h0 = o / C;   // wave-uniform for C=512
    float acc[8];
    #pragma unroll
    for (int j = 0; j < 8; ++j) acc[j] = 0.f;
    int s = row_ptr[d], eend = row_ptr[d + 1];
    for (int e = s; e < eend; ++e) {
        int src = col_src[e];
        float a = alpha[e * H + h0];
        if (HMODE == 0) {
            const uint4* hp = (const uint4*)(h_pk + (size_t)src * F + o);
            uint4 p0 = hp[0], p1 = hp[1];
            acc[0] = fmaf(a, rec2(p0.x), acc[0]);
            acc[1] = fmaf(a, rec2(p0.y), acc[1]);
            acc[2] = fmaf(a, rec2(p0.z), acc[2]);
            acc[3] = fmaf(a, rec2(p0.w), acc[3]);
            acc[4] = fmaf(a, rec2(p1.x), acc[4]);
            acc[5] = fmaf(a, rec2(p1.y), acc[5]);
            acc[6] = fmaf(a, rec2(p1.z), acc[6]);
            acc[7] = fmaf(a, rec2(p1.w), acc[7]);
        } else {
            short8 v = *(const short8*)(hf + (size_t)src * F + o);
            #pragma unroll
            for (int j = 0; j < 8; ++j)
                acc[j] = fmaf(a, h2f((u16)v[j]), acc[j]);
        }
    }
    #pragma unroll
    for (int j = 0; j < 8; ++j) {
        acc[j] += bias[o + j];
        if (ELU_) acc[j] = (acc[j] > 0.f) ? acc[j] : __expf(acc[j]) - 1.f;
    }
    if (PLANES_OUT) {
        bf16x8 rh, rl;
        #pragma unroll
        for (int j = 0; j < 8; ++j) {
            u16 hi = f2b(acc[j]);
            rh[j] = (short)hi;
            rl[j] = (short)f2b(acc[j] - b2f(hi));
        }
        *(bf16x8*)(Ohi + (size_t)d * F + o) = rh;
        *(bf16x8*)(Olo + (size_t)d * F + o) = rl;
    } else {
        float* po = Of + (size_t)d * F + o;
        #pragma unroll
        for (int j4 = 0; j4 < 2; ++j4) {
            float4 r;
            r.x = acc[j4 * 4 + 0]; r.y = acc[j4 * 4 + 1];
            r.z = acc[j4 * 4 + 2]; r.w = acc[j4 * 4 + 3];
            *(float4*)&po[j4 * 4] = r;
        }
    }
}

// ---------------------------------------------------------------------------
extern "C" void kernel_launch(void* const* d_in, const int* in_sizes, int n_in,
                              void* d_out, int out_size, void* d_ws, size_t ws_size,
                              hipStream_t stream) {
    const float* x      = (const float*)d_in[0];
    const int*   ei     = (const int*)d_in[1];
    const float* proj_W = (const float*)d_in[2];
    const float* proj_b = (const float*)d_in[3];
    const float* W1  = (const float*)d_in[4];
    const float* as1 = (const float*)d_in[5];
    const float* ad1 = (const float*)d_in[6];
    const float* b1  = (const float*)d_in[7];
    const float* W2  = (const float*)d_in[8];
    const float* as2 = (const float*)d_in[9];
    const float* ad2 = (const float*)d_in[10];
    const float* b2  = (const float*)d_in[11];
    const float* W3  = (const float*)d_in[12];
    const float* as3 = (const float*)d_in[13];
    const float* ad3 = (const float*)d_in[14];
    const float* b3  = (const float*)d_in[15];

    const int N  = in_sizes[0] / 256;   // 10000
    const int E  = in_sizes[1] / 2;     // 160000
    const int Ep = E + N;
    const int NB = (N + 255) / 256;     // 40 scan blocks

    size_t off = 0;
    auto alloc = [&](size_t bytes) -> void* {
        void* p = (char*)d_ws + off;
        off += (bytes + 255) & ~(size_t)255;
        return p;
    };
    u16* bufA_hi = (u16*)alloc((size_t)N * 2048 * 2);   // region A (80 MB)
    u16* bufA_lo = (u16*)alloc((size_t)N * 2048 * 2);
    u32* bufPk   = (u32*)alloc((size_t)N * 2048 * 4);   // region B (80 MB)
    u16* xb_hi   = (u16*)alloc((size_t)N * 256 * 2);
    u16* xb_lo   = (u16*)alloc((size_t)N * 256 * 2);
    float* att_z   = (float*)alloc((size_t)N * 18 * 4); // a_src/a_dst x3 layers
    float* alpha   = (float*)alloc((size_t)Ep * 4 * 4);
    int*   deg     = (int*)alloc((size_t)N * 4);
    int*   cursor  = (int*)alloc((size_t)N * 4);
    int*   row_ptr = (int*)alloc((size_t)(N + 1) * 4);
    int*   col_src = (int*)alloc((size_t)Ep * 4);
    int*   bsum    = (int*)alloc((size_t)NB * 4);
    int*   boff    = (int*)alloc((size_t)NB * 4);
    (void)ws_size;

    float* a_src1 = att_z;
    float* a_dst1 = att_z + (size_t)N * 4;
    float* a_src2 = att_z + (size_t)N * 8;
    float* a_dst2 = att_z + (size_t)N * 12;
    float* a_src3 = att_z + (size_t)N * 16;
    float* a_dst3 = att_z + (size_t)N * 17;

    // JIT weight planes in d_out (16.78 MB <= 20.48 MB); fully overwritten
    // by the final aggregate afterwards.
    u16* whi = (u16*)d_out;
    u16* wlo = (u16*)d_out + (size_t)2048 * 2048;

    // ---- CSR build + zero att accumulators ----
    hipMemsetAsync(deg, 0, (size_t)N * 4, stream);
    hipMemsetAsync(att_z, 0, (size_t)N * 18 * 4, stream);
    int eb = (Ep + 255) / 256;
    k_deg<<<eb, 256, 0, stream>>>(ei, E, N, deg);
    k_s1<<<NB, 256, 0, stream>>>(deg, row_ptr, bsum, N);
    k_s2<<<1, 64, 0, stream>>>(bsum, boff, NB);
    k_s3<<<NB, 256, 0, stream>>>(deg, row_ptr, boff, cursor, N);
    k_fill<<<eb, 256, 0, stream>>>(ei, E, N, cursor, col_src);

    const int MB1 = (N + 127) / 128;  // 79

    // ---- pack x into planes [N,256] ----
    k_pack<<<(N * 256 / 4 + 255) / 256, 256, 0, stream>>>(x, xb_hi, xb_lo, N * 256 / 4);

    // ---- proj: x planes -> proj planes (bufPk space), BN=64, +bias ----
    u16* proj_hi = (u16*)bufPk;                       // [N,512] u16
    u16* proj_lo = (u16*)bufPk + (size_t)N * 512;
    k_wt_pack<<<dim3(512 / 32, 256 / 32), 256, 0, stream>>>(proj_W, whi, wlo, 256, 512);
    k_gemm_pl<2, 0, false><<<dim3(512 / 64, MB1), 256, 0, stream>>>(
        xb_hi, xb_lo, whi, wlo, proj_b, proj_hi, proj_lo, nullptr, nullptr,
        nullptr, nullptr, nullptr, nullptr, 0, N, 256, 512);

    // ---- layer 1 (H=4, C=512, concat, ELU): exact packed payload ----
    k_wt_pack<<<dim3(2048 / 32, 512 / 32), 256, 0, stream>>>(W1, whi, wlo, 512, 2048);
    u32* l1pk = (u32*)bufA_hi;   // [N,2048] u32 spans region A
    k_gemm_pl<4, 1, true><<<dim3(2048 / 128, MB1), 256, 0, stream>>>(
        proj_hi, proj_lo, whi, wlo, nullptr, nullptr, nullptr, l1pk, nullptr,
        as1, ad1, a_src1, a_dst1, 4, N, 512, 2048);
    k_softmax<4><<<N, 64, 0, stream>>>(row_ptr, col_src, a_src1, a_dst1, alpha);
    u16* h1_hi = (u16*)bufPk;                         // planes in region B
    u16* h1_lo = (u16*)bufPk + (size_t)N * 2048;
    k_agg<0, true, true><<<N, 256, 0, stream>>>(row_ptr, col_src, alpha, l1pk, nullptr,
                                                b1, h1_hi, h1_lo, nullptr, 4, 512);

    // ---- layer 2 (H=4, C=512, concat, ELU): fp16 payload, exact logits ----
    k_wt_pack<<<dim3(2048 / 32, 2048 / 32), 256, 0, stream>>>(W2, whi, wlo, 2048, 2048);
    u16* l2f = (u16*)bufA_hi;    // [N,2048] fp16 in region A (40 MB)
    k_gemm_pl<4, 2, true><<<dim3(2048 / 128, MB1), 256, 0, stream>>>(
        h1_hi, h1_lo, whi, wlo, nullptr, nullptr, nullptr, nullptr, l2f,
        as2, ad2, a_src2, a_dst2, 4, N, 2048, 2048);
    k_softmax<4><<<N, 64, 0, stream>>>(row_ptr, col_src, a_src2, a_dst2, alpha);
    u16* h2_hi = (u16*)bufPk;
    u16* h2_lo = (u16*)bufPk + (size_t)N * 2048;
    k_agg<1, true, true><<<N, 256, 0, stream>>>(row_ptr, col_src, alpha, nullptr, l2f,
                                                b2, h2_hi, h2_lo, nullptr, 4, 512);

    // ---- layer 3 (H=1, C=512, mean over single head = identity, no ELU) ----
    k_wt_pack<<<dim3(512 / 32, 2048 / 32), 256, 0, stream>>>(W3, whi, wlo, 2048, 512);
    u16* l3f = (u16*)bufA_hi;   // [N,512] fp16 in region A
    k_gemm_pl<2, 2, true><<<dim3(512 / 64, MB1), 256, 0, stream>>>(
        h2_hi, h2_lo, whi, wlo, nullptr, nullptr, nullptr, nullptr, l3f,
        as3, ad3, a_src3, a_dst3, 1, N, 2048, 512);
    k_softmax<1><<<N, 64, 0, stream>>>(row_ptr, col_src, a_src3, a_dst3, alpha);
    k_agg<1, false, false><<<N, 64, 0, stream>>>(row_ptr, col_src, alpha, nullptr, l3f,
                                                 b3, nullptr, nullptr, (float*)d_out, 1, 512);
}

// Round 11
// 944.005 us; speedup vs baseline: 1.6700x; 1.0239x over previous
//
#include <hip/hip_runtime.h>
#include <hip/hip_bf16.h>

// ---------------------------------------------------------------------------
// GAT encoder, round 11: emulated-fp32 GEMM via hi/lo split bf16 MFMA
// (3 products: Ahi*Bhi + Ahi*Blo + Alo*Bhi, fp32 accum -> ~2^-17 relative).
// vs round-10 (passed, 966us, absmax 0.25):
//  * XCD-contiguous block remap on all GEMMs: wi=(flat%8)*(nwg/8)+flat/8
//    (bijective; nwg%8==0 for all grids). Each XCD runs contiguous row-
//    stripes with col-blocks adjacent in time -> A-stripe L2-resident,
//    FETCH amplification (345MB vs 97MB ideal) should collapse.
//  * k_agg: depth-1 software pipeline (prefetch next col_src/alpha/h-row);
//    single accumulator -> FP order identical, bit-identical results.
// ---------------------------------------------------------------------------

#define LB(x) __launch_bounds__(x)

typedef unsigned short u16;
typedef unsigned int u32;
typedef __attribute__((ext_vector_type(8))) short short8;
typedef __attribute__((ext_vector_type(8))) short bf16x8;
typedef __attribute__((ext_vector_type(4))) float f32x4;

__device__ __forceinline__ float b2f(u16 u) {
    union { float f; u32 u; } x;
    x.u = ((u32)u) << 16;
    return x.f;
}
__device__ __forceinline__ u16 f2b(float f) {
    u32 u = __float_as_uint(f);
    u = (u + 0x7FFFu + ((u >> 16) & 1u)) >> 16;   // RNE
    return (u16)u;
}
__device__ __forceinline__ float rec2(u32 p) {
    return b2f((u16)(p >> 16)) + b2f((u16)p);
}
__device__ __forceinline__ u16 f2h(float f) {
    union { _Float16 h; u16 u; } x;
    x.h = (_Float16)f;
    return x.u;
}
__device__ __forceinline__ float h2f(u16 u) {
    union { _Float16 h; u16 u; } x;
    x.u = u;
    return (float)x.h;
}
__device__ __forceinline__ void lds_cp16(const void* g, void* l) {
    __builtin_amdgcn_global_load_lds(
        (const __attribute__((address_space(1))) unsigned int*)g,
        (__attribute__((address_space(3))) unsigned int*)l, 16, 0, 0);
}

// ---------------- CSR build ----------------
__global__ void k_deg(const int* __restrict__ ei, int E, int Np, int* __restrict__ deg) {
    int e = blockIdx.x * blockDim.x + threadIdx.x;
    if (e >= E + Np) return;
    int dst = (e < E) ? ei[E + e] : (e - E);
    atomicAdd(&deg[dst], 1);
}

__global__ LB(256) void k_s1(const int* __restrict__ deg, int* __restrict__ row_ptr,
                             int* __restrict__ bsum, int n) {
    __shared__ int sh[256];
    int b = blockIdx.x, t = threadIdx.x;
    int i = b * 256 + t;
    int v = (i < n) ? deg[i] : 0;
    sh[t] = v;
    __syncthreads();
    #pragma unroll
    for (int off = 1; off < 256; off <<= 1) {
        int add = (t >= off) ? sh[t - off] : 0;
        __syncthreads();
        sh[t] += add;
        __syncthreads();
    }
    if (i < n) row_ptr[i + 1] = sh[t];
    if (t == 255) bsum[b] = sh[255];
}

__global__ LB(64) void k_s2(int* __restrict__ bsum, int* __restrict__ boff, int nb) {
    __shared__ int sh[64];
    int t = threadIdx.x;
    sh[t] = (t < nb) ? bsum[t] : 0;
    __syncthreads();
    #pragma unroll
    for (int off = 1; off < 64; off <<= 1) {
        int add = (t >= off) ? sh[t - off] : 0;
        __syncthreads();
        sh[t] += add;
        __syncthreads();
    }
    if (t < nb) boff[t] = (t == 0) ? 0 : sh[t - 1];
}

__global__ LB(256) void k_s3(const int* __restrict__ deg, int* __restrict__ row_ptr,
                             const int* __restrict__ boff, int* __restrict__ cursor, int n) {
    int b = blockIdx.x, t = threadIdx.x;
    int i = b * 256 + t;
    if (i == 0) row_ptr[0] = 0;
    if (i < n) {
        int inc = row_ptr[i + 1] + boff[b];
        row_ptr[i + 1] = inc;
        cursor[i] = inc - deg[i];
    }
}

__global__ void k_fill(const int* __restrict__ ei, int E, int Np,
                       int* __restrict__ cursor, int* __restrict__ col_src) {
    int e = blockIdx.x * blockDim.x + threadIdx.x;
    if (e >= E + Np) return;
    int src, dst;
    if (e < E) { src = ei[e]; dst = ei[E + e]; }
    else       { src = dst = e - E; }
    int pos = atomicAdd(&cursor[dst], 1);
    col_src[pos] = src;
}

// ---------------- fp32 -> hi/lo planes ----------------
__global__ void k_pack(const float* __restrict__ in, u16* __restrict__ hi,
                       u16* __restrict__ lo, int n4) {
    int i = blockIdx.x * blockDim.x + threadIdx.x;
    if (i >= n4) return;
    float4 v = ((const float4*)in)[i];
    ushort4 h, l;
    h.x = f2b(v.x); l.x = f2b(v.x - b2f(h.x));
    h.y = f2b(v.y); l.y = f2b(v.y - b2f(h.y));
    h.z = f2b(v.z); l.z = f2b(v.z - b2f(h.z));
    h.w = f2b(v.w); l.w = f2b(v.w - b2f(h.w));
    ((ushort4*)hi)[i] = h;
    ((ushort4*)lo)[i] = l;
}

// ---------------- weight transpose + split: Wt[n][k] planes ----------------
__global__ LB(256) void k_wt_pack(const float* __restrict__ W, u16* __restrict__ Whi,
                                  u16* __restrict__ Wlo, int K, int Nn) {
    __shared__ float sh[32][33];
    int n0 = blockIdx.x * 32, k0 = blockIdx.y * 32;
    int c = threadIdx.x & 31, r0 = threadIdx.x >> 5;
    #pragma unroll
    for (int r = r0; r < 32; r += 8)
        sh[r][c] = W[(size_t)(k0 + r) * Nn + n0 + c];
    __syncthreads();
    #pragma unroll
    for (int r = r0; r < 32; r += 8) {
        float v = sh[c][r];
        u16 hi = f2b(v);
        Whi[(size_t)(n0 + r) * K + k0 + c] = hi;
        Wlo[(size_t)(n0 + r) * K + k0 + c] = f2b(v - b2f(hi));
    }
}

// ---------------- split-plane MFMA GEMM: C = A[M,K] @ Bt[Nn,K]^T -----------
// Round-6 proven core: BM=128, BK=32, 4 waves (2x2), LDS XOR swizzle
// (row&7)<<4 with inverse-permuted global_load_lds source.
// XCD-contiguous block remap: each XCD gets a contiguous chunk of the
// (by-major) work list -> A-stripes become L2-resident per XCD.
// NFR = B-frags/wave (4 -> BN=128; 2 -> BN=64).  OUTMODE: 0=hi/lo planes
// (+bias), 1=packed u32, 2=fp16.  ATT: fuse a_src/a_dst = h . att_{s,d}.
template<int NFR, int OUTMODE, bool ATT>
__global__ LB(256) void k_gemm_pl(const u16* __restrict__ Ahi, const u16* __restrict__ Alo,
                                  const u16* __restrict__ Bhi, const u16* __restrict__ Blo,
                                  const float* __restrict__ bias,
                                  u16* __restrict__ Chi, u16* __restrict__ Clo,
                                  u32* __restrict__ Cpk, u16* __restrict__ Cf16,
                                  const float* __restrict__ att_s, const float* __restrict__ att_d,
                                  float* __restrict__ a_src, float* __restrict__ a_dst,
                                  int HH, int M, int K, int Nn) {
    constexpr int BN = NFR * 32;
    __shared__ u16 AsHi[128 * 32], AsLo[128 * 32];
    __shared__ u16 BsHi[BN * 32], BsLo[BN * 32];
    const int tid  = threadIdx.x;
    const int lane = tid & 63;
    const int w    = tid >> 6;
    const int wr   = w >> 1;
    const int wc   = w & 1;
    // XCD-contiguous remap (nwg % 8 == 0 for all our grids)
    const int gx   = gridDim.x;
    const int flat = blockIdx.y * gx + blockIdx.x;    // dispatch order, x fastest
    const int per  = (gx * gridDim.y) >> 3;
    const int wi   = (flat & 7) * per + (flat >> 3);
    const int row0 = (wi / gx) * 128;
    const int col0 = (wi % gx) * BN;
    const int ln15 = lane & 15;
    const int lq   = lane >> 4;

    f32x4 acc[4][NFR];
    #pragma unroll
    for (int m = 0; m < 4; ++m)
        #pragma unroll
        for (int n = 0; n < NFR; ++n) acc[m][n] = (f32x4){0.f, 0.f, 0.f, 0.f};

    for (int k0 = 0; k0 < K; k0 += 32) {
        // A planes: 512 16B-chunks each, 2 per thread per plane.
        #pragma unroll
        for (int i = 0; i < 2; ++i) {
            int c = i * 256 + tid;
            int r  = 2 * (c >> 3) + (((c >> 2) ^ (c >> 4)) & 1);   // inverse swizzle
            int kc = (c & 3) ^ (r & 3);
            int gra = row0 + r; if (gra >= M) gra = M - 1;          // tail clamp
            size_t ga = (size_t)gra * K + k0 + kc * 8;
            lds_cp16(Ahi + ga, (char*)AsHi + c * 16);
            lds_cp16(Alo + ga, (char*)AsLo + c * 16);
        }
        // B planes: BN*4 chunks each, NFR/2 per thread per plane.
        #pragma unroll
        for (int i = 0; i < NFR / 2; ++i) {
            int c = i * 256 + tid;
            int r  = 2 * (c >> 3) + (((c >> 2) ^ (c >> 4)) & 1);
            int kc = (c & 3) ^ (r & 3);
            size_t gb = (size_t)(col0 + r) * K + k0 + kc * 8;
            lds_cp16(Bhi + gb, (char*)BsHi + c * 16);
            lds_cp16(Blo + gb, (char*)BsLo + c * 16);
        }
        __syncthreads();
        bf16x8 ah[4], al[4], bh[NFR], bl[NFR];
        #pragma unroll
        for (int m = 0; m < 4; ++m) {
            int row = wr * 64 + m * 16 + ln15;
            int byo = (row * 64 + lq * 16) ^ ((row & 7) << 4);
            ah[m] = *(const bf16x8*)((const char*)AsHi + byo);
            al[m] = *(const bf16x8*)((const char*)AsLo + byo);
        }
        #pragma unroll
        for (int n = 0; n < NFR; ++n) {
            int row = wc * (NFR * 16) + n * 16 + ln15;
            int byo = (row * 64 + lq * 16) ^ ((row & 7) << 4);
            bh[n] = *(const bf16x8*)((const char*)BsHi + byo);
            bl[n] = *(const bf16x8*)((const char*)BsLo + byo);
        }
        #pragma unroll
        for (int m = 0; m < 4; ++m)
            #pragma unroll
            for (int n = 0; n < NFR; ++n) {
                acc[m][n] = __builtin_amdgcn_mfma_f32_16x16x32_bf16(al[m], bh[n], acc[m][n], 0, 0, 0);
                acc[m][n] = __builtin_amdgcn_mfma_f32_16x16x32_bf16(ah[m], bl[n], acc[m][n], 0, 0, 0);
                acc[m][n] = __builtin_amdgcn_mfma_f32_16x16x32_bf16(ah[m], bh[n], acc[m][n], 0, 0, 0);
            }
        __syncthreads();
    }

    // D: col = lane&15, row = (lane>>4)*4 + j  [m89/m91-verified]
    #pragma unroll
    for (int m = 0; m < 4; ++m) {
        #pragma unroll
        for (int n = 0; n < NFR; ++n) {
            int gc = col0 + wc * (NFR * 16) + n * 16 + ln15;
            float badd = (OUTMODE == 0 && bias) ? bias[gc] : 0.f;
            #pragma unroll
            for (int j = 0; j < 4; ++j) {
                int gr = row0 + wr * 64 + m * 16 + lq * 4 + j;
                if (gr < M) {
                    float v = acc[m][n][j] + badd;
                    size_t o = (size_t)gr * Nn + gc;
                    if (OUTMODE == 0) {
                        u16 hi = f2b(v);
                        Chi[o] = hi;
                        Clo[o] = f2b(v - b2f(hi));
                    } else if (OUTMODE == 1) {
                        u16 hi = f2b(v);
                        Cpk[o] = ((u32)hi << 16) | (u32)f2b(v - b2f(hi));
                    } else {
                        Cf16[o] = f2h(v);
                    }
                }
            }
        }
    }

    if (ATT) {
        float atts[NFR], attd[NFR];
        #pragma unroll
        for (int n = 0; n < NFR; ++n) {
            int gc = col0 + wc * (NFR * 16) + n * 16 + ln15;
            atts[n] = att_s[gc];
            attd[n] = att_d[gc];
        }
        const int head = (col0 + wc * (NFR * 16)) >> 9;   // /512, wave-uniform
        #pragma unroll
        for (int m = 0; m < 4; ++m) {
            #pragma unroll
            for (int j = 0; j < 4; ++j) {
                int gr = row0 + wr * 64 + m * 16 + lq * 4 + j;
                float s1 = 0.f, s2 = 0.f;
                #pragma unroll
                for (int n = 0; n < NFR; ++n) {
                    float v = acc[m][n][j];
                    s1 = fmaf(v, atts[n], s1);
                    s2 = fmaf(v, attd[n], s2);
                }
                #pragma unroll
                for (int off = 1; off < 16; off <<= 1) {
                    s1 += __shfl_xor(s1, off);
                    s2 += __shfl_xor(s2, off);
                }
                if (ln15 == 0 && gr < M) {
                    atomicAdd(&a_src[gr * HH + head], s1);
                    atomicAdd(&a_dst[gr * HH + head], s2);
                }
            }
        }
    }
}

// ---------------- fused segment softmax per dst (one wave) ----------------
template<int HH>
__global__ LB(64) void k_softmax(const int* __restrict__ row_ptr, const int* __restrict__ col_src,
                                 const float* __restrict__ a_src, const float* __restrict__ a_dst,
                                 float* __restrict__ alpha) {
    int d = blockIdx.x;
    int t = threadIdx.x;
    int s = row_ptr[d], eend = row_ptr[d + 1];
    int cnt = eend - s;
    float adh[HH];
    #pragma unroll
    for (int h = 0; h < HH; ++h) adh[h] = a_dst[d * HH + h];

    if (cnt <= 64) {
        bool act = t < cnt;
        float av[HH];
        #pragma unroll
        for (int h = 0; h < HH; ++h) av[h] = 0.f;
        if (act) {
            int src = col_src[s + t];
            if (HH == 4) {
                float4 q = ((const float4*)a_src)[src];
                av[0] = q.x; av[1] = q.y; av[2] = q.z; av[3] = q.w;
            } else {
                av[0] = a_src[src];
            }
        }
        float v[HH], m[HH], sum[HH];
        #pragma unroll
        for (int h = 0; h < HH; ++h) {
            float x = av[h] + adh[h];
            x = (x > 0.f) ? x : 0.2f * x;
            v[h] = act ? x : -1e30f;
            m[h] = v[h];
        }
        #pragma unroll
        for (int off = 32; off; off >>= 1)
            #pragma unroll
            for (int h = 0; h < HH; ++h) m[h] = fmaxf(m[h], __shfl_xor(m[h], off));
        #pragma unroll
        for (int h = 0; h < HH; ++h) {
            float e = act ? __expf(v[h] - m[h]) : 0.f;
            v[h] = e;
            sum[h] = e;
        }
        #pragma unroll
        for (int off = 32; off; off >>= 1)
            #pragma unroll
            for (int h = 0; h < HH; ++h) sum[h] += __shfl_xor(sum[h], off);
        if (act) {
            if (HH == 4) {
                float4 o;
                o.x = v[0] / sum[0]; o.y = v[1] / sum[1];
                o.z = v[2] / sum[2]; o.w = v[3] / sum[3];
                ((float4*)alpha)[s + t] = o;
            } else {
                alpha[s + t] = v[0] / sum[0];
            }
        }
        return;
    }

    // generic fallback (deg > 64): 3-pass recompute
    for (int h = 0; h < HH; ++h) {
        float m = -1e30f;
        for (int e = s + t; e < eend; e += 64) {
            float x = a_src[col_src[e] * HH + h] + adh[h];
            x = (x > 0.f) ? x : 0.2f * x;
            m = fmaxf(m, x);
        }
        #pragma unroll
        for (int off = 32; off; off >>= 1) m = fmaxf(m, __shfl_xor(m, off));
        float sum = 0.f;
        for (int e = s + t; e < eend; e += 64) {
            float x = a_src[col_src[e] * HH + h] + adh[h];
            x = (x > 0.f) ? x : 0.2f * x;
            sum += __expf(x - m);
        }
        #pragma unroll
        for (int off = 32; off; off >>= 1) sum += __shfl_xor(sum, off);
        float inv = 1.0f / sum;
        for (int e = s + t; e < eend; e += 64) {
            float x = a_src[col_src[e] * HH + h] + adh[h];
            x = (x > 0.f) ? x : 0.2f * x;
            alpha[e * HH + h] = __expf(x - m) * inv;
        }
    }
}

// ---------------- aggregate: out[d] = sum_e alpha[e,h]*h[src] (+bias,ELU) --
// HMODE 0: packed u32 h; HMODE 1: fp16 h. Depth-1 software pipeline
// (prefetch next edge's index/alpha/h-row); single accumulator -> FP order
// identical to the plain loop. Output planes or fp32 final.
template <int HMODE, bool PLANES_OUT, bool ELU_>
__global__ LB(256) void k_agg(const int* __restrict__ row_ptr, const int* __restrict__ col_src,
                              const float* __restrict__ alpha,
                              const u32* __restrict__ h_pk, const u16* __restrict__ hf,
                              const float* __restrict__ bias,
                              u16* __restrict__ Ohi, u16* __restrict__ Olo,
                              float* __restrict__ Of, int H, int C) {
    int d = blockIdx.x;
    int tid = threadIdx.x;
    int F = H * C;
    int o = tid * 8;
    int h0 = o / C;   // wave-uniform for C=512
    float acc[8];
    #pragma unroll
    for (int j = 0; j < 8; ++j) acc[j] = 0.f;
    int s = row_ptr[d], eend = row_ptr[d + 1];

    uint4 p0, p1; short8 v;
    float a;
    if (s < eend) {
        int src = col_src[s];
        a = alpha[s * H + h0];
        if (HMODE == 0) {
            const uint4* hp = (const uint4*)(h_pk + (size_t)src * F + o);
            p0 = hp[0]; p1 = hp[1];
        } else {
            v = *(const short8*)(hf + (size_t)src * F + o);
        }
    }
    for (int e = s; e < eend; ++e) {
        uint4 q0, q1; short8 w_; float an;
        bool more = (e + 1 < eend);           // block-uniform branch
        if (more) {
            int srcn = col_src[e + 1];
            an = alpha[(e + 1) * H + h0];
            if (HMODE == 0) {
                const uint4* hp = (const uint4*)(h_pk + (size_t)srcn * F + o);
                q0 = hp[0]; q1 = hp[1];
            } else {
                w_ = *(const short8*)(hf + (size_t)srcn * F + o);
            }
        }
        if (HMODE == 0) {
            acc[0] = fmaf(a, rec2(p0.x), acc[0]);
            acc[1] = fmaf(a, rec2(p0.y), acc[1]);
            acc[2] = fmaf(a, rec2(p0.z), acc[2]);
            acc[3] = fmaf(a, rec2(p0.w), acc[3]);
            acc[4] = fmaf(a, rec2(p1.x), acc[4]);
            acc[5] = fmaf(a, rec2(p1.y), acc[5]);
            acc[6] = fmaf(a, rec2(p1.z), acc[6]);
            acc[7] = fmaf(a, rec2(p1.w), acc[7]);
        } else {
            #pragma unroll
            for (int j = 0; j < 8; ++j)
                acc[j] = fmaf(a, h2f((u16)v[j]), acc[j]);
        }
        if (more) { a = an; p0 = q0; p1 = q1; v = w_; }
    }

    #pragma unroll
    for (int j = 0; j < 8; ++j) {
        acc[j] += bias[o + j];
        if (ELU_) acc[j] = (acc[j] > 0.f) ? acc[j] : __expf(acc[j]) - 1.f;
    }
    if (PLANES_OUT) {
        bf16x8 rh, rl;
        #pragma unroll
        for (int j = 0; j < 8; ++j) {
            u16 hi = f2b(acc[j]);
            rh[j] = (short)hi;
            rl[j] = (short)f2b(acc[j] - b2f(hi));
        }
        *(bf16x8*)(Ohi + (size_t)d * F + o) = rh;
        *(bf16x8*)(Olo + (size_t)d * F + o) = rl;
    } else {
        float* po = Of + (size_t)d * F + o;
        #pragma unroll
        for (int j4 = 0; j4 < 2; ++j4) {
            float4 r;
            r.x = acc[j4 * 4 + 0]; r.y = acc[j4 * 4 + 1];
            r.z = acc[j4 * 4 + 2]; r.w = acc[j4 * 4 + 3];
            *(float4*)&po[j4 * 4] = r;
        }
    }
}

// ---------------------------------------------------------------------------
extern "C" void kernel_launch(void* const* d_in, const int* in_sizes, int n_in,
                              void* d_out, int out_size, void* d_ws, size_t ws_size,
                              hipStream_t stream) {
    const float* x      = (const float*)d_in[0];
    const int*   ei     = (const int*)d_in[1];
    const float* proj_W = (const float*)d_in[2];
    const float* proj_b = (const float*)d_in[3];
    const float* W1  = (const float*)d_in[4];
    const float* as1 = (const float*)d_in[5];
    const float* ad1 = (const float*)d_in[6];
    const float* b1  = (const float*)d_in[7];
    const float* W2  = (const float*)d_in[8];
    const float* as2 = (const float*)d_in[9];
    const float* ad2 = (const float*)d_in[10];
    const float* b2  = (const float*)d_in[11];
    const float* W3  = (const float*)d_in[12];
    const float* as3 = (const float*)d_in[13];
    const float* ad3 = (const float*)d_in[14];
    const float* b3  = (const float*)d_in[15];

    const int N  = in_sizes[0] / 256;   // 10000
    const int E  = in_sizes[1] / 2;     // 160000
    const int Ep = E + N;
    const int NB = (N + 255) / 256;     // 40 scan blocks

    size_t off = 0;
    auto alloc = [&](size_t bytes) -> void* {
        void* p = (char*)d_ws + off;
        off += (bytes + 255) & ~(size_t)255;
        return p;
    };
    u16* bufA_hi = (u16*)alloc((size_t)N * 2048 * 2);   // region A (80 MB)
    u16* bufA_lo = (u16*)alloc((size_t)N * 2048 * 2);
    u32* bufPk   = (u32*)alloc((size_t)N * 2048 * 4);   // region B (80 MB)
    u16* xb_hi   = (u16*)alloc((size_t)N * 256 * 2);
    u16* xb_lo   = (u16*)alloc((size_t)N * 256 * 2);
    float* att_z   = (float*)alloc((size_t)N * 18 * 4); // a_src/a_dst x3 layers
    float* alpha   = (float*)alloc((size_t)Ep * 4 * 4);
    int*   deg     = (int*)alloc((size_t)N * 4);
    int*   cursor  = (int*)alloc((size_t)N * 4);
    int*   row_ptr = (int*)alloc((size_t)(N + 1) * 4);
    int*   col_src = (int*)alloc((size_t)Ep * 4);
    int*   bsum    = (int*)alloc((size_t)NB * 4);
    int*   boff    = (int*)alloc((size_t)NB * 4);
    (void)ws_size;

    float* a_src1 = att_z;
    float* a_dst1 = att_z + (size_t)N * 4;
    float* a_src2 = att_z + (size_t)N * 8;
    float* a_dst2 = att_z + (size_t)N * 12;
    float* a_src3 = att_z + (size_t)N * 16;
    float* a_dst3 = att_z + (size_t)N * 17;

    // JIT weight planes in d_out (16.78 MB <= 20.48 MB); fully overwritten
    // by the final aggregate afterwards.
    u16* whi = (u16*)d_out;
    u16* wlo = (u16*)d_out + (size_t)2048 * 2048;

    // ---- CSR build + zero att accumulators ----
    hipMemsetAsync(deg, 0, (size_t)N * 4, stream);
    hipMemsetAsync(att_z, 0, (size_t)N * 18 * 4, stream);
    int eb = (Ep + 255) / 256;
    k_deg<<<eb, 256, 0, stream>>>(ei, E, N, deg);
    k_s1<<<NB, 256, 0, stream>>>(deg, row_ptr, bsum, N);
    k_s2<<<1, 64, 0, stream>>>(bsum, boff, NB);
    k_s3<<<NB, 256, 0, stream>>>(deg, row_ptr, boff, cursor, N);
    k_fill<<<eb, 256, 0, stream>>>(ei, E, N, cursor, col_src);

    const int MB1 = (N + 127) / 128;  // 79

    // ---- pack x into planes [N,256] ----
    k_pack<<<(N * 256 / 4 + 255) / 256, 256, 0, stream>>>(x, xb_hi, xb_lo, N * 256 / 4);

    // ---- proj: x planes -> proj planes (bufPk space), BN=64, +bias ----
    u16* proj_hi = (u16*)bufPk;                       // [N,512] u16
    u16* proj_lo = (u16*)bufPk + (size_t)N * 512;
    k_wt_pack<<<dim3(512 / 32, 256 / 32), 256, 0, stream>>>(proj_W, whi, wlo, 256, 512);
    k_gemm_pl<2, 0, false><<<dim3(512 / 64, MB1), 256, 0, stream>>>(
        xb_hi, xb_lo, whi, wlo, proj_b, proj_hi, proj_lo, nullptr, nullptr,
        nullptr, nullptr, nullptr, nullptr, 0, N, 256, 512);

    // ---- layer 1 (H=4, C=512, concat, ELU): exact packed payload ----
    k_wt_pack<<<dim3(2048 / 32, 512 / 32), 256, 0, stream>>>(W1, whi, wlo, 512, 2048);
    u32* l1pk = (u32*)bufA_hi;   // [N,2048] u32 spans region A
    k_gemm_pl<4, 1, true><<<dim3(2048 / 128, MB1), 256, 0, stream>>>(
        proj_hi, proj_lo, whi, wlo, nullptr, nullptr, nullptr, l1pk, nullptr,
        as1, ad1, a_src1, a_dst1, 4, N, 512, 2048);
    k_softmax<4><<<N, 64, 0, stream>>>(row_ptr, col_src, a_src1, a_dst1, alpha);
    u16* h1_hi = (u16*)bufPk;                         // planes in region B
    u16* h1_lo = (u16*)bufPk + (size_t)N * 2048;
    k_agg<0, true, true><<<N, 256, 0, stream>>>(row_ptr, col_src, alpha, l1pk, nullptr,
                                                b1, h1_hi, h1_lo, nullptr, 4, 512);

    // ---- layer 2 (H=4, C=512, concat, ELU): fp16 payload, exact logits ----
    k_wt_pack<<<dim3(2048 / 32, 2048 / 32), 256, 0, stream>>>(W2, whi, wlo, 2048, 2048);
    u16* l2f = (u16*)bufA_hi;    // [N,2048] fp16 in region A (40 MB)
    k_gemm_pl<4, 2, true><<<dim3(2048 / 128, MB1), 256, 0, stream>>>(
        h1_hi, h1_lo, whi, wlo, nullptr, nullptr, nullptr, nullptr, l2f,
        as2, ad2, a_src2, a_dst2, 4, N, 2048, 2048);
    k_softmax<4><<<N, 64, 0, stream>>>(row_ptr, col_src, a_src2, a_dst2, alpha);
    u16* h2_hi = (u16*)bufPk;
    u16* h2_lo = (u16*)bufPk + (size_t)N * 2048;
    k_agg<1, true, true><<<N, 256, 0, stream>>>(row_ptr, col_src, alpha, nullptr, l2f,
                                                b2, h2_hi, h2_lo, nullptr, 4, 512);

    // ---- layer 3 (H=1, C=512, mean over single head = identity, no ELU) ----
    k_wt_pack<<<dim3(512 / 32, 2048 / 32), 256, 0, stream>>>(W3, whi, wlo, 2048, 512);
    u16* l3f = (u16*)bufA_hi;   // [N,512] fp16 in region A
    k_gemm_pl<2, 2, true><<<dim3(512 / 64, MB1), 256, 0, stream>>>(
        h2_hi, h2_lo, whi, wlo, nullptr, nullptr, nullptr, nullptr, l3f,
        as3, ad3, a_src3, a_dst3, 1, N, 2048, 512);
    k_softmax<1><<<N, 64, 0, stream>>>(row_ptr, col_src, a_src3, a_dst3, alpha);
    k_agg<1, false, false><<<N, 64, 0, stream>>>(row_ptr, col_src, alpha, nullptr, l3f,
                                                 b3, nullptr, nullptr, (float*)d_out, 1, 512);
}

// Round 12
// 760.444 us; speedup vs baseline: 2.0731x; 1.2414x over previous
//
#include <hip/hip_runtime.h>
#include <hip/hip_bf16.h>

// ---------------------------------------------------------------------------
// GAT encoder, round 12.
//  * proj + GEMM1: emulated-fp32 via split-bf16 3-product MFMA (exact-ish).
//  * GEMM2/GEMM3: 2-product fp16 MFMA: A = stored fp16 payload (no extra
//    rounding), B = fp16-hi + fp16-lo weight split (2^-24). Fewer MFMA
//    (32 vs 48 per K-step) and 3 staged planes (vs 4).
//  * ALL inter-layer payloads single fp16 plane; attention logits ALWAYS
//    exact (fused in GEMM epilogue from fp32 accumulator) -- the r10-proven
//    pattern (fp16 payload + exact logits == free) extended to layer 1.
//  * XCD block remap reverted (r11: -100MB FETCH but +15us -- not fetch-bound).
//  * k_agg depth-1 prefetch kept (r11 win).
// ---------------------------------------------------------------------------

#define LB(x) __launch_bounds__(x)

typedef unsigned short u16;
typedef unsigned int u32;
typedef __attribute__((ext_vector_type(8))) short short8;
typedef __attribute__((ext_vector_type(8))) short bf16x8;
typedef __attribute__((ext_vector_type(8))) _Float16 f16x8;
typedef __attribute__((ext_vector_type(4))) float f32x4;

__device__ __forceinline__ float b2f(u16 u) {
    union { float f; u32 u; } x;
    x.u = ((u32)u) << 16;
    return x.f;
}
__device__ __forceinline__ u16 f2b(float f) {
    u32 u = __float_as_uint(f);
    u = (u + 0x7FFFu + ((u >> 16) & 1u)) >> 16;   // RNE
    return (u16)u;
}
__device__ __forceinline__ u16 f2h(float f) {
    union { _Float16 h; u16 u; } x;
    x.h = (_Float16)f;
    return x.u;
}
__device__ __forceinline__ float h2f(u16 u) {
    union { _Float16 h; u16 u; } x;
    x.u = u;
    return (float)x.h;
}
__device__ __forceinline__ void lds_cp16(const void* g, void* l) {
    __builtin_amdgcn_global_load_lds(
        (const __attribute__((address_space(1))) unsigned int*)g,
        (__attribute__((address_space(3))) unsigned int*)l, 16, 0, 0);
}

// ---------------- CSR build ----------------
__global__ void k_deg(const int* __restrict__ ei, int E, int Np, int* __restrict__ deg) {
    int e = blockIdx.x * blockDim.x + threadIdx.x;
    if (e >= E + Np) return;
    int dst = (e < E) ? ei[E + e] : (e - E);
    atomicAdd(&deg[dst], 1);
}

__global__ LB(256) void k_s1(const int* __restrict__ deg, int* __restrict__ row_ptr,
                             int* __restrict__ bsum, int n) {
    __shared__ int sh[256];
    int b = blockIdx.x, t = threadIdx.x;
    int i = b * 256 + t;
    int v = (i < n) ? deg[i] : 0;
    sh[t] = v;
    __syncthreads();
    #pragma unroll
    for (int off = 1; off < 256; off <<= 1) {
        int add = (t >= off) ? sh[t - off] : 0;
        __syncthreads();
        sh[t] += add;
        __syncthreads();
    }
    if (i < n) row_ptr[i + 1] = sh[t];
    if (t == 255) bsum[b] = sh[255];
}

__global__ LB(64) void k_s2(int* __restrict__ bsum, int* __restrict__ boff, int nb) {
    __shared__ int sh[64];
    int t = threadIdx.x;
    sh[t] = (t < nb) ? bsum[t] : 0;
    __syncthreads();
    #pragma unroll
    for (int off = 1; off < 64; off <<= 1) {
        int add = (t >= off) ? sh[t - off] : 0;
        __syncthreads();
        sh[t] += add;
        __syncthreads();
    }
    if (t < nb) boff[t] = (t == 0) ? 0 : sh[t - 1];
}

__global__ LB(256) void k_s3(const int* __restrict__ deg, int* __restrict__ row_ptr,
                             const int* __restrict__ boff, int* __restrict__ cursor, int n) {
    int b = blockIdx.x, t = threadIdx.x;
    int i = b * 256 + t;
    if (i == 0) row_ptr[0] = 0;
    if (i < n) {
        int inc = row_ptr[i + 1] + boff[b];
        row_ptr[i + 1] = inc;
        cursor[i] = inc - deg[i];
    }
}

__global__ void k_fill(const int* __restrict__ ei, int E, int Np,
                       int* __restrict__ cursor, int* __restrict__ col_src) {
    int e = blockIdx.x * blockDim.x + threadIdx.x;
    if (e >= E + Np) return;
    int src, dst;
    if (e < E) { src = ei[e]; dst = ei[E + e]; }
    else       { src = dst = e - E; }
    int pos = atomicAdd(&cursor[dst], 1);
    col_src[pos] = src;
}

// ---------------- fp32 -> bf16 hi/lo planes (x) ----------------
__global__ void k_pack(const float* __restrict__ in, u16* __restrict__ hi,
                       u16* __restrict__ lo, int n4) {
    int i = blockIdx.x * blockDim.x + threadIdx.x;
    if (i >= n4) return;
    float4 v = ((const float4*)in)[i];
    ushort4 h, l;
    h.x = f2b(v.x); l.x = f2b(v.x - b2f(h.x));
    h.y = f2b(v.y); l.y = f2b(v.y - b2f(h.y));
    h.z = f2b(v.z); l.z = f2b(v.z - b2f(h.z));
    h.w = f2b(v.w); l.w = f2b(v.w - b2f(h.w));
    ((ushort4*)hi)[i] = h;
    ((ushort4*)lo)[i] = l;
}

// ---------------- weight transpose + split (bf16 or fp16 planes) ----------
template<bool F16>
__global__ LB(256) void k_wt_pack(const float* __restrict__ W, u16* __restrict__ Whi,
                                  u16* __restrict__ Wlo, int K, int Nn) {
    __shared__ float sh[32][33];
    int n0 = blockIdx.x * 32, k0 = blockIdx.y * 32;
    int c = threadIdx.x & 31, r0 = threadIdx.x >> 5;
    #pragma unroll
    for (int r = r0; r < 32; r += 8)
        sh[r][c] = W[(size_t)(k0 + r) * Nn + n0 + c];
    __syncthreads();
    #pragma unroll
    for (int r = r0; r < 32; r += 8) {
        float v = sh[c][r];
        if (F16) {
            u16 hi = f2h(v);
            Whi[(size_t)(n0 + r) * K + k0 + c] = hi;
            Wlo[(size_t)(n0 + r) * K + k0 + c] = f2h(v - h2f(hi));
        } else {
            u16 hi = f2b(v);
            Whi[(size_t)(n0 + r) * K + k0 + c] = hi;
            Wlo[(size_t)(n0 + r) * K + k0 + c] = f2b(v - b2f(hi));
        }
    }
}

// ---------------- MFMA GEMM: C = A[M,K] @ Bt[Nn,K]^T -----------------------
// BM=128, BK=32, 4 waves (2x2). LDS XOR swizzle (row&7)<<4 with inverse-
// permuted global_load_lds source. PREC 0: A,B = bf16 hi/lo planes,
// 3-product. PREC 1: A = fp16 plane, B = fp16 hi/lo planes, 2-product.
// OUTMODE 0: bf16 hi/lo planes (+bias). OUTMODE 2: fp16 plane.
// ATT: fused exact logits (fp32 accumulator . att_{s,d}, 16-lane reduce,
// atomicAdd into a_src/a_dst).
template<int NFR, int PREC, int OUTMODE, bool ATT>
__global__ LB(256) void k_gemm_pl(const u16* __restrict__ Ahi, const u16* __restrict__ Alo,
                                  const u16* __restrict__ Bhi, const u16* __restrict__ Blo,
                                  const float* __restrict__ bias,
                                  u16* __restrict__ Chi, u16* __restrict__ Clo,
                                  u16* __restrict__ Cf16,
                                  const float* __restrict__ att_s, const float* __restrict__ att_d,
                                  float* __restrict__ a_src, float* __restrict__ a_dst,
                                  int HH, int M, int K, int Nn) {
    constexpr int BN = NFR * 32;
    constexpr int ALO_SZ = (PREC == 0) ? 128 * 32 : 8;
    __shared__ u16 AsHi[128 * 32];
    __shared__ u16 AsLo[ALO_SZ];
    __shared__ u16 BsHi[BN * 32], BsLo[BN * 32];
    const int tid  = threadIdx.x;
    const int lane = tid & 63;
    const int w    = tid >> 6;
    const int wr   = w >> 1;
    const int wc   = w & 1;
    const int row0 = blockIdx.y * 128;
    const int col0 = blockIdx.x * BN;
    const int ln15 = lane & 15;
    const int lq   = lane >> 4;

    f32x4 acc[4][NFR];
    #pragma unroll
    for (int m = 0; m < 4; ++m)
        #pragma unroll
        for (int n = 0; n < NFR; ++n) acc[m][n] = (f32x4){0.f, 0.f, 0.f, 0.f};

    for (int k0 = 0; k0 < K; k0 += 32) {
        // A: 512 16B-chunks per plane, 2 per thread.
        #pragma unroll
        for (int i = 0; i < 2; ++i) {
            int c = i * 256 + tid;
            int r  = 2 * (c >> 3) + (((c >> 2) ^ (c >> 4)) & 1);   // inverse swizzle
            int kc = (c & 3) ^ (r & 3);
            int gra = row0 + r; if (gra >= M) gra = M - 1;          // tail clamp
            size_t ga = (size_t)gra * K + k0 + kc * 8;
            lds_cp16(Ahi + ga, (char*)AsHi + c * 16);
            if (PREC == 0) lds_cp16(Alo + ga, (char*)AsLo + c * 16);
        }
        // B: BN*4 chunks per plane, NFR/2 per thread per plane.
        #pragma unroll
        for (int i = 0; i < NFR / 2; ++i) {
            int c = i * 256 + tid;
            int r  = 2 * (c >> 3) + (((c >> 2) ^ (c >> 4)) & 1);
            int kc = (c & 3) ^ (r & 3);
            size_t gb = (size_t)(col0 + r) * K + k0 + kc * 8;
            lds_cp16(Bhi + gb, (char*)BsHi + c * 16);
            lds_cp16(Blo + gb, (char*)BsLo + c * 16);
        }
        __syncthreads();
        if (PREC == 0) {
            bf16x8 ah[4], al[4], bh[NFR], bl[NFR];
            #pragma unroll
            for (int m = 0; m < 4; ++m) {
                int row = wr * 64 + m * 16 + ln15;
                int byo = (row * 64 + lq * 16) ^ ((row & 7) << 4);
                ah[m] = *(const bf16x8*)((const char*)AsHi + byo);
                al[m] = *(const bf16x8*)((const char*)AsLo + byo);
            }
            #pragma unroll
            for (int n = 0; n < NFR; ++n) {
                int row = wc * (NFR * 16) + n * 16 + ln15;
                int byo = (row * 64 + lq * 16) ^ ((row & 7) << 4);
                bh[n] = *(const bf16x8*)((const char*)BsHi + byo);
                bl[n] = *(const bf16x8*)((const char*)BsLo + byo);
            }
            #pragma unroll
            for (int m = 0; m < 4; ++m)
                #pragma unroll
                for (int n = 0; n < NFR; ++n) {
                    acc[m][n] = __builtin_amdgcn_mfma_f32_16x16x32_bf16(al[m], bh[n], acc[m][n], 0, 0, 0);
                    acc[m][n] = __builtin_amdgcn_mfma_f32_16x16x32_bf16(ah[m], bl[n], acc[m][n], 0, 0, 0);
                    acc[m][n] = __builtin_amdgcn_mfma_f32_16x16x32_bf16(ah[m], bh[n], acc[m][n], 0, 0, 0);
                }
        } else {
            f16x8 a[4], bh[NFR], bl[NFR];
            #pragma unroll
            for (int m = 0; m < 4; ++m) {
                int row = wr * 64 + m * 16 + ln15;
                int byo = (row * 64 + lq * 16) ^ ((row & 7) << 4);
                a[m] = *(const f16x8*)((const char*)AsHi + byo);
            }
            #pragma unroll
            for (int n = 0; n < NFR; ++n) {
                int row = wc * (NFR * 16) + n * 16 + ln15;
                int byo = (row * 64 + lq * 16) ^ ((row & 7) << 4);
                bh[n] = *(const f16x8*)((const char*)BsHi + byo);
                bl[n] = *(const f16x8*)((const char*)BsLo + byo);
            }
            #pragma unroll
            for (int m = 0; m < 4; ++m)
                #pragma unroll
                for (int n = 0; n < NFR; ++n) {
                    acc[m][n] = __builtin_amdgcn_mfma_f32_16x16x32_f16(a[m], bl[n], acc[m][n], 0, 0, 0);
                    acc[m][n] = __builtin_amdgcn_mfma_f32_16x16x32_f16(a[m], bh[n], acc[m][n], 0, 0, 0);
                }
        }
        __syncthreads();
    }

    // D: col = lane&15, row = (lane>>4)*4 + j  [m89/m91-verified]
    #pragma unroll
    for (int m = 0; m < 4; ++m) {
        #pragma unroll
        for (int n = 0; n < NFR; ++n) {
            int gc = col0 + wc * (NFR * 16) + n * 16 + ln15;
            float badd = (OUTMODE == 0 && bias) ? bias[gc] : 0.f;
            #pragma unroll
            for (int j = 0; j < 4; ++j) {
                int gr = row0 + wr * 64 + m * 16 + lq * 4 + j;
                if (gr < M) {
                    float v = acc[m][n][j] + badd;
                    size_t o = (size_t)gr * Nn + gc;
                    if (OUTMODE == 0) {
                        u16 hi = f2b(v);
                        Chi[o] = hi;
                        Clo[o] = f2b(v - b2f(hi));
                    } else {
                        Cf16[o] = f2h(v);
                    }
                }
            }
        }
    }

    if (ATT) {
        float atts[NFR], attd[NFR];
        #pragma unroll
        for (int n = 0; n < NFR; ++n) {
            int gc = col0 + wc * (NFR * 16) + n * 16 + ln15;
            atts[n] = att_s[gc];
            attd[n] = att_d[gc];
        }
        const int head = (col0 + wc * (NFR * 16)) >> 9;   // /512, wave-uniform
        #pragma unroll
        for (int m = 0; m < 4; ++m) {
            #pragma unroll
            for (int j = 0; j < 4; ++j) {
                int gr = row0 + wr * 64 + m * 16 + lq * 4 + j;
                float s1 = 0.f, s2 = 0.f;
                #pragma unroll
                for (int n = 0; n < NFR; ++n) {
                    float v = acc[m][n][j];
                    s1 = fmaf(v, atts[n], s1);
                    s2 = fmaf(v, attd[n], s2);
                }
                #pragma unroll
                for (int off = 1; off < 16; off <<= 1) {
                    s1 += __shfl_xor(s1, off);
                    s2 += __shfl_xor(s2, off);
                }
                if (ln15 == 0 && gr < M) {
                    atomicAdd(&a_src[gr * HH + head], s1);
                    atomicAdd(&a_dst[gr * HH + head], s2);
                }
            }
        }
    }
}

// ---------------- fused segment softmax per dst (one wave) ----------------
template<int HH>
__global__ LB(64) void k_softmax(const int* __restrict__ row_ptr, const int* __restrict__ col_src,
                                 const float* __restrict__ a_src, const float* __restrict__ a_dst,
                                 float* __restrict__ alpha) {
    int d = blockIdx.x;
    int t = threadIdx.x;
    int s = row_ptr[d], eend = row_ptr[d + 1];
    int cnt = eend - s;
    float adh[HH];
    #pragma unroll
    for (int h = 0; h < HH; ++h) adh[h] = a_dst[d * HH + h];

    if (cnt <= 64) {
        bool act = t < cnt;
        float av[HH];
        #pragma unroll
        for (int h = 0; h < HH; ++h) av[h] = 0.f;
        if (act) {
            int src = col_src[s + t];
            if (HH == 4) {
                float4 q = ((const float4*)a_src)[src];
                av[0] = q.x; av[1] = q.y; av[2] = q.z; av[3] = q.w;
            } else {
                av[0] = a_src[src];
            }
        }
        float v[HH], m[HH], sum[HH];
        #pragma unroll
        for (int h = 0; h < HH; ++h) {
            float x = av[h] + adh[h];
            x = (x > 0.f) ? x : 0.2f * x;
            v[h] = act ? x : -1e30f;
            m[h] = v[h];
        }
        #pragma unroll
        for (int off = 32; off; off >>= 1)
            #pragma unroll
            for (int h = 0; h < HH; ++h) m[h] = fmaxf(m[h], __shfl_xor(m[h], off));
        #pragma unroll
        for (int h = 0; h < HH; ++h) {
            float e = act ? __expf(v[h] - m[h]) : 0.f;
            v[h] = e;
            sum[h] = e;
        }
        #pragma unroll
        for (int off = 32; off; off >>= 1)
            #pragma unroll
            for (int h = 0; h < HH; ++h) sum[h] += __shfl_xor(sum[h], off);
        if (act) {
            if (HH == 4) {
                float4 o;
                o.x = v[0] / sum[0]; o.y = v[1] / sum[1];
                o.z = v[2] / sum[2]; o.w = v[3] / sum[3];
                ((float4*)alpha)[s + t] = o;
            } else {
                alpha[s + t] = v[0] / sum[0];
            }
        }
        return;
    }

    // generic fallback (deg > 64): 3-pass recompute
    for (int h = 0; h < HH; ++h) {
        float m = -1e30f;
        for (int e = s + t; e < eend; e += 64) {
            float x = a_src[col_src[e] * HH + h] + adh[h];
            x = (x > 0.f) ? x : 0.2f * x;
            m = fmaxf(m, x);
        }
        #pragma unroll
        for (int off = 32; off; off >>= 1) m = fmaxf(m, __shfl_xor(m, off));
        float sum = 0.f;
        for (int e = s + t; e < eend; e += 64) {
            float x = a_src[col_src[e] * HH + h] + adh[h];
            x = (x > 0.f) ? x : 0.2f * x;
            sum += __expf(x - m);
        }
        #pragma unroll
        for (int off = 32; off; off >>= 1) sum += __shfl_xor(sum, off);
        float inv = 1.0f / sum;
        for (int e = s + t; e < eend; e += 64) {
            float x = a_src[col_src[e] * HH + h] + adh[h];
            x = (x > 0.f) ? x : 0.2f * x;
            alpha[e * HH + h] = __expf(x - m) * inv;
        }
    }
}

// ---------------- aggregate: out[d] = sum_e alpha[e,h]*h[src] (+bias,ELU) --
// fp16 h gather, depth-1 prefetch (single accumulator -> FP order identical).
// OMODE 0: fp16 plane out. OMODE 1: fp32 final out.
template <int OMODE, bool ELU_>
__global__ LB(256) void k_agg(const int* __restrict__ row_ptr, const int* __restrict__ col_src,
                              const float* __restrict__ alpha, const u16* __restrict__ hf,
                              const float* __restrict__ bias,
                              u16* __restrict__ Oh, float* __restrict__ Of, int H, int C) {
    int d = blockIdx.x;
    int tid = threadIdx.x;
    int F = H * C;
    int o = tid * 8;
    int h0 = o / C;   // wave-uniform for C=512
    float acc[8];
    #pragma unroll
    for (int j = 0; j < 8; ++j) acc[j] = 0.f;
    int s = row_ptr[d], eend = row_ptr[d + 1];

    short8 v; float a;
    if (s < eend) {
        int src = col_src[s];
        a = alpha[s * H + h0];
        v = *(const short8*)(hf + (size_t)src * F + o);
    }
    for (int e = s; e < eend; ++e) {
        short8 w_; float an;
        bool more = (e + 1 < eend);           // block-uniform branch
        if (more) {
            int srcn = col_src[e + 1];
            an = alpha[(e + 1) * H + h0];
            w_ = *(const short8*)(hf + (size_t)srcn * F + o);
        }
        #pragma unroll
        for (int j = 0; j < 8; ++j)
            acc[j] = fmaf(a, h2f((u16)v[j]), acc[j]);
        if (more) { a = an; v = w_; }
    }

    #pragma unroll
    for (int j = 0; j < 8; ++j) {
        acc[j] += bias[o + j];
        if (ELU_) acc[j] = (acc[j] > 0.f) ? acc[j] : __expf(acc[j]) - 1.f;
    }
    if (OMODE == 0) {
        short8 r;
        #pragma unroll
        for (int j = 0; j < 8; ++j) r[j] = (short)f2h(acc[j]);
        *(short8*)(Oh + (size_t)d * F + o) = r;
    } else {
        float* po = Of + (size_t)d * F + o;
        #pragma unroll
        for (int j4 = 0; j4 < 2; ++j4) {
            float4 r;
            r.x = acc[j4 * 4 + 0]; r.y = acc[j4 * 4 + 1];
            r.z = acc[j4 * 4 + 2]; r.w = acc[j4 * 4 + 3];
            *(float4*)&po[j4 * 4] = r;
        }
    }
}

// ---------------------------------------------------------------------------
extern "C" void kernel_launch(void* const* d_in, const int* in_sizes, int n_in,
                              void* d_out, int out_size, void* d_ws, size_t ws_size,
                              hipStream_t stream) {
    const float* x      = (const float*)d_in[0];
    const int*   ei     = (const int*)d_in[1];
    const float* proj_W = (const float*)d_in[2];
    const float* proj_b = (const float*)d_in[3];
    const float* W1  = (const float*)d_in[4];
    const float* as1 = (const float*)d_in[5];
    const float* ad1 = (const float*)d_in[6];
    const float* b1  = (const float*)d_in[7];
    const float* W2  = (const float*)d_in[8];
    const float* as2 = (const float*)d_in[9];
    const float* ad2 = (const float*)d_in[10];
    const float* b2  = (const float*)d_in[11];
    const float* W3  = (const float*)d_in[12];
    const float* as3 = (const float*)d_in[13];
    const float* ad3 = (const float*)d_in[14];
    const float* b3  = (const float*)d_in[15];

    const int N  = in_sizes[0] / 256;   // 10000
    const int E  = in_sizes[1] / 2;     // 160000
    const int Ep = E + N;
    const int NB = (N + 255) / 256;     // 40 scan blocks

    size_t off = 0;
    auto alloc = [&](size_t bytes) -> void* {
        void* p = (char*)d_ws + off;
        off += (bytes + 255) & ~(size_t)255;
        return p;
    };
    u16* bufX    = (u16*)alloc((size_t)N * 2048 * 2);   // fp16 h  (40 MB)
    u16* bufY    = (u16*)alloc((size_t)N * 2048 * 2);   // fp16 h' (40 MB)
    u16* proj_hi = (u16*)alloc((size_t)N * 512 * 2);    // bf16 planes
    u16* proj_lo = (u16*)alloc((size_t)N * 512 * 2);
    u16* xb_hi   = (u16*)alloc((size_t)N * 256 * 2);
    u16* xb_lo   = (u16*)alloc((size_t)N * 256 * 2);
    float* att_z   = (float*)alloc((size_t)N * 18 * 4); // a_src/a_dst x3 layers
    float* alpha   = (float*)alloc((size_t)Ep * 4 * 4);
    int*   deg     = (int*)alloc((size_t)N * 4);
    int*   cursor  = (int*)alloc((size_t)N * 4);
    int*   row_ptr = (int*)alloc((size_t)(N + 1) * 4);
    int*   col_src = (int*)alloc((size_t)Ep * 4);
    int*   bsum    = (int*)alloc((size_t)NB * 4);
    int*   boff    = (int*)alloc((size_t)NB * 4);
    (void)ws_size;

    float* a_src1 = att_z;
    float* a_dst1 = att_z + (size_t)N * 4;
    float* a_src2 = att_z + (size_t)N * 8;
    float* a_dst2 = att_z + (size_t)N * 12;
    float* a_src3 = att_z + (size_t)N * 16;
    float* a_dst3 = att_z + (size_t)N * 17;

    // JIT weight planes in d_out (16.78 MB <= 20.48 MB); fully overwritten
    // by the final aggregate afterwards.
    u16* whi = (u16*)d_out;
    u16* wlo = (u16*)d_out + (size_t)2048 * 2048;

    // ---- CSR build + zero att accumulators ----
    hipMemsetAsync(deg, 0, (size_t)N * 4, stream);
    hipMemsetAsync(att_z, 0, (size_t)N * 18 * 4, stream);
    int eb = (Ep + 255) / 256;
    k_deg<<<eb, 256, 0, stream>>>(ei, E, N, deg);
    k_s1<<<NB, 256, 0, stream>>>(deg, row_ptr, bsum, N);
    k_s2<<<1, 64, 0, stream>>>(bsum, boff, NB);
    k_s3<<<NB, 256, 0, stream>>>(deg, row_ptr, boff, cursor, N);
    k_fill<<<eb, 256, 0, stream>>>(ei, E, N, cursor, col_src);

    const int MB1 = (N + 127) / 128;  // 79

    // ---- pack x into bf16 planes [N,256] ----
    k_pack<<<(N * 256 / 4 + 255) / 256, 256, 0, stream>>>(x, xb_hi, xb_lo, N * 256 / 4);

    // ---- proj (split-bf16 3-product): x planes -> proj planes, +bias ----
    k_wt_pack<false><<<dim3(512 / 32, 256 / 32), 256, 0, stream>>>(proj_W, whi, wlo, 256, 512);
    k_gemm_pl<2, 0, 0, false><<<dim3(512 / 64, MB1), 256, 0, stream>>>(
        xb_hi, xb_lo, whi, wlo, proj_b, proj_hi, proj_lo, nullptr,
        nullptr, nullptr, nullptr, nullptr, 0, N, 256, 512);

    // ---- layer 1 (split-bf16 3-product, fp16 h out, exact fused logits) ----
    k_wt_pack<false><<<dim3(2048 / 32, 512 / 32), 256, 0, stream>>>(W1, whi, wlo, 512, 2048);
    k_gemm_pl<4, 0, 2, true><<<dim3(2048 / 128, MB1), 256, 0, stream>>>(
        proj_hi, proj_lo, whi, wlo, nullptr, nullptr, nullptr, bufX,
        as1, ad1, a_src1, a_dst1, 4, N, 512, 2048);
    k_softmax<4><<<N, 64, 0, stream>>>(row_ptr, col_src, a_src1, a_dst1, alpha);
    k_agg<0, true><<<N, 256, 0, stream>>>(row_ptr, col_src, alpha, bufX,
                                          b1, bufY, nullptr, 4, 512);

    // ---- layer 2 (fp16 2-product: A=h1' fp16, B=W2 fp16 hi/lo) ----
    k_wt_pack<true><<<dim3(2048 / 32, 2048 / 32), 256, 0, stream>>>(W2, whi, wlo, 2048, 2048);
    k_gemm_pl<4, 1, 2, true><<<dim3(2048 / 128, MB1), 256, 0, stream>>>(
        bufY, nullptr, whi, wlo, nullptr, nullptr, nullptr, bufX,
        as2, ad2, a_src2, a_dst2, 4, N, 2048, 2048);
    k_softmax<4><<<N, 64, 0, stream>>>(row_ptr, col_src, a_src2, a_dst2, alpha);
    k_agg<0, true><<<N, 256, 0, stream>>>(row_ptr, col_src, alpha, bufX,
                                          b2, bufY, nullptr, 4, 512);

    // ---- layer 3 (fp16 2-product; single head -> mean = identity) ----
    k_wt_pack<true><<<dim3(512 / 32, 2048 / 32), 256, 0, stream>>>(W3, whi, wlo, 2048, 512);
    k_gemm_pl<2, 1, 2, true><<<dim3(512 / 64, MB1), 256, 0, stream>>>(
        bufY, nullptr, whi, wlo, nullptr, nullptr, nullptr, bufX,
        as3, ad3, a_src3, a_dst3, 1, N, 2048, 512);
    k_softmax<1><<<N, 64, 0, stream>>>(row_ptr, col_src, a_src3, a_dst3, alpha);
    k_agg<1, false><<<N, 64, 0, stream>>>(row_ptr, col_src, alpha, bufX,
                                          b3, nullptr, (float*)d_out, 1, 512);
}

// Round 13
// 758.966 us; speedup vs baseline: 2.0772x; 1.0019x over previous
//
#include <hip/hip_runtime.h>
#include <hip/hip_bf16.h>

// ---------------------------------------------------------------------------
// GAT encoder, round 13.
//  * PROJ FOLDED INTO GEMM1 (exact linear identity):
//      h1 = (x@Wp + bp)@W1 = x@(Wp W1) + bp@W1.
//    Wfold^T computed on-device via split-bf16 3-product GEMM (output lands
//    directly in B^T plane layout); bfold via tiny wave-reduce kernel.
//    GEMM1 now K=256 from x planes; bfold added in epilogue before the
//    fused logits and fp16 store. Proj GEMM + 20MB plane round-trip gone.
//  * GEMM1 (+fold GEMM): split-bf16 3-product (exact-ish).
//    GEMM2/3: 2-product fp16 (A = fp16 payload, B = fp16 hi/lo).
//  * fp16 payloads everywhere, logits always exact-fused (r10/r12-proven).
//  * k_agg depth-1 prefetch kept.
// ---------------------------------------------------------------------------

#define LB(x) __launch_bounds__(x)

typedef unsigned short u16;
typedef unsigned int u32;
typedef __attribute__((ext_vector_type(8))) short short8;
typedef __attribute__((ext_vector_type(8))) short bf16x8;
typedef __attribute__((ext_vector_type(8))) _Float16 f16x8;
typedef __attribute__((ext_vector_type(4))) float f32x4;

__device__ __forceinline__ float b2f(u16 u) {
    union { float f; u32 u; } x;
    x.u = ((u32)u) << 16;
    return x.f;
}
__device__ __forceinline__ u16 f2b(float f) {
    u32 u = __float_as_uint(f);
    u = (u + 0x7FFFu + ((u >> 16) & 1u)) >> 16;   // RNE
    return (u16)u;
}
__device__ __forceinline__ u16 f2h(float f) {
    union { _Float16 h; u16 u; } x;
    x.h = (_Float16)f;
    return x.u;
}
__device__ __forceinline__ float h2f(u16 u) {
    union { _Float16 h; u16 u; } x;
    x.u = u;
    return (float)x.h;
}
__device__ __forceinline__ void lds_cp16(const void* g, void* l) {
    __builtin_amdgcn_global_load_lds(
        (const __attribute__((address_space(1))) unsigned int*)g,
        (__attribute__((address_space(3))) unsigned int*)l, 16, 0, 0);
}

// ---------------- CSR build ----------------
__global__ void k_deg(const int* __restrict__ ei, int E, int Np, int* __restrict__ deg) {
    int e = blockIdx.x * blockDim.x + threadIdx.x;
    if (e >= E + Np) return;
    int dst = (e < E) ? ei[E + e] : (e - E);
    atomicAdd(&deg[dst], 1);
}

__global__ LB(256) void k_s1(const int* __restrict__ deg, int* __restrict__ row_ptr,
                             int* __restrict__ bsum, int n) {
    __shared__ int sh[256];
    int b = blockIdx.x, t = threadIdx.x;
    int i = b * 256 + t;
    int v = (i < n) ? deg[i] : 0;
    sh[t] = v;
    __syncthreads();
    #pragma unroll
    for (int off = 1; off < 256; off <<= 1) {
        int add = (t >= off) ? sh[t - off] : 0;
        __syncthreads();
        sh[t] += add;
        __syncthreads();
    }
    if (i < n) row_ptr[i + 1] = sh[t];
    if (t == 255) bsum[b] = sh[255];
}

__global__ LB(64) void k_s2(int* __restrict__ bsum, int* __restrict__ boff, int nb) {
    __shared__ int sh[64];
    int t = threadIdx.x;
    sh[t] = (t < nb) ? bsum[t] : 0;
    __syncthreads();
    #pragma unroll
    for (int off = 1; off < 64; off <<= 1) {
        int add = (t >= off) ? sh[t - off] : 0;
        __syncthreads();
        sh[t] += add;
        __syncthreads();
    }
    if (t < nb) boff[t] = (t == 0) ? 0 : sh[t - 1];
}

__global__ LB(256) void k_s3(const int* __restrict__ deg, int* __restrict__ row_ptr,
                             const int* __restrict__ boff, int* __restrict__ cursor, int n) {
    int b = blockIdx.x, t = threadIdx.x;
    int i = b * 256 + t;
    if (i == 0) row_ptr[0] = 0;
    if (i < n) {
        int inc = row_ptr[i + 1] + boff[b];
        row_ptr[i + 1] = inc;
        cursor[i] = inc - deg[i];
    }
}

__global__ void k_fill(const int* __restrict__ ei, int E, int Np,
                       int* __restrict__ cursor, int* __restrict__ col_src) {
    int e = blockIdx.x * blockDim.x + threadIdx.x;
    if (e >= E + Np) return;
    int src, dst;
    if (e < E) { src = ei[e]; dst = ei[E + e]; }
    else       { src = dst = e - E; }
    int pos = atomicAdd(&cursor[dst], 1);
    col_src[pos] = src;
}

// ---------------- fp32 -> bf16 hi/lo planes (flat) ----------------
__global__ void k_pack(const float* __restrict__ in, u16* __restrict__ hi,
                       u16* __restrict__ lo, int n4) {
    int i = blockIdx.x * blockDim.x + threadIdx.x;
    if (i >= n4) return;
    float4 v = ((const float4*)in)[i];
    ushort4 h, l;
    h.x = f2b(v.x); l.x = f2b(v.x - b2f(h.x));
    h.y = f2b(v.y); l.y = f2b(v.y - b2f(h.y));
    h.z = f2b(v.z); l.z = f2b(v.z - b2f(h.z));
    h.w = f2b(v.w); l.w = f2b(v.w - b2f(h.w));
    ((ushort4*)hi)[i] = h;
    ((ushort4*)lo)[i] = l;
}

// ---------------- weight transpose + split (bf16 or fp16 planes) ----------
template<bool F16>
__global__ LB(256) void k_wt_pack(const float* __restrict__ W, u16* __restrict__ Whi,
                                  u16* __restrict__ Wlo, int K, int Nn) {
    __shared__ float sh[32][33];
    int n0 = blockIdx.x * 32, k0 = blockIdx.y * 32;
    int c = threadIdx.x & 31, r0 = threadIdx.x >> 5;
    #pragma unroll
    for (int r = r0; r < 32; r += 8)
        sh[r][c] = W[(size_t)(k0 + r) * Nn + n0 + c];
    __syncthreads();
    #pragma unroll
    for (int r = r0; r < 32; r += 8) {
        float v = sh[c][r];
        if (F16) {
            u16 hi = f2h(v);
            Whi[(size_t)(n0 + r) * K + k0 + c] = hi;
            Wlo[(size_t)(n0 + r) * K + k0 + c] = f2h(v - h2f(hi));
        } else {
            u16 hi = f2b(v);
            Whi[(size_t)(n0 + r) * K + k0 + c] = hi;
            Wlo[(size_t)(n0 + r) * K + k0 + c] = f2b(v - b2f(hi));
        }
    }
}

// ---------------- bias fold: bfold[n] = sum_k pb[k] * W1[k][n] ------------
// W1 given as transposed bf16 planes w1t[n][k] (hi+lo). One wave per n.
__global__ LB(64) void k_bfold(const float* __restrict__ pb,
                               const u16* __restrict__ w1t_hi, const u16* __restrict__ w1t_lo,
                               float* __restrict__ bfold, int K) {
    int n = blockIdx.x;
    int lane = threadIdx.x;
    float s = 0.f;
    for (int k = lane; k < K; k += 64) {
        float w = b2f(w1t_hi[(size_t)n * K + k]) + b2f(w1t_lo[(size_t)n * K + k]);
        s = fmaf(pb[k], w, s);
    }
    #pragma unroll
    for (int off = 32; off; off >>= 1) s += __shfl_xor(s, off);
    if (lane == 0) bfold[n] = s;
}

// ---------------- MFMA GEMM: C = A[M,K] @ Bt[Nn,K]^T -----------------------
// BM=128, BK=32, 4 waves (2x2). LDS XOR swizzle (row&7)<<4 with inverse-
// permuted global_load_lds source. PREC 0: A,B = bf16 hi/lo planes,
// 3-product. PREC 1: A = fp16 plane, B = fp16 hi/lo planes, 2-product.
// OUTMODE 0: bf16 hi/lo planes. OUTMODE 2: fp16 plane. bias added in
// epilogue for all OUTMODEs (pre-store AND pre-logit).
// ATT: fused exact logits ((acc+bias) . att_{s,d}, 16-lane reduce, atomicAdd).
template<int NFR, int PREC, int OUTMODE, bool ATT>
__global__ LB(256) void k_gemm_pl(const u16* __restrict__ Ahi, const u16* __restrict__ Alo,
                                  const u16* __restrict__ Bhi, const u16* __restrict__ Blo,
                                  const float* __restrict__ bias,
                                  u16* __restrict__ Chi, u16* __restrict__ Clo,
                                  u16* __restrict__ Cf16,
                                  const float* __restrict__ att_s, const float* __restrict__ att_d,
                                  float* __restrict__ a_src, float* __restrict__ a_dst,
                                  int HH, int M, int K, int Nn) {
    constexpr int BN = NFR * 32;
    constexpr int ALO_SZ = (PREC == 0) ? 128 * 32 : 8;
    __shared__ u16 AsHi[128 * 32];
    __shared__ u16 AsLo[ALO_SZ];
    __shared__ u16 BsHi[BN * 32], BsLo[BN * 32];
    const int tid  = threadIdx.x;
    const int lane = tid & 63;
    const int w    = tid >> 6;
    const int wr   = w >> 1;
    const int wc   = w & 1;
    const int row0 = blockIdx.y * 128;
    const int col0 = blockIdx.x * BN;
    const int ln15 = lane & 15;
    const int lq   = lane >> 4;

    f32x4 acc[4][NFR];
    #pragma unroll
    for (int m = 0; m < 4; ++m)
        #pragma unroll
        for (int n = 0; n < NFR; ++n) acc[m][n] = (f32x4){0.f, 0.f, 0.f, 0.f};

    for (int k0 = 0; k0 < K; k0 += 32) {
        // A: 512 16B-chunks per plane, 2 per thread.
        #pragma unroll
        for (int i = 0; i < 2; ++i) {
            int c = i * 256 + tid;
            int r  = 2 * (c >> 3) + (((c >> 2) ^ (c >> 4)) & 1);   // inverse swizzle
            int kc = (c & 3) ^ (r & 3);
            int gra = row0 + r; if (gra >= M) gra = M - 1;          // tail clamp
            size_t ga = (size_t)gra * K + k0 + kc * 8;
            lds_cp16(Ahi + ga, (char*)AsHi + c * 16);
            if (PREC == 0) lds_cp16(Alo + ga, (char*)AsLo + c * 16);
        }
        // B: BN*4 chunks per plane, NFR/2 per thread per plane.
        #pragma unroll
        for (int i = 0; i < NFR / 2; ++i) {
            int c = i * 256 + tid;
            int r  = 2 * (c >> 3) + (((c >> 2) ^ (c >> 4)) & 1);
            int kc = (c & 3) ^ (r & 3);
            size_t gb = (size_t)(col0 + r) * K + k0 + kc * 8;
            lds_cp16(Bhi + gb, (char*)BsHi + c * 16);
            lds_cp16(Blo + gb, (char*)BsLo + c * 16);
        }
        __syncthreads();
        if (PREC == 0) {
            bf16x8 ah[4], al[4], bh[NFR], bl[NFR];
            #pragma unroll
            for (int m = 0; m < 4; ++m) {
                int row = wr * 64 + m * 16 + ln15;
                int byo = (row * 64 + lq * 16) ^ ((row & 7) << 4);
                ah[m] = *(const bf16x8*)((const char*)AsHi + byo);
                al[m] = *(const bf16x8*)((const char*)AsLo + byo);
            }
            #pragma unroll
            for (int n = 0; n < NFR; ++n) {
                int row = wc * (NFR * 16) + n * 16 + ln15;
                int byo = (row * 64 + lq * 16) ^ ((row & 7) << 4);
                bh[n] = *(const bf16x8*)((const char*)BsHi + byo);
                bl[n] = *(const bf16x8*)((const char*)BsLo + byo);
            }
            #pragma unroll
            for (int m = 0; m < 4; ++m)
                #pragma unroll
                for (int n = 0; n < NFR; ++n) {
                    acc[m][n] = __builtin_amdgcn_mfma_f32_16x16x32_bf16(al[m], bh[n], acc[m][n], 0, 0, 0);
                    acc[m][n] = __builtin_amdgcn_mfma_f32_16x16x32_bf16(ah[m], bl[n], acc[m][n], 0, 0, 0);
                    acc[m][n] = __builtin_amdgcn_mfma_f32_16x16x32_bf16(ah[m], bh[n], acc[m][n], 0, 0, 0);
                }
        } else {
            f16x8 a[4], bh[NFR], bl[NFR];
            #pragma unroll
            for (int m = 0; m < 4; ++m) {
                int row = wr * 64 + m * 16 + ln15;
                int byo = (row * 64 + lq * 16) ^ ((row & 7) << 4);
                a[m] = *(const f16x8*)((const char*)AsHi + byo);
            }
            #pragma unroll
            for (int n = 0; n < NFR; ++n) {
                int row = wc * (NFR * 16) + n * 16 + ln15;
                int byo = (row * 64 + lq * 16) ^ ((row & 7) << 4);
                bh[n] = *(const f16x8*)((const char*)BsHi + byo);
                bl[n] = *(const f16x8*)((const char*)BsLo + byo);
            }
            #pragma unroll
            for (int m = 0; m < 4; ++m)
                #pragma unroll
                for (int n = 0; n < NFR; ++n) {
                    acc[m][n] = __builtin_amdgcn_mfma_f32_16x16x32_f16(a[m], bl[n], acc[m][n], 0, 0, 0);
                    acc[m][n] = __builtin_amdgcn_mfma_f32_16x16x32_f16(a[m], bh[n], acc[m][n], 0, 0, 0);
                }
        }
        __syncthreads();
    }

    // D: col = lane&15, row = (lane>>4)*4 + j  [m89/m91-verified]
    #pragma unroll
    for (int m = 0; m < 4; ++m) {
        #pragma unroll
        for (int n = 0; n < NFR; ++n) {
            int gc = col0 + wc * (NFR * 16) + n * 16 + ln15;
            float badd = bias ? bias[gc] : 0.f;
            #pragma unroll
            for (int j = 0; j < 4; ++j) {
                int gr = row0 + wr * 64 + m * 16 + lq * 4 + j;
                if (gr < M) {
                    float v = acc[m][n][j] + badd;
                    size_t o = (size_t)gr * Nn + gc;
                    if (OUTMODE == 0) {
                        u16 hi = f2b(v);
                        Chi[o] = hi;
                        Clo[o] = f2b(v - b2f(hi));
                    } else {
                        Cf16[o] = f2h(v);
                    }
                }
            }
        }
    }

    if (ATT) {
        float atts[NFR], attd[NFR], bb[NFR];
        #pragma unroll
        for (int n = 0; n < NFR; ++n) {
            int gc = col0 + wc * (NFR * 16) + n * 16 + ln15;
            atts[n] = att_s[gc];
            attd[n] = att_d[gc];
            bb[n]   = bias ? bias[gc] : 0.f;
        }
        const int head = (col0 + wc * (NFR * 16)) >> 9;   // /512, wave-uniform
        #pragma unroll
        for (int m = 0; m < 4; ++m) {
            #pragma unroll
            for (int j = 0; j < 4; ++j) {
                int gr = row0 + wr * 64 + m * 16 + lq * 4 + j;
                float s1 = 0.f, s2 = 0.f;
                #pragma unroll
                for (int n = 0; n < NFR; ++n) {
                    float v = acc[m][n][j] + bb[n];
                    s1 = fmaf(v, atts[n], s1);
                    s2 = fmaf(v, attd[n], s2);
                }
                #pragma unroll
                for (int off = 1; off < 16; off <<= 1) {
                    s1 += __shfl_xor(s1, off);
                    s2 += __shfl_xor(s2, off);
                }
                if (ln15 == 0 && gr < M) {
                    atomicAdd(&a_src[gr * HH + head], s1);
                    atomicAdd(&a_dst[gr * HH + head], s2);
                }
            }
        }
    }
}

// ---------------- fused segment softmax per dst (one wave) ----------------
template<int HH>
__global__ LB(64) void k_softmax(const int* __restrict__ row_ptr, const int* __restrict__ col_src,
                                 const float* __restrict__ a_src, const float* __restrict__ a_dst,
                                 float* __restrict__ alpha) {
    int d = blockIdx.x;
    int t = threadIdx.x;
    int s = row_ptr[d], eend = row_ptr[d + 1];
    int cnt = eend - s;
    float adh[HH];
    #pragma unroll
    for (int h = 0; h < HH; ++h) adh[h] = a_dst[d * HH + h];

    if (cnt <= 64) {
        bool act = t < cnt;
        float av[HH];
        #pragma unroll
        for (int h = 0; h < HH; ++h) av[h] = 0.f;
        if (act) {
            int src = col_src[s + t];
            if (HH == 4) {
                float4 q = ((const float4*)a_src)[src];
                av[0] = q.x; av[1] = q.y; av[2] = q.z; av[3] = q.w;
            } else {
                av[0] = a_src[src];
            }
        }
        float v[HH], m[HH], sum[HH];
        #pragma unroll
        for (int h = 0; h < HH; ++h) {
            float x = av[h] + adh[h];
            x = (x > 0.f) ? x : 0.2f * x;
            v[h] = act ? x : -1e30f;
            m[h] = v[h];
        }
        #pragma unroll
        for (int off = 32; off; off >>= 1)
            #pragma unroll
            for (int h = 0; h < HH; ++h) m[h] = fmaxf(m[h], __shfl_xor(m[h], off));
        #pragma unroll
        for (int h = 0; h < HH; ++h) {
            float e = act ? __expf(v[h] - m[h]) : 0.f;
            v[h] = e;
            sum[h] = e;
        }
        #pragma unroll
        for (int off = 32; off; off >>= 1)
            #pragma unroll
            for (int h = 0; h < HH; ++h) sum[h] += __shfl_xor(sum[h], off);
        if (act) {
            if (HH == 4) {
                float4 o;
                o.x = v[0] / sum[0]; o.y = v[1] / sum[1];
                o.z = v[2] / sum[2]; o.w = v[3] / sum[3];
                ((float4*)alpha)[s + t] = o;
            } else {
                alpha[s + t] = v[0] / sum[0];
            }
        }
        return;
    }

    // generic fallback (deg > 64): 3-pass recompute
    for (int h = 0; h < HH; ++h) {
        float m = -1e30f;
        for (int e = s + t; e < eend; e += 64) {
            float x = a_src[col_src[e] * HH + h] + adh[h];
            x = (x > 0.f) ? x : 0.2f * x;
            m = fmaxf(m, x);
        }
        #pragma unroll
        for (int off = 32; off; off >>= 1) m = fmaxf(m, __shfl_xor(m, off));
        float sum = 0.f;
        for (int e = s + t; e < eend; e += 64) {
            float x = a_src[col_src[e] * HH + h] + adh[h];
            x = (x > 0.f) ? x : 0.2f * x;
            sum += __expf(x - m);
        }
        #pragma unroll
        for (int off = 32; off; off >>= 1) sum += __shfl_xor(sum, off);
        float inv = 1.0f / sum;
        for (int e = s + t; e < eend; e += 64) {
            float x = a_src[col_src[e] * HH + h] + adh[h];
            x = (x > 0.f) ? x : 0.2f * x;
            alpha[e * HH + h] = __expf(x - m) * inv;
        }
    }
}

// ---------------- aggregate: out[d] = sum_e alpha[e,h]*h[src] (+bias,ELU) --
// fp16 h gather, depth-1 prefetch (single accumulator -> FP order identical).
// OMODE 0: fp16 plane out. OMODE 1: fp32 final out.
template <int OMODE, bool ELU_>
__global__ LB(256) void k_agg(const int* __restrict__ row_ptr, const int* __restrict__ col_src,
                              const float* __restrict__ alpha, const u16* __restrict__ hf,
                              const float* __restrict__ bias,
                              u16* __restrict__ Oh, float* __restrict__ Of, int H, int C) {
    int d = blockIdx.x;
    int tid = threadIdx.x;
    int F = H * C;
    int o = tid * 8;
    int h0 = o / C;   // wave-uniform for C=512
    float acc[8];
    #pragma unroll
    for (int j = 0; j < 8; ++j) acc[j] = 0.f;
    int s = row_ptr[d], eend = row_ptr[d + 1];

    short8 v; float a;
    if (s < eend) {
        int src = col_src[s];
        a = alpha[s * H + h0];
        v = *(const short8*)(hf + (size_t)src * F + o);
    }
    for (int e = s; e < eend; ++e) {
        short8 w_; float an;
        bool more = (e + 1 < eend);           // block-uniform branch
        if (more) {
            int srcn = col_src[e + 1];
            an = alpha[(e + 1) * H + h0];
            w_ = *(const short8*)(hf + (size_t)srcn * F + o);
        }
        #pragma unroll
        for (int j = 0; j < 8; ++j)
            acc[j] = fmaf(a, h2f((u16)v[j]), acc[j]);
        if (more) { a = an; v = w_; }
    }

    #pragma unroll
    for (int j = 0; j < 8; ++j) {
        acc[j] += bias[o + j];
        if (ELU_) acc[j] = (acc[j] > 0.f) ? acc[j] : __expf(acc[j]) - 1.f;
    }
    if (OMODE == 0) {
        short8 r;
        #pragma unroll
        for (int j = 0; j < 8; ++j) r[j] = (short)f2h(acc[j]);
        *(short8*)(Oh + (size_t)d * F + o) = r;
    } else {
        float* po = Of + (size_t)d * F + o;
        #pragma unroll
        for (int j4 = 0; j4 < 2; ++j4) {
            float4 r;
            r.x = acc[j4 * 4 + 0]; r.y = acc[j4 * 4 + 1];
            r.z = acc[j4 * 4 + 2]; r.w = acc[j4 * 4 + 3];
            *(float4*)&po[j4 * 4] = r;
        }
    }
}

// ---------------------------------------------------------------------------
extern "C" void kernel_launch(void* const* d_in, const int* in_sizes, int n_in,
                              void* d_out, int out_size, void* d_ws, size_t ws_size,
                              hipStream_t stream) {
    const float* x      = (const float*)d_in[0];
    const int*   ei     = (const int*)d_in[1];
    const float* proj_W = (const float*)d_in[2];
    const float* proj_b = (const float*)d_in[3];
    const float* W1  = (const float*)d_in[4];
    const float* as1 = (const float*)d_in[5];
    const float* ad1 = (const float*)d_in[6];
    const float* b1  = (const float*)d_in[7];
    const float* W2  = (const float*)d_in[8];
    const float* as2 = (const float*)d_in[9];
    const float* ad2 = (const float*)d_in[10];
    const float* b2  = (const float*)d_in[11];
    const float* W3  = (const float*)d_in[12];
    const float* as3 = (const float*)d_in[13];
    const float* ad3 = (const float*)d_in[14];
    const float* b3  = (const float*)d_in[15];

    const int N  = in_sizes[0] / 256;   // 10000
    const int E  = in_sizes[1] / 2;     // 160000
    const int Ep = E + N;
    const int NB = (N + 255) / 256;     // 40 scan blocks

    size_t off = 0;
    auto alloc = [&](size_t bytes) -> void* {
        void* p = (char*)d_ws + off;
        off += (bytes + 255) & ~(size_t)255;
        return p;
    };
    u16* bufX    = (u16*)alloc((size_t)N * 2048 * 2);   // fp16 h  (40 MB)
    u16* bufY    = (u16*)alloc((size_t)N * 2048 * 2);   // fp16 h' (40 MB)
    u16* xb_hi   = (u16*)alloc((size_t)N * 256 * 2);
    u16* xb_lo   = (u16*)alloc((size_t)N * 256 * 2);
    u16* pw_hi   = (u16*)alloc((size_t)256 * 512 * 2);  // proj_W flat planes
    u16* pw_lo   = (u16*)alloc((size_t)256 * 512 * 2);
    u16* wf_hi   = (u16*)alloc((size_t)2048 * 256 * 2); // Wfold^T planes
    u16* wf_lo   = (u16*)alloc((size_t)2048 * 256 * 2);
    float* bfold   = (float*)alloc((size_t)2048 * 4);
    float* att_z   = (float*)alloc((size_t)N * 18 * 4); // a_src/a_dst x3 layers
    float* alpha   = (float*)alloc((size_t)Ep * 4 * 4);
    int*   deg     = (int*)alloc((size_t)N * 4);
    int*   cursor  = (int*)alloc((size_t)N * 4);
    int*   row_ptr = (int*)alloc((size_t)(N + 1) * 4);
    int*   col_src = (int*)alloc((size_t)Ep * 4);
    int*   bsum    = (int*)alloc((size_t)NB * 4);
    int*   boff    = (int*)alloc((size_t)NB * 4);
    (void)ws_size;

    float* a_src1 = att_z;
    float* a_dst1 = att_z + (size_t)N * 4;
    float* a_src2 = att_z + (size_t)N * 8;
    float* a_dst2 = att_z + (size_t)N * 12;
    float* a_src3 = att_z + (size_t)N * 16;
    float* a_dst3 = att_z + (size_t)N * 17;

    // JIT weight planes in d_out (16.78 MB <= 20.48 MB); fully overwritten
    // by the final aggregate afterwards.
    u16* whi = (u16*)d_out;
    u16* wlo = (u16*)d_out + (size_t)2048 * 2048;

    // ---- CSR build + zero att accumulators ----
    hipMemsetAsync(deg, 0, (size_t)N * 4, stream);
    hipMemsetAsync(att_z, 0, (size_t)N * 18 * 4, stream);
    int eb = (Ep + 255) / 256;
    k_deg<<<eb, 256, 0, stream>>>(ei, E, N, deg);
    k_s1<<<NB, 256, 0, stream>>>(deg, row_ptr, bsum, N);
    k_s2<<<1, 64, 0, stream>>>(bsum, boff, NB);
    k_s3<<<NB, 256, 0, stream>>>(deg, row_ptr, boff, cursor, N);
    k_fill<<<eb, 256, 0, stream>>>(ei, E, N, cursor, col_src);

    const int MB1 = (N + 127) / 128;  // 79

    // ---- pack x [N,256] and proj_W (flat [256x512]) into bf16 planes ----
    k_pack<<<(N * 256 / 4 + 255) / 256, 256, 0, stream>>>(x, xb_hi, xb_lo, N * 256 / 4);
    k_pack<<<(256 * 512 / 4 + 255) / 256, 256, 0, stream>>>(proj_W, pw_hi, pw_lo, 256 * 512 / 4);

    // ---- W1^T planes; fold: Wfold^T = W1^T @ proj_W^T; bfold = pb @ W1 ----
    k_wt_pack<false><<<dim3(2048 / 32, 512 / 32), 256, 0, stream>>>(W1, whi, wlo, 512, 2048);
    k_bfold<<<2048, 64, 0, stream>>>(proj_b, whi, wlo, bfold, 512);
    // C[n][k] = sum_j W1t[n][j] * projW[k][j]  -> Wfold^T [2048][256] planes
    k_gemm_pl<2, 0, 0, false><<<dim3(256 / 64, 2048 / 128), 256, 0, stream>>>(
        whi, wlo, pw_hi, pw_lo, nullptr, wf_hi, wf_lo, nullptr,
        nullptr, nullptr, nullptr, nullptr, 0, 2048, 512, 256);

    // ---- layer 1 (K=256 folded; split-bf16 3-product; fp16 h out;
    //      exact fused logits include bfold) ----
    k_gemm_pl<4, 0, 2, true><<<dim3(2048 / 128, MB1), 256, 0, stream>>>(
        xb_hi, xb_lo, wf_hi, wf_lo, bfold, nullptr, nullptr, bufX,
        as1, ad1, a_src1, a_dst1, 4, N, 256, 2048);
    k_softmax<4><<<N, 64, 0, stream>>>(row_ptr, col_src, a_src1, a_dst1, alpha);
    k_agg<0, true><<<N, 256, 0, stream>>>(row_ptr, col_src, alpha, bufX,
                                          b1, bufY, nullptr, 4, 512);

    // ---- layer 2 (fp16 2-product: A=h1' fp16, B=W2 fp16 hi/lo) ----
    k_wt_pack<true><<<dim3(2048 / 32, 2048 / 32), 256, 0, stream>>>(W2, whi, wlo, 2048, 2048);
    k_gemm_pl<4, 1, 2, true><<<dim3(2048 / 128, MB1), 256, 0, stream>>>(
        bufY, nullptr, whi, wlo, nullptr, nullptr, nullptr, bufX,
        as2, ad2, a_src2, a_dst2, 4, N, 2048, 2048);
    k_softmax<4><<<N, 64, 0, stream>>>(row_ptr, col_src, a_src2, a_dst2, alpha);
    k_agg<0, true><<<N, 256, 0, stream>>>(row_ptr, col_src, alpha, bufX,
                                          b2, bufY, nullptr, 4, 512);

    // ---- layer 3 (fp16 2-product; single head -> mean = identity) ----
    k_wt_pack<true><<<dim3(512 / 32, 2048 / 32), 256, 0, stream>>>(W3, whi, wlo, 2048, 512);
    k_gemm_pl<2, 1, 2, true><<<dim3(512 / 64, MB1), 256, 0, stream>>>(
        bufY, nullptr, whi, wlo, nullptr, nullptr, nullptr, bufX,
        as3, ad3, a_src3, a_dst3, 1, N, 2048, 512);
    k_softmax<1><<<N, 64, 0, stream>>>(row_ptr, col_src, a_src3, a_dst3, alpha);
    k_agg<1, false><<<N, 64, 0, stream>>>(row_ptr, col_src, alpha, bufX,
                                          b3, nullptr, (float*)d_out, 1, 512);
}

// Round 14
// 638.009 us; speedup vs baseline: 2.4710x; 1.1896x over previous
//
#include <hip/hip_runtime.h>
#include <hip/hip_bf16.h>

// ---------------------------------------------------------------------------
// GAT encoder, round 14.
//  * GEMM2/GEMM3: SINGLE-product fp16 MFMA (A = fp16 payload, B = fp16 W).
//    W-fp16 rounding injects h2-class error == what r10 proved invisible.
//    MFMA/K-step halves, B staging halves. W2/W3 packed hi-plane only.
//  * proj folded into GEMM1 (r13): h1 = x@(Wp W1) + bp@W1, K=256.
//  * GEMM1 + fold GEMM: split-bf16 3-product (exact-ish logits).
//  * fp16 payloads everywhere; logits always exact-fused from fp32 acc.
//  * k_agg depth-1 prefetch kept.
// ---------------------------------------------------------------------------

#define LB(x) __launch_bounds__(x)

typedef unsigned short u16;
typedef unsigned int u32;
typedef __attribute__((ext_vector_type(8))) short short8;
typedef __attribute__((ext_vector_type(8))) short bf16x8;
typedef __attribute__((ext_vector_type(8))) _Float16 f16x8;
typedef __attribute__((ext_vector_type(4))) float f32x4;

__device__ __forceinline__ float b2f(u16 u) {
    union { float f; u32 u; } x;
    x.u = ((u32)u) << 16;
    return x.f;
}
__device__ __forceinline__ u16 f2b(float f) {
    u32 u = __float_as_uint(f);
    u = (u + 0x7FFFu + ((u >> 16) & 1u)) >> 16;   // RNE
    return (u16)u;
}
__device__ __forceinline__ u16 f2h(float f) {
    union { _Float16 h; u16 u; } x;
    x.h = (_Float16)f;
    return x.u;
}
__device__ __forceinline__ float h2f(u16 u) {
    union { _Float16 h; u16 u; } x;
    x.u = u;
    return (float)x.h;
}
__device__ __forceinline__ void lds_cp16(const void* g, void* l) {
    __builtin_amdgcn_global_load_lds(
        (const __attribute__((address_space(1))) unsigned int*)g,
        (__attribute__((address_space(3))) unsigned int*)l, 16, 0, 0);
}

// ---------------- CSR build ----------------
__global__ void k_deg(const int* __restrict__ ei, int E, int Np, int* __restrict__ deg) {
    int e = blockIdx.x * blockDim.x + threadIdx.x;
    if (e >= E + Np) return;
    int dst = (e < E) ? ei[E + e] : (e - E);
    atomicAdd(&deg[dst], 1);
}

__global__ LB(256) void k_s1(const int* __restrict__ deg, int* __restrict__ row_ptr,
                             int* __restrict__ bsum, int n) {
    __shared__ int sh[256];
    int b = blockIdx.x, t = threadIdx.x;
    int i = b * 256 + t;
    int v = (i < n) ? deg[i] : 0;
    sh[t] = v;
    __syncthreads();
    #pragma unroll
    for (int off = 1; off < 256; off <<= 1) {
        int add = (t >= off) ? sh[t - off] : 0;
        __syncthreads();
        sh[t] += add;
        __syncthreads();
    }
    if (i < n) row_ptr[i + 1] = sh[t];
    if (t == 255) bsum[b] = sh[255];
}

__global__ LB(64) void k_s2(int* __restrict__ bsum, int* __restrict__ boff, int nb) {
    __shared__ int sh[64];
    int t = threadIdx.x;
    sh[t] = (t < nb) ? bsum[t] : 0;
    __syncthreads();
    #pragma unroll
    for (int off = 1; off < 64; off <<= 1) {
        int add = (t >= off) ? sh[t - off] : 0;
        __syncthreads();
        sh[t] += add;
        __syncthreads();
    }
    if (t < nb) boff[t] = (t == 0) ? 0 : sh[t - 1];
}

__global__ LB(256) void k_s3(const int* __restrict__ deg, int* __restrict__ row_ptr,
                             const int* __restrict__ boff, int* __restrict__ cursor, int n) {
    int b = blockIdx.x, t = threadIdx.x;
    int i = b * 256 + t;
    if (i == 0) row_ptr[0] = 0;
    if (i < n) {
        int inc = row_ptr[i + 1] + boff[b];
        row_ptr[i + 1] = inc;
        cursor[i] = inc - deg[i];
    }
}

__global__ void k_fill(const int* __restrict__ ei, int E, int Np,
                       int* __restrict__ cursor, int* __restrict__ col_src) {
    int e = blockIdx.x * blockDim.x + threadIdx.x;
    if (e >= E + Np) return;
    int src, dst;
    if (e < E) { src = ei[e]; dst = ei[E + e]; }
    else       { src = dst = e - E; }
    int pos = atomicAdd(&cursor[dst], 1);
    col_src[pos] = src;
}

// ---------------- fp32 -> bf16 hi/lo planes (flat) ----------------
__global__ void k_pack(const float* __restrict__ in, u16* __restrict__ hi,
                       u16* __restrict__ lo, int n4) {
    int i = blockIdx.x * blockDim.x + threadIdx.x;
    if (i >= n4) return;
    float4 v = ((const float4*)in)[i];
    ushort4 h, l;
    h.x = f2b(v.x); l.x = f2b(v.x - b2f(h.x));
    h.y = f2b(v.y); l.y = f2b(v.y - b2f(h.y));
    h.z = f2b(v.z); l.z = f2b(v.z - b2f(h.z));
    h.w = f2b(v.w); l.w = f2b(v.w - b2f(h.w));
    ((ushort4*)hi)[i] = h;
    ((ushort4*)lo)[i] = l;
}

// ---------------- weight transpose + pack ----------------
// F16S = false: bf16 hi/lo split planes. F16S = true: single fp16 plane.
template<bool F16S>
__global__ LB(256) void k_wt_pack(const float* __restrict__ W, u16* __restrict__ Whi,
                                  u16* __restrict__ Wlo, int K, int Nn) {
    __shared__ float sh[32][33];
    int n0 = blockIdx.x * 32, k0 = blockIdx.y * 32;
    int c = threadIdx.x & 31, r0 = threadIdx.x >> 5;
    #pragma unroll
    for (int r = r0; r < 32; r += 8)
        sh[r][c] = W[(size_t)(k0 + r) * Nn + n0 + c];
    __syncthreads();
    #pragma unroll
    for (int r = r0; r < 32; r += 8) {
        float v = sh[c][r];
        if (F16S) {
            Whi[(size_t)(n0 + r) * K + k0 + c] = f2h(v);
        } else {
            u16 hi = f2b(v);
            Whi[(size_t)(n0 + r) * K + k0 + c] = hi;
            Wlo[(size_t)(n0 + r) * K + k0 + c] = f2b(v - b2f(hi));
        }
    }
}

// ---------------- bias fold: bfold[n] = sum_k pb[k] * W1[k][n] ------------
// W1 given as transposed bf16 planes w1t[n][k] (hi+lo). One wave per n.
__global__ LB(64) void k_bfold(const float* __restrict__ pb,
                               const u16* __restrict__ w1t_hi, const u16* __restrict__ w1t_lo,
                               float* __restrict__ bfold, int K) {
    int n = blockIdx.x;
    int lane = threadIdx.x;
    float s = 0.f;
    for (int k = lane; k < K; k += 64) {
        float w = b2f(w1t_hi[(size_t)n * K + k]) + b2f(w1t_lo[(size_t)n * K + k]);
        s = fmaf(pb[k], w, s);
    }
    #pragma unroll
    for (int off = 32; off; off >>= 1) s += __shfl_xor(s, off);
    if (lane == 0) bfold[n] = s;
}

// ---------------- MFMA GEMM: C = A[M,K] @ Bt[Nn,K]^T -----------------------
// BM=128, BK=32, 4 waves (2x2). LDS XOR swizzle (row&7)<<4 with inverse-
// permuted global_load_lds source.
// PREC 0: A,B = bf16 hi/lo planes, 3-product (emulated ~fp32).
// PREC 2: A = fp16 plane, B = fp16 plane, single product.
// OUTMODE 0: bf16 hi/lo planes. OUTMODE 2: fp16 plane. bias added in
// epilogue (pre-store AND pre-logit).
// ATT: fused exact logits ((acc+bias) . att_{s,d}, 16-lane reduce, atomicAdd).
template<int NFR, int PREC, int OUTMODE, bool ATT>
__global__ LB(256) void k_gemm_pl(const u16* __restrict__ Ahi, const u16* __restrict__ Alo,
                                  const u16* __restrict__ Bhi, const u16* __restrict__ Blo,
                                  const float* __restrict__ bias,
                                  u16* __restrict__ Chi, u16* __restrict__ Clo,
                                  u16* __restrict__ Cf16,
                                  const float* __restrict__ att_s, const float* __restrict__ att_d,
                                  float* __restrict__ a_src, float* __restrict__ a_dst,
                                  int HH, int M, int K, int Nn) {
    constexpr int BN = NFR * 32;
    constexpr int ALO_SZ = (PREC == 0) ? 128 * 32 : 8;
    constexpr int BLO_SZ = (PREC == 0) ? BN * 32 : 8;
    __shared__ u16 AsHi[128 * 32];
    __shared__ u16 AsLo[ALO_SZ];
    __shared__ u16 BsHi[BN * 32];
    __shared__ u16 BsLo[BLO_SZ];
    const int tid  = threadIdx.x;
    const int lane = tid & 63;
    const int w    = tid >> 6;
    const int wr   = w >> 1;
    const int wc   = w & 1;
    const int row0 = blockIdx.y * 128;
    const int col0 = blockIdx.x * BN;
    const int ln15 = lane & 15;
    const int lq   = lane >> 4;

    f32x4 acc[4][NFR];
    #pragma unroll
    for (int m = 0; m < 4; ++m)
        #pragma unroll
        for (int n = 0; n < NFR; ++n) acc[m][n] = (f32x4){0.f, 0.f, 0.f, 0.f};

    for (int k0 = 0; k0 < K; k0 += 32) {
        // A: 512 16B-chunks per plane, 2 per thread.
        #pragma unroll
        for (int i = 0; i < 2; ++i) {
            int c = i * 256 + tid;
            int r  = 2 * (c >> 3) + (((c >> 2) ^ (c >> 4)) & 1);   // inverse swizzle
            int kc = (c & 3) ^ (r & 3);
            int gra = row0 + r; if (gra >= M) gra = M - 1;          // tail clamp
            size_t ga = (size_t)gra * K + k0 + kc * 8;
            lds_cp16(Ahi + ga, (char*)AsHi + c * 16);
            if (PREC == 0) lds_cp16(Alo + ga, (char*)AsLo + c * 16);
        }
        // B: BN*4 chunks per plane, NFR/2 per thread per plane.
        #pragma unroll
        for (int i = 0; i < NFR / 2; ++i) {
            int c = i * 256 + tid;
            int r  = 2 * (c >> 3) + (((c >> 2) ^ (c >> 4)) & 1);
            int kc = (c & 3) ^ (r & 3);
            size_t gb = (size_t)(col0 + r) * K + k0 + kc * 8;
            lds_cp16(Bhi + gb, (char*)BsHi + c * 16);
            if (PREC == 0) lds_cp16(Blo + gb, (char*)BsLo + c * 16);
        }
        __syncthreads();
        if (PREC == 0) {
            bf16x8 ah[4], al[4], bh[NFR], bl[NFR];
            #pragma unroll
            for (int m = 0; m < 4; ++m) {
                int row = wr * 64 + m * 16 + ln15;
                int byo = (row * 64 + lq * 16) ^ ((row & 7) << 4);
                ah[m] = *(const bf16x8*)((const char*)AsHi + byo);
                al[m] = *(const bf16x8*)((const char*)AsLo + byo);
            }
            #pragma unroll
            for (int n = 0; n < NFR; ++n) {
                int row = wc * (NFR * 16) + n * 16 + ln15;
                int byo = (row * 64 + lq * 16) ^ ((row & 7) << 4);
                bh[n] = *(const bf16x8*)((const char*)BsHi + byo);
                bl[n] = *(const bf16x8*)((const char*)BsLo + byo);
            }
            #pragma unroll
            for (int m = 0; m < 4; ++m)
                #pragma unroll
                for (int n = 0; n < NFR; ++n) {
                    acc[m][n] = __builtin_amdgcn_mfma_f32_16x16x32_bf16(al[m], bh[n], acc[m][n], 0, 0, 0);
                    acc[m][n] = __builtin_amdgcn_mfma_f32_16x16x32_bf16(ah[m], bl[n], acc[m][n], 0, 0, 0);
                    acc[m][n] = __builtin_amdgcn_mfma_f32_16x16x32_bf16(ah[m], bh[n], acc[m][n], 0, 0, 0);
                }
        } else {
            f16x8 a[4], b[NFR];
            #pragma unroll
            for (int m = 0; m < 4; ++m) {
                int row = wr * 64 + m * 16 + ln15;
                int byo = (row * 64 + lq * 16) ^ ((row & 7) << 4);
                a[m] = *(const f16x8*)((const char*)AsHi + byo);
            }
            #pragma unroll
            for (int n = 0; n < NFR; ++n) {
                int row = wc * (NFR * 16) + n * 16 + ln15;
                int byo = (row * 64 + lq * 16) ^ ((row & 7) << 4);
                b[n] = *(const f16x8*)((const char*)BsHi + byo);
            }
            #pragma unroll
            for (int m = 0; m < 4; ++m)
                #pragma unroll
                for (int n = 0; n < NFR; ++n)
                    acc[m][n] = __builtin_amdgcn_mfma_f32_16x16x32_f16(a[m], b[n], acc[m][n], 0, 0, 0);
        }
        __syncthreads();
    }

    // D: col = lane&15, row = (lane>>4)*4 + j  [m89/m91-verified]
    #pragma unroll
    for (int m = 0; m < 4; ++m) {
        #pragma unroll
        for (int n = 0; n < NFR; ++n) {
            int gc = col0 + wc * (NFR * 16) + n * 16 + ln15;
            float badd = bias ? bias[gc] : 0.f;
            #pragma unroll
            for (int j = 0; j < 4; ++j) {
                int gr = row0 + wr * 64 + m * 16 + lq * 4 + j;
                if (gr < M) {
                    float v = acc[m][n][j] + badd;
                    size_t o = (size_t)gr * Nn + gc;
                    if (OUTMODE == 0) {
                        u16 hi = f2b(v);
                        Chi[o] = hi;
                        Clo[o] = f2b(v - b2f(hi));
                    } else {
                        Cf16[o] = f2h(v);
                    }
                }
            }
        }
    }

    if (ATT) {
        float atts[NFR], attd[NFR], bb[NFR];
        #pragma unroll
        for (int n = 0; n < NFR; ++n) {
            int gc = col0 + wc * (NFR * 16) + n * 16 + ln15;
            atts[n] = att_s[gc];
            attd[n] = att_d[gc];
            bb[n]   = bias ? bias[gc] : 0.f;
        }
        const int head = (col0 + wc * (NFR * 16)) >> 9;   // /512, wave-uniform
        #pragma unroll
        for (int m = 0; m < 4; ++m) {
            #pragma unroll
            for (int j = 0; j < 4; ++j) {
                int gr = row0 + wr * 64 + m * 16 + lq * 4 + j;
                float s1 = 0.f, s2 = 0.f;
                #pragma unroll
                for (int n = 0; n < NFR; ++n) {
                    float v = acc[m][n][j] + bb[n];
                    s1 = fmaf(v, atts[n], s1);
                    s2 = fmaf(v, attd[n], s2);
                }
                #pragma unroll
                for (int off = 1; off < 16; off <<= 1) {
                    s1 += __shfl_xor(s1, off);
                    s2 += __shfl_xor(s2, off);
                }
                if (ln15 == 0 && gr < M) {
                    atomicAdd(&a_src[gr * HH + head], s1);
                    atomicAdd(&a_dst[gr * HH + head], s2);
                }
            }
        }
    }
}

// ---------------- fused segment softmax per dst (one wave) ----------------
template<int HH>
__global__ LB(64) void k_softmax(const int* __restrict__ row_ptr, const int* __restrict__ col_src,
                                 const float* __restrict__ a_src, const float* __restrict__ a_dst,
                                 float* __restrict__ alpha) {
    int d = blockIdx.x;
    int t = threadIdx.x;
    int s = row_ptr[d], eend = row_ptr[d + 1];
    int cnt = eend - s;
    float adh[HH];
    #pragma unroll
    for (int h = 0; h < HH; ++h) adh[h] = a_dst[d * HH + h];

    if (cnt <= 64) {
        bool act = t < cnt;
        float av[HH];
        #pragma unroll
        for (int h = 0; h < HH; ++h) av[h] = 0.f;
        if (act) {
            int src = col_src[s + t];
            if (HH == 4) {
                float4 q = ((const float4*)a_src)[src];
                av[0] = q.x; av[1] = q.y; av[2] = q.z; av[3] = q.w;
            } else {
                av[0] = a_src[src];
            }
        }
        float v[HH], m[HH], sum[HH];
        #pragma unroll
        for (int h = 0; h < HH; ++h) {
            float x = av[h] + adh[h];
            x = (x > 0.f) ? x : 0.2f * x;
            v[h] = act ? x : -1e30f;
            m[h] = v[h];
        }
        #pragma unroll
        for (int off = 32; off; off >>= 1)
            #pragma unroll
            for (int h = 0; h < HH; ++h) m[h] = fmaxf(m[h], __shfl_xor(m[h], off));
        #pragma unroll
        for (int h = 0; h < HH; ++h) {
            float e = act ? __expf(v[h] - m[h]) : 0.f;
            v[h] = e;
            sum[h] = e;
        }
        #pragma unroll
        for (int off = 32; off; off >>= 1)
            #pragma unroll
            for (int h = 0; h < HH; ++h) sum[h] += __shfl_xor(sum[h], off);
        if (act) {
            if (HH == 4) {
                float4 o;
                o.x = v[0] / sum[0]; o.y = v[1] / sum[1];
                o.z = v[2] / sum[2]; o.w = v[3] / sum[3];
                ((float4*)alpha)[s + t] = o;
            } else {
                alpha[s + t] = v[0] / sum[0];
            }
        }
        return;
    }

    // generic fallback (deg > 64): 3-pass recompute
    for (int h = 0; h < HH; ++h) {
        float m = -1e30f;
        for (int e = s + t; e < eend; e += 64) {
            float x = a_src[col_src[e] * HH + h] + adh[h];
            x = (x > 0.f) ? x : 0.2f * x;
            m = fmaxf(m, x);
        }
        #pragma unroll
        for (int off = 32; off; off >>= 1) m = fmaxf(m, __shfl_xor(m, off));
        float sum = 0.f;
        for (int e = s + t; e < eend; e += 64) {
            float x = a_src[col_src[e] * HH + h] + adh[h];
            x = (x > 0.f) ? x : 0.2f * x;
            sum += __expf(x - m);
        }
        #pragma unroll
        for (int off = 32; off; off >>= 1) sum += __shfl_xor(sum, off);
        float inv = 1.0f / sum;
        for (int e = s + t; e < eend; e += 64) {
            float x = a_src[col_src[e] * HH + h] + adh[h];
            x = (x > 0.f) ? x : 0.2f * x;
            alpha[e * HH + h] = __expf(x - m) * inv;
        }
    }
}

// ---------------- aggregate: out[d] = sum_e alpha[e,h]*h[src] (+bias,ELU) --
// fp16 h gather, depth-1 prefetch (single accumulator -> FP order identical).
// OMODE 0: fp16 plane out. OMODE 1: fp32 final out.
template <int OMODE, bool ELU_>
__global__ LB(256) void k_agg(const int* __restrict__ row_ptr, const int* __restrict__ col_src,
                              const float* __restrict__ alpha, const u16* __restrict__ hf,
                              const float* __restrict__ bias,
                              u16* __restrict__ Oh, float* __restrict__ Of, int H, int C) {
    int d = blockIdx.x;
    int tid = threadIdx.x;
    int F = H * C;
    int o = tid * 8;
    int h0 = o / C;   // wave-uniform for C=512
    float acc[8];
    #pragma unroll
    for (int j = 0; j < 8; ++j) acc[j] = 0.f;
    int s = row_ptr[d], eend = row_ptr[d + 1];

    short8 v; float a;
    if (s < eend) {
        int src = col_src[s];
        a = alpha[s * H + h0];
        v = *(const short8*)(hf + (size_t)src * F + o);
    }
    for (int e = s; e < eend; ++e) {
        short8 w_; float an;
        bool more = (e + 1 < eend);           // block-uniform branch
        if (more) {
            int srcn = col_src[e + 1];
            an = alpha[(e + 1) * H + h0];
            w_ = *(const short8*)(hf + (size_t)srcn * F + o);
        }
        #pragma unroll
        for (int j = 0; j < 8; ++j)
            acc[j] = fmaf(a, h2f((u16)v[j]), acc[j]);
        if (more) { a = an; v = w_; }
    }

    #pragma unroll
    for (int j = 0; j < 8; ++j) {
        acc[j] += bias[o + j];
        if (ELU_) acc[j] = (acc[j] > 0.f) ? acc[j] : __expf(acc[j]) - 1.f;
    }
    if (OMODE == 0) {
        short8 r;
        #pragma unroll
        for (int j = 0; j < 8; ++j) r[j] = (short)f2h(acc[j]);
        *(short8*)(Oh + (size_t)d * F + o) = r;
    } else {
        float* po = Of + (size_t)d * F + o;
        #pragma unroll
        for (int j4 = 0; j4 < 2; ++j4) {
            float4 r;
            r.x = acc[j4 * 4 + 0]; r.y = acc[j4 * 4 + 1];
            r.z = acc[j4 * 4 + 2]; r.w = acc[j4 * 4 + 3];
            *(float4*)&po[j4 * 4] = r;
        }
    }
}

// ---------------------------------------------------------------------------
extern "C" void kernel_launch(void* const* d_in, const int* in_sizes, int n_in,
                              void* d_out, int out_size, void* d_ws, size_t ws_size,
                              hipStream_t stream) {
    const float* x      = (const float*)d_in[0];
    const int*   ei     = (const int*)d_in[1];
    const float* proj_W = (const float*)d_in[2];
    const float* proj_b = (const float*)d_in[3];
    const float* W1  = (const float*)d_in[4];
    const float* as1 = (const float*)d_in[5];
    const float* ad1 = (const float*)d_in[6];
    const float* b1  = (const float*)d_in[7];
    const float* W2  = (const float*)d_in[8];
    const float* as2 = (const float*)d_in[9];
    const float* ad2 = (const float*)d_in[10];
    const float* b2  = (const float*)d_in[11];
    const float* W3  = (const float*)d_in[12];
    const float* as3 = (const float*)d_in[13];
    const float* ad3 = (const float*)d_in[14];
    const float* b3  = (const float*)d_in[15];

    const int N  = in_sizes[0] / 256;   // 10000
    const int E  = in_sizes[1] / 2;     // 160000
    const int Ep = E + N;
    const int NB = (N + 255) / 256;     // 40 scan blocks

    size_t off = 0;
    auto alloc = [&](size_t bytes) -> void* {
        void* p = (char*)d_ws + off;
        off += (bytes + 255) & ~(size_t)255;
        return p;
    };
    u16* bufX    = (u16*)alloc((size_t)N * 2048 * 2);   // fp16 h  (40 MB)
    u16* bufY    = (u16*)alloc((size_t)N * 2048 * 2);   // fp16 h' (40 MB)
    u16* xb_hi   = (u16*)alloc((size_t)N * 256 * 2);
    u16* xb_lo   = (u16*)alloc((size_t)N * 256 * 2);
    u16* pw_hi   = (u16*)alloc((size_t)256 * 512 * 2);  // proj_W flat planes
    u16* pw_lo   = (u16*)alloc((size_t)256 * 512 * 2);
    u16* wf_hi   = (u16*)alloc((size_t)2048 * 256 * 2); // Wfold^T planes
    u16* wf_lo   = (u16*)alloc((size_t)2048 * 256 * 2);
    float* bfold   = (float*)alloc((size_t)2048 * 4);
    float* att_z   = (float*)alloc((size_t)N * 18 * 4); // a_src/a_dst x3 layers
    float* alpha   = (float*)alloc((size_t)Ep * 4 * 4);
    int*   deg     = (int*)alloc((size_t)N * 4);
    int*   cursor  = (int*)alloc((size_t)N * 4);
    int*   row_ptr = (int*)alloc((size_t)(N + 1) * 4);
    int*   col_src = (int*)alloc((size_t)Ep * 4);
    int*   bsum    = (int*)alloc((size_t)NB * 4);
    int*   boff    = (int*)alloc((size_t)NB * 4);
    (void)ws_size;

    float* a_src1 = att_z;
    float* a_dst1 = att_z + (size_t)N * 4;
    float* a_src2 = att_z + (size_t)N * 8;
    float* a_dst2 = att_z + (size_t)N * 12;
    float* a_src3 = att_z + (size_t)N * 16;
    float* a_dst3 = att_z + (size_t)N * 17;

    // JIT weight planes in d_out (16.78 MB <= 20.48 MB); fully overwritten
    // by the final aggregate afterwards.
    u16* whi = (u16*)d_out;
    u16* wlo = (u16*)d_out + (size_t)2048 * 2048;

    // ---- CSR build + zero att accumulators ----
    hipMemsetAsync(deg, 0, (size_t)N * 4, stream);
    hipMemsetAsync(att_z, 0, (size_t)N * 18 * 4, stream);
    int eb = (Ep + 255) / 256;
    k_deg<<<eb, 256, 0, stream>>>(ei, E, N, deg);
    k_s1<<<NB, 256, 0, stream>>>(deg, row_ptr, bsum, N);
    k_s2<<<1, 64, 0, stream>>>(bsum, boff, NB);
    k_s3<<<NB, 256, 0, stream>>>(deg, row_ptr, boff, cursor, N);
    k_fill<<<eb, 256, 0, stream>>>(ei, E, N, cursor, col_src);

    const int MB1 = (N + 127) / 128;  // 79

    // ---- pack x [N,256] and proj_W (flat [256x512]) into bf16 planes ----
    k_pack<<<(N * 256 / 4 + 255) / 256, 256, 0, stream>>>(x, xb_hi, xb_lo, N * 256 / 4);
    k_pack<<<(256 * 512 / 4 + 255) / 256, 256, 0, stream>>>(proj_W, pw_hi, pw_lo, 256 * 512 / 4);

    // ---- W1^T planes; fold: Wfold^T = W1^T @ proj_W^T; bfold = pb @ W1 ----
    k_wt_pack<false><<<dim3(2048 / 32, 512 / 32), 256, 0, stream>>>(W1, whi, wlo, 512, 2048);
    k_bfold<<<2048, 64, 0, stream>>>(proj_b, whi, wlo, bfold, 512);
    // C[n][k] = sum_j W1t[n][j] * projW[k][j]  -> Wfold^T [2048][256] planes
    k_gemm_pl<2, 0, 0, false><<<dim3(256 / 64, 2048 / 128), 256, 0, stream>>>(
        whi, wlo, pw_hi, pw_lo, nullptr, wf_hi, wf_lo, nullptr,
        nullptr, nullptr, nullptr, nullptr, 0, 2048, 512, 256);

    // ---- layer 1 (K=256 folded; split-bf16 3-product; fp16 h out;
    //      exact fused logits include bfold) ----
    k_gemm_pl<4, 0, 2, true><<<dim3(2048 / 128, MB1), 256, 0, stream>>>(
        xb_hi, xb_lo, wf_hi, wf_lo, bfold, nullptr, nullptr, bufX,
        as1, ad1, a_src1, a_dst1, 4, N, 256, 2048);
    k_softmax<4><<<N, 64, 0, stream>>>(row_ptr, col_src, a_src1, a_dst1, alpha);
    k_agg<0, true><<<N, 256, 0, stream>>>(row_ptr, col_src, alpha, bufX,
                                          b1, bufY, nullptr, 4, 512);

    // ---- layer 2 (single-product fp16: A=h1' fp16, B=W2 fp16) ----
    k_wt_pack<true><<<dim3(2048 / 32, 2048 / 32), 256, 0, stream>>>(W2, whi, nullptr, 2048, 2048);
    k_gemm_pl<4, 2, 2, true><<<dim3(2048 / 128, MB1), 256, 0, stream>>>(
        bufY, nullptr, whi, nullptr, nullptr, nullptr, nullptr, bufX,
        as2, ad2, a_src2, a_dst2, 4, N, 2048, 2048);
    k_softmax<4><<<N, 64, 0, stream>>>(row_ptr, col_src, a_src2, a_dst2, alpha);
    k_agg<0, true><<<N, 256, 0, stream>>>(row_ptr, col_src, alpha, bufX,
                                          b2, bufY, nullptr, 4, 512);

    // ---- layer 3 (single-product fp16; single head -> mean = identity) ----
    k_wt_pack<true><<<dim3(512 / 32, 2048 / 32), 256, 0, stream>>>(W3, whi, nullptr, 2048, 512);
    k_gemm_pl<2, 2, 2, true><<<dim3(512 / 64, MB1), 256, 0, stream>>>(
        bufY, nullptr, whi, nullptr, nullptr, nullptr, nullptr, bufX,
        as3, ad3, a_src3, a_dst3, 1, N, 2048, 512);
    k_softmax<1><<<N, 64, 0, stream>>>(row_ptr, col_src, a_src3, a_dst3, alpha);
    k_agg<1, false><<<N, 64, 0, stream>>>(row_ptr, col_src, alpha, bufX,
                                          b3, nullptr, (float*)d_out, 1, 512);
}

// Round 15
// 623.781 us; speedup vs baseline: 2.5273x; 1.0228x over previous
//
#include <hip/hip_runtime.h>
#include <hip/hip_bf16.h>

// ---------------------------------------------------------------------------
// GAT encoder, round 15.
//  * softmax FUSED into aggregate (k_sagg): wave w == head w; alpha computed
//    in-register (identical values/order), parked in LDS, gather loop reads
//    it locally. 3 softmax launches + alpha round-trip removed.
//  * GEMM2: BM=256 via 8 waves (512 thr), acc stays [4][4] (64 VGPR) --
//    barrier cost per output halves vs r14. Template param WM.
//  * GEMM2/3 single-product fp16 (r14); GEMM1+fold split-bf16 3-product;
//    proj folded (r13); fp16 payloads + exact fused logits (r10/r12).
// ---------------------------------------------------------------------------

#define LB(x) __launch_bounds__(x)

typedef unsigned short u16;
typedef unsigned int u32;
typedef __attribute__((ext_vector_type(8))) short short8;
typedef __attribute__((ext_vector_type(8))) short bf16x8;
typedef __attribute__((ext_vector_type(8))) _Float16 f16x8;
typedef __attribute__((ext_vector_type(4))) float f32x4;

__device__ __forceinline__ float b2f(u16 u) {
    union { float f; u32 u; } x;
    x.u = ((u32)u) << 16;
    return x.f;
}
__device__ __forceinline__ u16 f2b(float f) {
    u32 u = __float_as_uint(f);
    u = (u + 0x7FFFu + ((u >> 16) & 1u)) >> 16;   // RNE
    return (u16)u;
}
__device__ __forceinline__ u16 f2h(float f) {
    union { _Float16 h; u16 u; } x;
    x.h = (_Float16)f;
    return x.u;
}
__device__ __forceinline__ float h2f(u16 u) {
    union { _Float16 h; u16 u; } x;
    x.u = u;
    return (float)x.h;
}
__device__ __forceinline__ void lds_cp16(const void* g, void* l) {
    __builtin_amdgcn_global_load_lds(
        (const __attribute__((address_space(1))) unsigned int*)g,
        (__attribute__((address_space(3))) unsigned int*)l, 16, 0, 0);
}

// ---------------- CSR build ----------------
__global__ void k_deg(const int* __restrict__ ei, int E, int Np, int* __restrict__ deg) {
    int e = blockIdx.x * blockDim.x + threadIdx.x;
    if (e >= E + Np) return;
    int dst = (e < E) ? ei[E + e] : (e - E);
    atomicAdd(&deg[dst], 1);
}

__global__ LB(256) void k_s1(const int* __restrict__ deg, int* __restrict__ row_ptr,
                             int* __restrict__ bsum, int n) {
    __shared__ int sh[256];
    int b = blockIdx.x, t = threadIdx.x;
    int i = b * 256 + t;
    int v = (i < n) ? deg[i] : 0;
    sh[t] = v;
    __syncthreads();
    #pragma unroll
    for (int off = 1; off < 256; off <<= 1) {
        int add = (t >= off) ? sh[t - off] : 0;
        __syncthreads();
        sh[t] += add;
        __syncthreads();
    }
    if (i < n) row_ptr[i + 1] = sh[t];
    if (t == 255) bsum[b] = sh[255];
}

__global__ LB(64) void k_s2(int* __restrict__ bsum, int* __restrict__ boff, int nb) {
    __shared__ int sh[64];
    int t = threadIdx.x;
    sh[t] = (t < nb) ? bsum[t] : 0;
    __syncthreads();
    #pragma unroll
    for (int off = 1; off < 64; off <<= 1) {
        int add = (t >= off) ? sh[t - off] : 0;
        __syncthreads();
        sh[t] += add;
        __syncthreads();
    }
    if (t < nb) boff[t] = (t == 0) ? 0 : sh[t - 1];
}

__global__ LB(256) void k_s3(const int* __restrict__ deg, int* __restrict__ row_ptr,
                             const int* __restrict__ boff, int* __restrict__ cursor, int n) {
    int b = blockIdx.x, t = threadIdx.x;
    int i = b * 256 + t;
    if (i == 0) row_ptr[0] = 0;
    if (i < n) {
        int inc = row_ptr[i + 1] + boff[b];
        row_ptr[i + 1] = inc;
        cursor[i] = inc - deg[i];
    }
}

__global__ void k_fill(const int* __restrict__ ei, int E, int Np,
                       int* __restrict__ cursor, int* __restrict__ col_src) {
    int e = blockIdx.x * blockDim.x + threadIdx.x;
    if (e >= E + Np) return;
    int src, dst;
    if (e < E) { src = ei[e]; dst = ei[E + e]; }
    else       { src = dst = e - E; }
    int pos = atomicAdd(&cursor[dst], 1);
    col_src[pos] = src;
}

// ---------------- fp32 -> bf16 hi/lo planes (flat) ----------------
__global__ void k_pack(const float* __restrict__ in, u16* __restrict__ hi,
                       u16* __restrict__ lo, int n4) {
    int i = blockIdx.x * blockDim.x + threadIdx.x;
    if (i >= n4) return;
    float4 v = ((const float4*)in)[i];
    ushort4 h, l;
    h.x = f2b(v.x); l.x = f2b(v.x - b2f(h.x));
    h.y = f2b(v.y); l.y = f2b(v.y - b2f(h.y));
    h.z = f2b(v.z); l.z = f2b(v.z - b2f(h.z));
    h.w = f2b(v.w); l.w = f2b(v.w - b2f(h.w));
    ((ushort4*)hi)[i] = h;
    ((ushort4*)lo)[i] = l;
}

// ---------------- weight transpose + pack ----------------
// F16S = false: bf16 hi/lo split planes. F16S = true: single fp16 plane.
template<bool F16S>
__global__ LB(256) void k_wt_pack(const float* __restrict__ W, u16* __restrict__ Whi,
                                  u16* __restrict__ Wlo, int K, int Nn) {
    __shared__ float sh[32][33];
    int n0 = blockIdx.x * 32, k0 = blockIdx.y * 32;
    int c = threadIdx.x & 31, r0 = threadIdx.x >> 5;
    #pragma unroll
    for (int r = r0; r < 32; r += 8)
        sh[r][c] = W[(size_t)(k0 + r) * Nn + n0 + c];
    __syncthreads();
    #pragma unroll
    for (int r = r0; r < 32; r += 8) {
        float v = sh[c][r];
        if (F16S) {
            Whi[(size_t)(n0 + r) * K + k0 + c] = f2h(v);
        } else {
            u16 hi = f2b(v);
            Whi[(size_t)(n0 + r) * K + k0 + c] = hi;
            Wlo[(size_t)(n0 + r) * K + k0 + c] = f2b(v - b2f(hi));
        }
    }
}

// ---------------- bias fold: bfold[n] = sum_k pb[k] * W1[k][n] ------------
__global__ LB(64) void k_bfold(const float* __restrict__ pb,
                               const u16* __restrict__ w1t_hi, const u16* __restrict__ w1t_lo,
                               float* __restrict__ bfold, int K) {
    int n = blockIdx.x;
    int lane = threadIdx.x;
    float s = 0.f;
    for (int k = lane; k < K; k += 64) {
        float w = b2f(w1t_hi[(size_t)n * K + k]) + b2f(w1t_lo[(size_t)n * K + k]);
        s = fmaf(pb[k], w, s);
    }
    #pragma unroll
    for (int off = 32; off; off >>= 1) s += __shfl_xor(s, off);
    if (lane == 0) bfold[n] = s;
}

// ---------------- MFMA GEMM: C = A[M,K] @ Bt[Nn,K]^T -----------------------
// WM waves along M (BM = WM*64), 2 waves along N (BN = NFR*32), threads =
// WM*128, BK=32. LDS XOR swizzle (row&7)<<4, inverse-permuted source.
// PREC 0: A,B = bf16 hi/lo planes, 3-product. PREC 2: fp16 single product.
// OUTMODE 0: bf16 hi/lo planes. OUTMODE 2: fp16 plane. bias in epilogue
// (pre-store AND pre-logit). ATT: fused exact logits -> atomicAdd.
template<int WM, int NFR, int PREC, int OUTMODE, bool ATT>
__global__ __launch_bounds__(WM * 128)
void k_gemm_pl(const u16* __restrict__ Ahi, const u16* __restrict__ Alo,
               const u16* __restrict__ Bhi, const u16* __restrict__ Blo,
               const float* __restrict__ bias,
               u16* __restrict__ Chi, u16* __restrict__ Clo,
               u16* __restrict__ Cf16,
               const float* __restrict__ att_s, const float* __restrict__ att_d,
               float* __restrict__ a_src, float* __restrict__ a_dst,
               int HH, int M, int K, int Nn) {
    constexpr int BM = WM * 64;
    constexpr int BN = NFR * 32;
    constexpr int T  = WM * 128;
    constexpr int BITER = (NFR * 128) / T > 0 ? (NFR * 128) / T : 1;
    constexpr int ALO_SZ = (PREC == 0) ? BM * 32 : 8;
    constexpr int BLO_SZ = (PREC == 0) ? BN * 32 : 8;
    __shared__ u16 AsHi[BM * 32];
    __shared__ u16 AsLo[ALO_SZ];
    __shared__ u16 BsHi[BN * 32];
    __shared__ u16 BsLo[BLO_SZ];
    const int tid  = threadIdx.x;
    const int lane = tid & 63;
    const int w    = tid >> 6;
    const int wr   = w >> 1;          // 0..WM-1
    const int wc   = w & 1;
    const int row0 = blockIdx.y * BM;
    const int col0 = blockIdx.x * BN;
    const int ln15 = lane & 15;
    const int lq   = lane >> 4;

    f32x4 acc[4][NFR];
    #pragma unroll
    for (int m = 0; m < 4; ++m)
        #pragma unroll
        for (int n = 0; n < NFR; ++n) acc[m][n] = (f32x4){0.f, 0.f, 0.f, 0.f};

    for (int k0 = 0; k0 < K; k0 += 32) {
        // A: BM*4 16B-chunks per plane, 2 per thread.
        #pragma unroll
        for (int i = 0; i < 2; ++i) {
            int c = i * T + tid;
            int r  = 2 * (c >> 3) + (((c >> 2) ^ (c >> 4)) & 1);   // inverse swizzle
            int kc = (c & 3) ^ (r & 3);
            int gra = row0 + r; if (gra >= M) gra = M - 1;          // tail clamp
            size_t ga = (size_t)gra * K + k0 + kc * 8;
            lds_cp16(Ahi + ga, (char*)AsHi + c * 16);
            if (PREC == 0) lds_cp16(Alo + ga, (char*)AsLo + c * 16);
        }
        // B: BN*4 chunks per plane.
        #pragma unroll
        for (int i = 0; i < BITER; ++i) {
            int c = i * T + tid;
            int r  = 2 * (c >> 3) + (((c >> 2) ^ (c >> 4)) & 1);
            int kc = (c & 3) ^ (r & 3);
            size_t gb = (size_t)(col0 + r) * K + k0 + kc * 8;
            lds_cp16(Bhi + gb, (char*)BsHi + c * 16);
            if (PREC == 0) lds_cp16(Blo + gb, (char*)BsLo + c * 16);
        }
        __syncthreads();
        if (PREC == 0) {
            bf16x8 ah[4], al[4], bh[NFR], bl[NFR];
            #pragma unroll
            for (int m = 0; m < 4; ++m) {
                int row = wr * 64 + m * 16 + ln15;
                int byo = (row * 64 + lq * 16) ^ ((row & 7) << 4);
                ah[m] = *(const bf16x8*)((const char*)AsHi + byo);
                al[m] = *(const bf16x8*)((const char*)AsLo + byo);
            }
            #pragma unroll
            for (int n = 0; n < NFR; ++n) {
                int row = wc * (NFR * 16) + n * 16 + ln15;
                int byo = (row * 64 + lq * 16) ^ ((row & 7) << 4);
                bh[n] = *(const bf16x8*)((const char*)BsHi + byo);
                bl[n] = *(const bf16x8*)((const char*)BsLo + byo);
            }
            #pragma unroll
            for (int m = 0; m < 4; ++m)
                #pragma unroll
                for (int n = 0; n < NFR; ++n) {
                    acc[m][n] = __builtin_amdgcn_mfma_f32_16x16x32_bf16(al[m], bh[n], acc[m][n], 0, 0, 0);
                    acc[m][n] = __builtin_amdgcn_mfma_f32_16x16x32_bf16(ah[m], bl[n], acc[m][n], 0, 0, 0);
                    acc[m][n] = __builtin_amdgcn_mfma_f32_16x16x32_bf16(ah[m], bh[n], acc[m][n], 0, 0, 0);
                }
        } else {
            f16x8 a[4], b[NFR];
            #pragma unroll
            for (int m = 0; m < 4; ++m) {
                int row = wr * 64 + m * 16 + ln15;
                int byo = (row * 64 + lq * 16) ^ ((row & 7) << 4);
                a[m] = *(const f16x8*)((const char*)AsHi + byo);
            }
            #pragma unroll
            for (int n = 0; n < NFR; ++n) {
                int row = wc * (NFR * 16) + n * 16 + ln15;
                int byo = (row * 64 + lq * 16) ^ ((row & 7) << 4);
                b[n] = *(const f16x8*)((const char*)BsHi + byo);
            }
            #pragma unroll
            for (int m = 0; m < 4; ++m)
                #pragma unroll
                for (int n = 0; n < NFR; ++n)
                    acc[m][n] = __builtin_amdgcn_mfma_f32_16x16x32_f16(a[m], b[n], acc[m][n], 0, 0, 0);
        }
        __syncthreads();
    }

    // D: col = lane&15, row = (lane>>4)*4 + j  [m89/m91-verified]
    #pragma unroll
    for (int m = 0; m < 4; ++m) {
        #pragma unroll
        for (int n = 0; n < NFR; ++n) {
            int gc = col0 + wc * (NFR * 16) + n * 16 + ln15;
            float badd = bias ? bias[gc] : 0.f;
            #pragma unroll
            for (int j = 0; j < 4; ++j) {
                int gr = row0 + wr * 64 + m * 16 + lq * 4 + j;
                if (gr < M) {
                    float v = acc[m][n][j] + badd;
                    size_t o = (size_t)gr * Nn + gc;
                    if (OUTMODE == 0) {
                        u16 hi = f2b(v);
                        Chi[o] = hi;
                        Clo[o] = f2b(v - b2f(hi));
                    } else {
                        Cf16[o] = f2h(v);
                    }
                }
            }
        }
    }

    if (ATT) {
        float atts[NFR], attd[NFR], bb[NFR];
        #pragma unroll
        for (int n = 0; n < NFR; ++n) {
            int gc = col0 + wc * (NFR * 16) + n * 16 + ln15;
            atts[n] = att_s[gc];
            attd[n] = att_d[gc];
            bb[n]   = bias ? bias[gc] : 0.f;
        }
        const int head = (col0 + wc * (NFR * 16)) >> 9;   // /512, wave-uniform
        #pragma unroll
        for (int m = 0; m < 4; ++m) {
            #pragma unroll
            for (int j = 0; j < 4; ++j) {
                int gr = row0 + wr * 64 + m * 16 + lq * 4 + j;
                float s1 = 0.f, s2 = 0.f;
                #pragma unroll
                for (int n = 0; n < NFR; ++n) {
                    float v = acc[m][n][j] + bb[n];
                    s1 = fmaf(v, atts[n], s1);
                    s2 = fmaf(v, attd[n], s2);
                }
                #pragma unroll
                for (int off = 1; off < 16; off <<= 1) {
                    s1 += __shfl_xor(s1, off);
                    s2 += __shfl_xor(s2, off);
                }
                if (ln15 == 0 && gr < M) {
                    atomicAdd(&a_src[gr * HH + head], s1);
                    atomicAdd(&a_dst[gr * HH + head], s2);
                }
            }
        }
    }
}

// ---------------- fused softmax + aggregate (one block per dst) ------------
// HH waves; wave w == head w (64 lanes x 8 feats = 512 = C). Alpha computed
// in-register (same values/order as the old k_softmax), parked in LDS,
// gather loop reads it locally. OMODE 0: fp16 plane out; 1: fp32 final out.
template <int HH, int OMODE, bool ELU_>
__global__ __launch_bounds__(HH * 64)
void k_sagg(const int* __restrict__ row_ptr, const int* __restrict__ col_src,
            const float* __restrict__ a_src, const float* __restrict__ a_dst,
            const u16* __restrict__ hf, const float* __restrict__ bias,
            u16* __restrict__ Oh, float* __restrict__ Of, int C) {
    __shared__ float sal[HH * 64];
    const int d    = blockIdx.x;
    const int tid  = threadIdx.x;
    const int w    = tid >> 6;       // head
    const int lane = tid & 63;
    const int F    = HH * C;
    const int o    = tid * 8;
    const int s = row_ptr[d], eend = row_ptr[d + 1];
    const int cnt = eend - s;
    const float adh = a_dst[d * HH + w];

    float acc[8];
    #pragma unroll
    for (int j = 0; j < 8; ++j) acc[j] = 0.f;

    if (cnt <= 64) {
        bool act = lane < cnt;
        float av = act ? a_src[col_src[s + lane] * HH + w] : 0.f;
        float x = av + adh;
        x = (x > 0.f) ? x : 0.2f * x;
        float v = act ? x : -1e30f;
        float m = v;
        #pragma unroll
        for (int off = 32; off; off >>= 1) m = fmaxf(m, __shfl_xor(m, off));
        float e_ = act ? __expf(v - m) : 0.f;
        float sum = e_;
        #pragma unroll
        for (int off = 32; off; off >>= 1) sum += __shfl_xor(sum, off);
        if (act) sal[w * 64 + lane] = e_ / sum;
        __syncthreads();

        if (cnt > 0) {
            short8 vv; float a;
            {
                int src0 = col_src[s];
                a = sal[w * 64];
                vv = *(const short8*)(hf + (size_t)src0 * F + o);
            }
            for (int i = 0; i < cnt; ++i) {
                short8 w_; float an;
                bool more = (i + 1 < cnt);
                if (more) {
                    int srcn = col_src[s + i + 1];
                    an = sal[w * 64 + i + 1];
                    w_ = *(const short8*)(hf + (size_t)srcn * F + o);
                }
                #pragma unroll
                for (int j = 0; j < 8; ++j)
                    acc[j] = fmaf(a, h2f((u16)vv[j]), acc[j]);
                if (more) { a = an; vv = w_; }
            }
        }
    } else {
        // generic fallback (deg > 64): 3-pass + chunked aggregate
        float m = -1e30f;
        for (int e = s + lane; e < eend; e += 64) {
            float x = a_src[col_src[e] * HH + w] + adh;
            x = (x > 0.f) ? x : 0.2f * x;
            m = fmaxf(m, x);
        }
        #pragma unroll
        for (int off = 32; off; off >>= 1) m = fmaxf(m, __shfl_xor(m, off));
        float sum = 0.f;
        for (int e = s + lane; e < eend; e += 64) {
            float x = a_src[col_src[e] * HH + w] + adh;
            x = (x > 0.f) ? x : 0.2f * x;
            sum += __expf(x - m);
        }
        #pragma unroll
        for (int off = 32; off; off >>= 1) sum += __shfl_xor(sum, off);
        float inv = 1.0f / sum;
        for (int base = s; base < eend; base += 64) {
            int e = base + lane;
            if (e < eend) {
                float x = a_src[col_src[e] * HH + w] + adh;
                x = (x > 0.f) ? x : 0.2f * x;
                sal[w * 64 + lane] = __expf(x - m) * inv;
            }
            __syncthreads();
            int nn = (eend - base < 64) ? (eend - base) : 64;
            for (int i = 0; i < nn; ++i) {
                int src = col_src[base + i];
                float a = sal[w * 64 + i];
                short8 vv = *(const short8*)(hf + (size_t)src * F + o);
                #pragma unroll
                for (int j = 0; j < 8; ++j)
                    acc[j] = fmaf(a, h2f((u16)vv[j]), acc[j]);
            }
            __syncthreads();
        }
    }

    #pragma unroll
    for (int j = 0; j < 8; ++j) {
        acc[j] += bias[o + j];
        if (ELU_) acc[j] = (acc[j] > 0.f) ? acc[j] : __expf(acc[j]) - 1.f;
    }
    if (OMODE == 0) {
        short8 r;
        #pragma unroll
        for (int j = 0; j < 8; ++j) r[j] = (short)f2h(acc[j]);
        *(short8*)(Oh + (size_t)d * F + o) = r;
    } else {
        float* po = Of + (size_t)d * F + o;
        #pragma unroll
        for (int j4 = 0; j4 < 2; ++j4) {
            float4 r;
            r.x = acc[j4 * 4 + 0]; r.y = acc[j4 * 4 + 1];
            r.z = acc[j4 * 4 + 2]; r.w = acc[j4 * 4 + 3];
            *(float4*)&po[j4 * 4] = r;
        }
    }
}

// ---------------------------------------------------------------------------
extern "C" void kernel_launch(void* const* d_in, const int* in_sizes, int n_in,
                              void* d_out, int out_size, void* d_ws, size_t ws_size,
                              hipStream_t stream) {
    const float* x      = (const float*)d_in[0];
    const int*   ei     = (const int*)d_in[1];
    const float* proj_W = (const float*)d_in[2];
    const float* proj_b = (const float*)d_in[3];
    const float* W1  = (const float*)d_in[4];
    const float* as1 = (const float*)d_in[5];
    const float* ad1 = (const float*)d_in[6];
    const float* b1  = (const float*)d_in[7];
    const float* W2  = (const float*)d_in[8];
    const float* as2 = (const float*)d_in[9];
    const float* ad2 = (const float*)d_in[10];
    const float* b2  = (const float*)d_in[11];
    const float* W3  = (const float*)d_in[12];
    const float* as3 = (const float*)d_in[13];
    const float* ad3 = (const float*)d_in[14];
    const float* b3  = (const float*)d_in[15];

    const int N  = in_sizes[0] / 256;   // 10000
    const int E  = in_sizes[1] / 2;     // 160000
    const int Ep = E + N;
    const int NB = (N + 255) / 256;     // 40 scan blocks

    size_t off = 0;
    auto alloc = [&](size_t bytes) -> void* {
        void* p = (char*)d_ws + off;
        off += (bytes + 255) & ~(size_t)255;
        return p;
    };
    u16* bufX    = (u16*)alloc((size_t)N * 2048 * 2);   // fp16 h  (40 MB)
    u16* bufY    = (u16*)alloc((size_t)N * 2048 * 2);   // fp16 h' (40 MB)
    u16* xb_hi   = (u16*)alloc((size_t)N * 256 * 2);
    u16* xb_lo   = (u16*)alloc((size_t)N * 256 * 2);
    u16* pw_hi   = (u16*)alloc((size_t)256 * 512 * 2);  // proj_W flat planes
    u16* pw_lo   = (u16*)alloc((size_t)256 * 512 * 2);
    u16* wf_hi   = (u16*)alloc((size_t)2048 * 256 * 2); // Wfold^T planes
    u16* wf_lo   = (u16*)alloc((size_t)2048 * 256 * 2);
    float* bfold   = (float*)alloc((size_t)2048 * 4);
    float* att_z   = (float*)alloc((size_t)N * 18 * 4); // a_src/a_dst x3 layers
    int*   deg     = (int*)alloc((size_t)N * 4);
    int*   cursor  = (int*)alloc((size_t)N * 4);
    int*   row_ptr = (int*)alloc((size_t)(N + 1) * 4);
    int*   col_src = (int*)alloc((size_t)Ep * 4);
    int*   bsum    = (int*)alloc((size_t)NB * 4);
    int*   boff    = (int*)alloc((size_t)NB * 4);
    (void)ws_size;

    float* a_src1 = att_z;
    float* a_dst1 = att_z + (size_t)N * 4;
    float* a_src2 = att_z + (size_t)N * 8;
    float* a_dst2 = att_z + (size_t)N * 12;
    float* a_src3 = att_z + (size_t)N * 16;
    float* a_dst3 = att_z + (size_t)N * 17;

    // JIT weight planes in d_out (16.78 MB <= 20.48 MB); fully overwritten
    // by the final aggregate afterwards.
    u16* whi = (u16*)d_out;
    u16* wlo = (u16*)d_out + (size_t)2048 * 2048;

    // ---- CSR build + zero att accumulators ----
    hipMemsetAsync(deg, 0, (size_t)N * 4, stream);
    hipMemsetAsync(att_z, 0, (size_t)N * 18 * 4, stream);
    int eb = (Ep + 255) / 256;
    k_deg<<<eb, 256, 0, stream>>>(ei, E, N, deg);
    k_s1<<<NB, 256, 0, stream>>>(deg, row_ptr, bsum, N);
    k_s2<<<1, 64, 0, stream>>>(bsum, boff, NB);
    k_s3<<<NB, 256, 0, stream>>>(deg, row_ptr, boff, cursor, N);
    k_fill<<<eb, 256, 0, stream>>>(ei, E, N, cursor, col_src);

    const int MB1 = (N + 127) / 128;  // 79
    const int MB2 = (N + 255) / 256;  // 40

    // ---- pack x [N,256] and proj_W (flat [256x512]) into bf16 planes ----
    k_pack<<<(N * 256 / 4 + 255) / 256, 256, 0, stream>>>(x, xb_hi, xb_lo, N * 256 / 4);
    k_pack<<<(256 * 512 / 4 + 255) / 256, 256, 0, stream>>>(proj_W, pw_hi, pw_lo, 256 * 512 / 4);

    // ---- W1^T planes; fold: Wfold^T = W1^T @ proj_W^T; bfold = pb @ W1 ----
    k_wt_pack<false><<<dim3(2048 / 32, 512 / 32), 256, 0, stream>>>(W1, whi, wlo, 512, 2048);
    k_bfold<<<2048, 64, 0, stream>>>(proj_b, whi, wlo, bfold, 512);
    k_gemm_pl<2, 2, 0, 0, false><<<dim3(256 / 64, 2048 / 128), 256, 0, stream>>>(
        whi, wlo, pw_hi, pw_lo, nullptr, wf_hi, wf_lo, nullptr,
        nullptr, nullptr, nullptr, nullptr, 0, 2048, 512, 256);

    // ---- layer 1 (K=256 folded; split-bf16 3-product; fp16 h out;
    //      exact fused logits include bfold) ----
    k_gemm_pl<2, 4, 0, 2, true><<<dim3(2048 / 128, MB1), 256, 0, stream>>>(
        xb_hi, xb_lo, wf_hi, wf_lo, bfold, nullptr, nullptr, bufX,
        as1, ad1, a_src1, a_dst1, 4, N, 256, 2048);
    k_sagg<4, 0, true><<<N, 256, 0, stream>>>(row_ptr, col_src, a_src1, a_dst1,
                                              bufX, b1, bufY, nullptr, 512);

    // ---- layer 2 (single-product fp16; BM=256, 8 waves) ----
    k_wt_pack<true><<<dim3(2048 / 32, 2048 / 32), 256, 0, stream>>>(W2, whi, nullptr, 2048, 2048);
    k_gemm_pl<4, 4, 2, 2, true><<<dim3(2048 / 128, MB2), 512, 0, stream>>>(
        bufY, nullptr, whi, nullptr, nullptr, nullptr, nullptr, bufX,
        as2, ad2, a_src2, a_dst2, 4, N, 2048, 2048);
    k_sagg<4, 0, true><<<N, 256, 0, stream>>>(row_ptr, col_src, a_src2, a_dst2,
                                              bufX, b2, bufY, nullptr, 512);

    // ---- layer 3 (single-product fp16; single head -> mean = identity) ----
    k_wt_pack<true><<<dim3(512 / 32, 2048 / 32), 256, 0, stream>>>(W3, whi, nullptr, 2048, 512);
    k_gemm_pl<2, 2, 2, 2, true><<<dim3(512 / 64, MB1), 256, 0, stream>>>(
        bufY, nullptr, whi, nullptr, nullptr, nullptr, nullptr, bufX,
        as3, ad3, a_src3, a_dst3, 1, N, 2048, 512);
    k_sagg<1, 1, false><<<N, 64, 0, stream>>>(row_ptr, col_src, a_src3, a_dst3,
                                              bufX, b3, nullptr, (float*)d_out, 512);
}

// Round 16
// 619.166 us; speedup vs baseline: 2.5462x; 1.0075x over previous
//
#include <hip/hip_runtime.h>
#include <hip/hip_bf16.h>

// ---------------------------------------------------------------------------
// GAT encoder, round 16.
//  * GEMM2/GEMM3: double-buffered LDS, ONE barrier per K-step (T3-minimum
//    pipeline): STAGE(buf^1, t+1) -> COMPUTE(buf) -> __syncthreads().
//    Load issue overlaps the MFMA phase; drain moves after compute.
//  * k_sagg: depth-2 paired prefetch (named slots, in-order consume ->
//    bit-identical FP).
//  * carried: softmax fused in aggregate (r15), GEMM2 BM=256/8-wave (r15),
//    single-product fp16 GEMM2/3 (r14), proj folded into GEMM1 (r13),
//    fp16 payloads + exact fused logits (r10/r12).
// ---------------------------------------------------------------------------

#define LB(x) __launch_bounds__(x)

typedef unsigned short u16;
typedef unsigned int u32;
typedef __attribute__((ext_vector_type(8))) short short8;
typedef __attribute__((ext_vector_type(8))) short bf16x8;
typedef __attribute__((ext_vector_type(8))) _Float16 f16x8;
typedef __attribute__((ext_vector_type(4))) float f32x4;

__device__ __forceinline__ float b2f(u16 u) {
    union { float f; u32 u; } x;
    x.u = ((u32)u) << 16;
    return x.f;
}
__device__ __forceinline__ u16 f2b(float f) {
    u32 u = __float_as_uint(f);
    u = (u + 0x7FFFu + ((u >> 16) & 1u)) >> 16;   // RNE
    return (u16)u;
}
__device__ __forceinline__ u16 f2h(float f) {
    union { _Float16 h; u16 u; } x;
    x.h = (_Float16)f;
    return x.u;
}
__device__ __forceinline__ float h2f(u16 u) {
    union { _Float16 h; u16 u; } x;
    x.u = u;
    return (float)x.h;
}
__device__ __forceinline__ void lds_cp16(const void* g, void* l) {
    __builtin_amdgcn_global_load_lds(
        (const __attribute__((address_space(1))) unsigned int*)g,
        (__attribute__((address_space(3))) unsigned int*)l, 16, 0, 0);
}

// ---------------- CSR build ----------------
__global__ void k_deg(const int* __restrict__ ei, int E, int Np, int* __restrict__ deg) {
    int e = blockIdx.x * blockDim.x + threadIdx.x;
    if (e >= E + Np) return;
    int dst = (e < E) ? ei[E + e] : (e - E);
    atomicAdd(&deg[dst], 1);
}

__global__ LB(256) void k_s1(const int* __restrict__ deg, int* __restrict__ row_ptr,
                             int* __restrict__ bsum, int n) {
    __shared__ int sh[256];
    int b = blockIdx.x, t = threadIdx.x;
    int i = b * 256 + t;
    int v = (i < n) ? deg[i] : 0;
    sh[t] = v;
    __syncthreads();
    #pragma unroll
    for (int off = 1; off < 256; off <<= 1) {
        int add = (t >= off) ? sh[t - off] : 0;
        __syncthreads();
        sh[t] += add;
        __syncthreads();
    }
    if (i < n) row_ptr[i + 1] = sh[t];
    if (t == 255) bsum[b] = sh[255];
}

__global__ LB(64) void k_s2(int* __restrict__ bsum, int* __restrict__ boff, int nb) {
    __shared__ int sh[64];
    int t = threadIdx.x;
    sh[t] = (t < nb) ? bsum[t] : 0;
    __syncthreads();
    #pragma unroll
    for (int off = 1; off < 64; off <<= 1) {
        int add = (t >= off) ? sh[t - off] : 0;
        __syncthreads();
        sh[t] += add;
        __syncthreads();
    }
    if (t < nb) boff[t] = (t == 0) ? 0 : sh[t - 1];
}

__global__ LB(256) void k_s3(const int* __restrict__ deg, int* __restrict__ row_ptr,
                             const int* __restrict__ boff, int* __restrict__ cursor, int n) {
    int b = blockIdx.x, t = threadIdx.x;
    int i = b * 256 + t;
    if (i == 0) row_ptr[0] = 0;
    if (i < n) {
        int inc = row_ptr[i + 1] + boff[b];
        row_ptr[i + 1] = inc;
        cursor[i] = inc - deg[i];
    }
}

__global__ void k_fill(const int* __restrict__ ei, int E, int Np,
                       int* __restrict__ cursor, int* __restrict__ col_src) {
    int e = blockIdx.x * blockDim.x + threadIdx.x;
    if (e >= E + Np) return;
    int src, dst;
    if (e < E) { src = ei[e]; dst = ei[E + e]; }
    else       { src = dst = e - E; }
    int pos = atomicAdd(&cursor[dst], 1);
    col_src[pos] = src;
}

// ---------------- fp32 -> bf16 hi/lo planes (flat) ----------------
__global__ void k_pack(const float* __restrict__ in, u16* __restrict__ hi,
                       u16* __restrict__ lo, int n4) {
    int i = blockIdx.x * blockDim.x + threadIdx.x;
    if (i >= n4) return;
    float4 v = ((const float4*)in)[i];
    ushort4 h, l;
    h.x = f2b(v.x); l.x = f2b(v.x - b2f(h.x));
    h.y = f2b(v.y); l.y = f2b(v.y - b2f(h.y));
    h.z = f2b(v.z); l.z = f2b(v.z - b2f(h.z));
    h.w = f2b(v.w); l.w = f2b(v.w - b2f(h.w));
    ((ushort4*)hi)[i] = h;
    ((ushort4*)lo)[i] = l;
}

// ---------------- weight transpose + pack ----------------
// F16S = false: bf16 hi/lo split planes. F16S = true: single fp16 plane.
template<bool F16S>
__global__ LB(256) void k_wt_pack(const float* __restrict__ W, u16* __restrict__ Whi,
                                  u16* __restrict__ Wlo, int K, int Nn) {
    __shared__ float sh[32][33];
    int n0 = blockIdx.x * 32, k0 = blockIdx.y * 32;
    int c = threadIdx.x & 31, r0 = threadIdx.x >> 5;
    #pragma unroll
    for (int r = r0; r < 32; r += 8)
        sh[r][c] = W[(size_t)(k0 + r) * Nn + n0 + c];
    __syncthreads();
    #pragma unroll
    for (int r = r0; r < 32; r += 8) {
        float v = sh[c][r];
        if (F16S) {
            Whi[(size_t)(n0 + r) * K + k0 + c] = f2h(v);
        } else {
            u16 hi = f2b(v);
            Whi[(size_t)(n0 + r) * K + k0 + c] = hi;
            Wlo[(size_t)(n0 + r) * K + k0 + c] = f2b(v - b2f(hi));
        }
    }
}

// ---------------- bias fold: bfold[n] = sum_k pb[k] * W1[k][n] ------------
__global__ LB(64) void k_bfold(const float* __restrict__ pb,
                               const u16* __restrict__ w1t_hi, const u16* __restrict__ w1t_lo,
                               float* __restrict__ bfold, int K) {
    int n = blockIdx.x;
    int lane = threadIdx.x;
    float s = 0.f;
    for (int k = lane; k < K; k += 64) {
        float w = b2f(w1t_hi[(size_t)n * K + k]) + b2f(w1t_lo[(size_t)n * K + k]);
        s = fmaf(pb[k], w, s);
    }
    #pragma unroll
    for (int off = 32; off; off >>= 1) s += __shfl_xor(s, off);
    if (lane == 0) bfold[n] = s;
}

// ---------------- MFMA GEMM: C = A[M,K] @ Bt[Nn,K]^T -----------------------
// WM waves along M (BM=WM*64), 2 along N (BN=NFR*32), threads = WM*128,
// BK=32. LDS XOR swizzle (row&7)<<4, inverse-permuted global_load_lds src.
// PREC 0: bf16 hi/lo 3-product. PREC 2: fp16 single product.
// DB: double-buffered LDS, one barrier per K-step (stage t+1 overlaps
// compute t; __syncthreads' vmcnt(0)+barrier fences the swap).
// OUTMODE 0: bf16 hi/lo planes. 2: fp16 plane. bias in epilogue (pre-store
// AND pre-logit). ATT: fused exact logits -> atomicAdd.
template<int WM, int NFR, int PREC, int OUTMODE, bool ATT, bool DB>
__global__ __launch_bounds__(WM * 128)
void k_gemm_pl(const u16* __restrict__ Ahi, const u16* __restrict__ Alo,
               const u16* __restrict__ Bhi, const u16* __restrict__ Blo,
               const float* __restrict__ bias,
               u16* __restrict__ Chi, u16* __restrict__ Clo,
               u16* __restrict__ Cf16,
               const float* __restrict__ att_s, const float* __restrict__ att_d,
               float* __restrict__ a_src, float* __restrict__ a_dst,
               int HH, int M, int K, int Nn) {
    constexpr int BM = WM * 64;
    constexpr int BN = NFR * 32;
    constexpr int T  = WM * 128;
    constexpr int BITER = ((NFR * 128) / T > 0) ? (NFR * 128) / T : 1;
    constexpr int NBUF = DB ? 2 : 1;
    constexpr int ASZ = BM * 32;          // u16 elems per A plane buffer
    constexpr int BSZ = BN * 32;
    __shared__ u16 AsHi[NBUF * ASZ];
    __shared__ u16 AsLo[(PREC == 0) ? NBUF * ASZ : 8];
    __shared__ u16 BsHi[NBUF * BSZ];
    __shared__ u16 BsLo[(PREC == 0) ? NBUF * BSZ : 8];
    const int tid  = threadIdx.x;
    const int lane = tid & 63;
    const int w    = tid >> 6;
    const int wr   = w >> 1;          // 0..WM-1
    const int wc   = w & 1;
    const int row0 = blockIdx.y * BM;
    const int col0 = blockIdx.x * BN;
    const int ln15 = lane & 15;
    const int lq   = lane >> 4;

    f32x4 acc[4][NFR];
    #pragma unroll
    for (int m = 0; m < 4; ++m)
        #pragma unroll
        for (int n = 0; n < NFR; ++n) acc[m][n] = (f32x4){0.f, 0.f, 0.f, 0.f};

    auto STAGE = [&](int k0, int buf) {
        size_t ab = (size_t)buf * ASZ * 2;     // byte offsets
        size_t bb = (size_t)buf * BSZ * 2;
        #pragma unroll
        for (int i = 0; i < 2; ++i) {
            int c = i * T + tid;
            int r  = 2 * (c >> 3) + (((c >> 2) ^ (c >> 4)) & 1);   // inverse swizzle
            int kc = (c & 3) ^ (r & 3);
            int gra = row0 + r; if (gra >= M) gra = M - 1;          // tail clamp
            size_t ga = (size_t)gra * K + k0 + kc * 8;
            lds_cp16(Ahi + ga, (char*)AsHi + ab + c * 16);
            if (PREC == 0) lds_cp16(Alo + ga, (char*)AsLo + ab + c * 16);
        }
        #pragma unroll
        for (int i = 0; i < BITER; ++i) {
            int c = i * T + tid;
            int r  = 2 * (c >> 3) + (((c >> 2) ^ (c >> 4)) & 1);
            int kc = (c & 3) ^ (r & 3);
            size_t gb = (size_t)(col0 + r) * K + k0 + kc * 8;
            lds_cp16(Bhi + gb, (char*)BsHi + bb + c * 16);
            if (PREC == 0) lds_cp16(Blo + gb, (char*)BsLo + bb + c * 16);
        }
    };

    auto COMPUTE = [&](int buf) {
        size_t ab = (size_t)buf * ASZ * 2;
        size_t bb = (size_t)buf * BSZ * 2;
        if (PREC == 0) {
            bf16x8 ah[4], al[4], bh[NFR], bl[NFR];
            #pragma unroll
            for (int m = 0; m < 4; ++m) {
                int row = wr * 64 + m * 16 + ln15;
                size_t byo = (size_t)((row * 64 + lq * 16) ^ ((row & 7) << 4));
                ah[m] = *(const bf16x8*)((const char*)AsHi + ab + byo);
                al[m] = *(const bf16x8*)((const char*)AsLo + ab + byo);
            }
            #pragma unroll
            for (int n = 0; n < NFR; ++n) {
                int row = wc * (NFR * 16) + n * 16 + ln15;
                size_t byo = (size_t)((row * 64 + lq * 16) ^ ((row & 7) << 4));
                bh[n] = *(const bf16x8*)((const char*)BsHi + bb + byo);
                bl[n] = *(const bf16x8*)((const char*)BsLo + bb + byo);
            }
            #pragma unroll
            for (int m = 0; m < 4; ++m)
                #pragma unroll
                for (int n = 0; n < NFR; ++n) {
                    acc[m][n] = __builtin_amdgcn_mfma_f32_16x16x32_bf16(al[m], bh[n], acc[m][n], 0, 0, 0);
                    acc[m][n] = __builtin_amdgcn_mfma_f32_16x16x32_bf16(ah[m], bl[n], acc[m][n], 0, 0, 0);
                    acc[m][n] = __builtin_amdgcn_mfma_f32_16x16x32_bf16(ah[m], bh[n], acc[m][n], 0, 0, 0);
                }
        } else {
            f16x8 a[4], b[NFR];
            #pragma unroll
            for (int m = 0; m < 4; ++m) {
                int row = wr * 64 + m * 16 + ln15;
                size_t byo = (size_t)((row * 64 + lq * 16) ^ ((row & 7) << 4));
                a[m] = *(const f16x8*)((const char*)AsHi + ab + byo);
            }
            #pragma unroll
            for (int n = 0; n < NFR; ++n) {
                int row = wc * (NFR * 16) + n * 16 + ln15;
                size_t byo = (size_t)((row * 64 + lq * 16) ^ ((row & 7) << 4));
                b[n] = *(const f16x8*)((const char*)BsHi + bb + byo);
            }
            #pragma unroll
            for (int m = 0; m < 4; ++m)
                #pragma unroll
                for (int n = 0; n < NFR; ++n)
                    acc[m][n] = __builtin_amdgcn_mfma_f32_16x16x32_f16(a[m], b[n], acc[m][n], 0, 0, 0);
        }
    };

    if (DB) {
        const int nt = K >> 5;
        STAGE(0, 0);
        __syncthreads();                       // drain tile 0
        for (int t = 0; t < nt; ++t) {
            int cur = t & 1;
            if (t + 1 < nt) STAGE((t + 1) << 5, cur ^ 1);   // overlaps compute
            COMPUTE(cur);
            __syncthreads();                   // vmcnt(0)+barrier: next tile ready
        }
    } else {
        for (int k0 = 0; k0 < K; k0 += 32) {
            STAGE(k0, 0);
            __syncthreads();
            COMPUTE(0);
            __syncthreads();
        }
    }

    // D: col = lane&15, row = (lane>>4)*4 + j  [m89/m91-verified]
    #pragma unroll
    for (int m = 0; m < 4; ++m) {
        #pragma unroll
        for (int n = 0; n < NFR; ++n) {
            int gc = col0 + wc * (NFR * 16) + n * 16 + ln15;
            float badd = bias ? bias[gc] : 0.f;
            #pragma unroll
            for (int j = 0; j < 4; ++j) {
                int gr = row0 + wr * 64 + m * 16 + lq * 4 + j;
                if (gr < M) {
                    float v = acc[m][n][j] + badd;
                    size_t o = (size_t)gr * Nn + gc;
                    if (OUTMODE == 0) {
                        u16 hi = f2b(v);
                        Chi[o] = hi;
                        Clo[o] = f2b(v - b2f(hi));
                    } else {
                        Cf16[o] = f2h(v);
                    }
                }
            }
        }
    }

    if (ATT) {
        float atts[NFR], attd[NFR], bb[NFR];
        #pragma unroll
        for (int n = 0; n < NFR; ++n) {
            int gc = col0 + wc * (NFR * 16) + n * 16 + ln15;
            atts[n] = att_s[gc];
            attd[n] = att_d[gc];
            bb[n]   = bias ? bias[gc] : 0.f;
        }
        const int head = (col0 + wc * (NFR * 16)) >> 9;   // /512, wave-uniform
        #pragma unroll
        for (int m = 0; m < 4; ++m) {
            #pragma unroll
            for (int j = 0; j < 4; ++j) {
                int gr = row0 + wr * 64 + m * 16 + lq * 4 + j;
                float s1 = 0.f, s2 = 0.f;
                #pragma unroll
                for (int n = 0; n < NFR; ++n) {
                    float v = acc[m][n][j] + bb[n];
                    s1 = fmaf(v, atts[n], s1);
                    s2 = fmaf(v, attd[n], s2);
                }
                #pragma unroll
                for (int off = 1; off < 16; off <<= 1) {
                    s1 += __shfl_xor(s1, off);
                    s2 += __shfl_xor(s2, off);
                }
                if (ln15 == 0 && gr < M) {
                    atomicAdd(&a_src[gr * HH + head], s1);
                    atomicAdd(&a_dst[gr * HH + head], s2);
                }
            }
        }
    }
}

// ---------------- fused softmax + aggregate (one block per dst) ------------
// HH waves; wave w == head w (64 lanes x 8 feats = 512 = C). Alpha computed
// in-register, parked in LDS; gather loop with depth-2 paired prefetch
// (named slots, in-order consume -> bit-identical FP).
template <int HH, int OMODE, bool ELU_>
__global__ __launch_bounds__(HH * 64)
void k_sagg(const int* __restrict__ row_ptr, const int* __restrict__ col_src,
            const float* __restrict__ a_src, const float* __restrict__ a_dst,
            const u16* __restrict__ hf, const float* __restrict__ bias,
            u16* __restrict__ Oh, float* __restrict__ Of, int C) {
    __shared__ float sal[HH * 64];
    const int d    = blockIdx.x;
    const int tid  = threadIdx.x;
    const int w    = tid >> 6;       // head
    const int lane = tid & 63;
    const int F    = HH * C;
    const int o    = tid * 8;
    const int s = row_ptr[d], eend = row_ptr[d + 1];
    const int cnt = eend - s;
    const float adh = a_dst[d * HH + w];

    float acc[8];
    #pragma unroll
    for (int j = 0; j < 8; ++j) acc[j] = 0.f;

    if (cnt <= 64) {
        bool act = lane < cnt;
        float av = act ? a_src[col_src[s + lane] * HH + w] : 0.f;
        float x = av + adh;
        x = (x > 0.f) ? x : 0.2f * x;
        float v = act ? x : -1e30f;
        float m = v;
        #pragma unroll
        for (int off = 32; off; off >>= 1) m = fmaxf(m, __shfl_xor(m, off));
        float e_ = act ? __expf(v - m) : 0.f;
        float sum = e_;
        #pragma unroll
        for (int off = 32; off; off >>= 1) sum += __shfl_xor(sum, off);
        if (act) sal[w * 64 + lane] = e_ / sum;
        __syncthreads();

        // depth-2 paired-prefetch gather (consume strictly in edge order)
        short8 v0, v1; float a0, a1;
        if (cnt > 0) { v0 = *(const short8*)(hf + (size_t)col_src[s] * F + o); a0 = sal[w * 64]; }
        if (cnt > 1) { v1 = *(const short8*)(hf + (size_t)col_src[s + 1] * F + o); a1 = sal[w * 64 + 1]; }
        int i = 0;
        for (; i + 2 <= cnt; i += 2) {
            short8 t0, t1; float b0, b1;
            bool m0 = (i + 2 < cnt), m1 = (i + 3 < cnt);   // block-uniform
            if (m0) { t0 = *(const short8*)(hf + (size_t)col_src[s + i + 2] * F + o); b0 = sal[w * 64 + i + 2]; }
            if (m1) { t1 = *(const short8*)(hf + (size_t)col_src[s + i + 3] * F + o); b1 = sal[w * 64 + i + 3]; }
            #pragma unroll
            for (int j = 0; j < 8; ++j) acc[j] = fmaf(a0, h2f((u16)v0[j]), acc[j]);
            #pragma unroll
            for (int j = 0; j < 8; ++j) acc[j] = fmaf(a1, h2f((u16)v1[j]), acc[j]);
            if (m0) { v0 = t0; a0 = b0; }
            if (m1) { v1 = t1; a1 = b1; }
        }
        if (i < cnt) {   // odd tail: edge i lives in slot 0
            #pragma unroll
            for (int j = 0; j < 8; ++j) acc[j] = fmaf(a0, h2f((u16)v0[j]), acc[j]);
        }
    } else {
        // generic fallback (deg > 64): 3-pass + chunked aggregate
        float m = -1e30f;
        for (int e = s + lane; e < eend; e += 64) {
            float x = a_src[col_src[e] * HH + w] + adh;
            x = (x > 0.f) ? x : 0.2f * x;
            m = fmaxf(m, x);
        }
        #pragma unroll
        for (int off = 32; off; off >>= 1) m = fmaxf(m, __shfl_xor(m, off));
        float sum = 0.f;
        for (int e = s + lane; e < eend; e += 64) {
            float x = a_src[col_src[e] * HH + w] + adh;
            x = (x > 0.f) ? x : 0.2f * x;
            sum += __expf(x - m);
        }
        #pragma unroll
        for (int off = 32; off; off >>= 1) sum += __shfl_xor(sum, off);
        float inv = 1.0f / sum;
        for (int base = s; base < eend; base += 64) {
            int e = base + lane;
            if (e < eend) {
                float x = a_src[col_src[e] * HH + w] + adh;
                x = (x > 0.f) ? x : 0.2f * x;
                sal[w * 64 + lane] = __expf(x - m) * inv;
            }
            __syncthreads();
            int nn = (eend - base < 64) ? (eend - base) : 64;
            for (int i = 0; i < nn; ++i) {
                int src = col_src[base + i];
                float a = sal[w * 64 + i];
                short8 vv = *(const short8*)(hf + (size_t)src * F + o);
                #pragma unroll
                for (int j = 0; j < 8; ++j)
                    acc[j] = fmaf(a, h2f((u16)vv[j]), acc[j]);
            }
            __syncthreads();
        }
    }

    #pragma unroll
    for (int j = 0; j < 8; ++j) {
        acc[j] += bias[o + j];
        if (ELU_) acc[j] = (acc[j] > 0.f) ? acc[j] : __expf(acc[j]) - 1.f;
    }
    if (OMODE == 0) {
        short8 r;
        #pragma unroll
        for (int j = 0; j < 8; ++j) r[j] = (short)f2h(acc[j]);
        *(short8*)(Oh + (size_t)d * F + o) = r;
    } else {
        float* po = Of + (size_t)d * F + o;
        #pragma unroll
        for (int j4 = 0; j4 < 2; ++j4) {
            float4 r;
            r.x = acc[j4 * 4 + 0]; r.y = acc[j4 * 4 + 1];
            r.z = acc[j4 * 4 + 2]; r.w = acc[j4 * 4 + 3];
            *(float4*)&po[j4 * 4] = r;
        }
    }
}

// ---------------------------------------------------------------------------
extern "C" void kernel_launch(void* const* d_in, const int* in_sizes, int n_in,
                              void* d_out, int out_size, void* d_ws, size_t ws_size,
                              hipStream_t stream) {
    const float* x      = (const float*)d_in[0];
    const int*   ei     = (const int*)d_in[1];
    const float* proj_W = (const float*)d_in[2];
    const float* proj_b = (const float*)d_in[3];
    const float* W1  = (const float*)d_in[4];
    const float* as1 = (const float*)d_in[5];
    const float* ad1 = (const float*)d_in[6];
    const float* b1  = (const float*)d_in[7];
    const float* W2  = (const float*)d_in[8];
    const float* as2 = (const float*)d_in[9];
    const float* ad2 = (const float*)d_in[10];
    const float* b2  = (const float*)d_in[11];
    const float* W3  = (const float*)d_in[12];
    const float* as3 = (const float*)d_in[13];
    const float* ad3 = (const float*)d_in[14];
    const float* b3  = (const float*)d_in[15];

    const int N  = in_sizes[0] / 256;   // 10000
    const int E  = in_sizes[1] / 2;     // 160000
    const int Ep = E + N;
    const int NB = (N + 255) / 256;     // 40 scan blocks

    size_t off = 0;
    auto alloc = [&](size_t bytes) -> void* {
        void* p = (char*)d_ws + off;
        off += (bytes + 255) & ~(size_t)255;
        return p;
    };
    u16* bufX    = (u16*)alloc((size_t)N * 2048 * 2);   // fp16 h  (40 MB)
    u16* bufY    = (u16*)alloc((size_t)N * 2048 * 2);   // fp16 h' (40 MB)
    u16* xb_hi   = (u16*)alloc((size_t)N * 256 * 2);
    u16* xb_lo   = (u16*)alloc((size_t)N * 256 * 2);
    u16* pw_hi   = (u16*)alloc((size_t)256 * 512 * 2);  // proj_W flat planes
    u16* pw_lo   = (u16*)alloc((size_t)256 * 512 * 2);
    u16* wf_hi   = (u16*)alloc((size_t)2048 * 256 * 2); // Wfold^T planes
    u16* wf_lo   = (u16*)alloc((size_t)2048 * 256 * 2);
    float* bfold   = (float*)alloc((size_t)2048 * 4);
    float* att_z   = (float*)alloc((size_t)N * 18 * 4); // a_src/a_dst x3 layers
    int*   deg     = (int*)alloc((size_t)N * 4);
    int*   cursor  = (int*)alloc((size_t)N * 4);
    int*   row_ptr = (int*)alloc((size_t)(N + 1) * 4);
    int*   col_src = (int*)alloc((size_t)Ep * 4);
    int*   bsum    = (int*)alloc((size_t)NB * 4);
    int*   boff    = (int*)alloc((size_t)NB * 4);
    (void)ws_size;

    float* a_src1 = att_z;
    float* a_dst1 = att_z + (size_t)N * 4;
    float* a_src2 = att_z + (size_t)N * 8;
    float* a_dst2 = att_z + (size_t)N * 12;
    float* a_src3 = att_z + (size_t)N * 16;
    float* a_dst3 = att_z + (size_t)N * 17;

    // JIT weight planes in d_out (16.78 MB <= 20.48 MB); fully overwritten
    // by the final aggregate afterwards.
    u16* whi = (u16*)d_out;
    u16* wlo = (u16*)d_out + (size_t)2048 * 2048;

    // ---- CSR build + zero att accumulators ----
    hipMemsetAsync(deg, 0, (size_t)N * 4, stream);
    hipMemsetAsync(att_z, 0, (size_t)N * 18 * 4, stream);
    int eb = (Ep + 255) / 256;
    k_deg<<<eb, 256, 0, stream>>>(ei, E, N, deg);
    k_s1<<<NB, 256, 0, stream>>>(deg, row_ptr, bsum, N);
    k_s2<<<1, 64, 0, stream>>>(bsum, boff, NB);
    k_s3<<<NB, 256, 0, stream>>>(deg, row_ptr, boff, cursor, N);
    k_fill<<<eb, 256, 0, stream>>>(ei, E, N, cursor, col_src);

    const int MB1 = (N + 127) / 128;  // 79
    const int MB2 = (N + 255) / 256;  // 40

    // ---- pack x [N,256] and proj_W (flat [256x512]) into bf16 planes ----
    k_pack<<<(N * 256 / 4 + 255) / 256, 256, 0, stream>>>(x, xb_hi, xb_lo, N * 256 / 4);
    k_pack<<<(256 * 512 / 4 + 255) / 256, 256, 0, stream>>>(proj_W, pw_hi, pw_lo, 256 * 512 / 4);

    // ---- W1^T planes; fold: Wfold^T = W1^T @ proj_W^T; bfold = pb @ W1 ----
    k_wt_pack<false><<<dim3(2048 / 32, 512 / 32), 256, 0, stream>>>(W1, whi, wlo, 512, 2048);
    k_bfold<<<2048, 64, 0, stream>>>(proj_b, whi, wlo, bfold, 512);
    k_gemm_pl<2, 2, 0, 0, false, false><<<dim3(256 / 64, 2048 / 128), 256, 0, stream>>>(
        whi, wlo, pw_hi, pw_lo, nullptr, wf_hi, wf_lo, nullptr,
        nullptr, nullptr, nullptr, nullptr, 0, 2048, 512, 256);

    // ---- layer 1 (K=256 folded; split-bf16 3-product; fp16 h out;
    //      exact fused logits include bfold) ----
    k_gemm_pl<2, 4, 0, 2, true, false><<<dim3(2048 / 128, MB1), 256, 0, stream>>>(
        xb_hi, xb_lo, wf_hi, wf_lo, bfold, nullptr, nullptr, bufX,
        as1, ad1, a_src1, a_dst1, 4, N, 256, 2048);
    k_sagg<4, 0, true><<<N, 256, 0, stream>>>(row_ptr, col_src, a_src1, a_dst1,
                                              bufX, b1, bufY, nullptr, 512);

    // ---- layer 2 (single-product fp16; BM=256, 8 waves; double-buffered) --
    k_wt_pack<true><<<dim3(2048 / 32, 2048 / 32), 256, 0, stream>>>(W2, whi, nullptr, 2048, 2048);
    k_gemm_pl<4, 4, 2, 2, true, true><<<dim3(2048 / 128, MB2), 512, 0, stream>>>(
        bufY, nullptr, whi, nullptr, nullptr, nullptr, nullptr, bufX,
        as2, ad2, a_src2, a_dst2, 4, N, 2048, 2048);
    k_sagg<4, 0, true><<<N, 256, 0, stream>>>(row_ptr, col_src, a_src2, a_dst2,
                                              bufX, b2, bufY, nullptr, 512);

    // ---- layer 3 (single-product fp16; double-buffered; 1 head) ----
    k_wt_pack<true><<<dim3(512 / 32, 2048 / 32), 256, 0, stream>>>(W3, whi, nullptr, 2048, 512);
    k_gemm_pl<2, 2, 2, 2, true, true><<<dim3(512 / 64, MB1), 256, 0, stream>>>(
        bufY, nullptr, whi, nullptr, nullptr, nullptr, nullptr, bufX,
        as3, ad3, a_src3, a_dst3, 1, N, 2048, 512);
    k_sagg<1, 1, false><<<N, 64, 0, stream>>>(row_ptr, col_src, a_src3, a_dst3,
                                              bufX, b3, nullptr, (float*)d_out, 512);
}